// Round 2
// baseline (1265.797 us; speedup 1.0000x reference)
//
#include <hip/hip_runtime.h>
#include <math.h>

#define BB 16384
#define P 20
#define NT 512

typedef short v8s __attribute__((ext_vector_type(8)));
typedef _Float16 v8h __attribute__((ext_vector_type(8)));
typedef float f32x4 __attribute__((ext_vector_type(4)));
typedef float f32x16 __attribute__((ext_vector_type(16)));

// ---- static device buffers: referenced ONLY inside device code (never passed
// as kernel args from host — that passes the host shadow and faults). ----
// +4096 pad: knn_mfma reads rows m=20..31 of the last samples (garbage, unused).
#define NELEM ((size_t)BB * P * 320)          // 209.7 MB each
__device__ unsigned int g_C[3][P * P];
__device__ __align__(16) unsigned short g_bufA[NELEM + 4096];  // z1 / z2 / z3 / h4
__device__ __align__(16) unsigned short g_bufB[NELEM + 4096];  // h1 / h2 / h3f
__device__ __align__(16) unsigned short g_W1b[320 * 128];
__device__ __align__(16) unsigned short g_W2b[128 * 320];
__device__ __align__(16) unsigned short g_W3b[64 * 128];
__device__ __align__(16) unsigned short g_W4b[112 * 1024];
__device__ __align__(16) float g_b1p[320];
__device__ __align__(16) float g_b2p[128];
__device__ __align__(16) float g_b3p[64];
__device__ __align__(16) float g_b4p[112];

__device__ inline float bf2f(unsigned short u) {
    union { unsigned int i; float f; } c; c.i = ((unsigned int)u) << 16; return c.f;
}
__device__ inline unsigned short f2bf(float f) {
    union { float f; unsigned int i; } c; c.f = f;
    unsigned int u = c.i + 0x7fffu + ((c.i >> 16) & 1u);  // RNE (no NaN in data)
    return (unsigned short)(u >> 16);
}

__global__ void zero_C_kernel() { g_C[blockIdx.x][threadIdx.x] = 0u; }

// Pad+convert weights/biases to bf16 (zero pads -> pad outputs relu(0+0)=0).
__global__ void prep_kernel(const float* __restrict__ W1, const float* __restrict__ b1,
                            const float* __restrict__ W2, const float* __restrict__ b2,
                            const float* __restrict__ W3, const float* __restrict__ b3,
                            const float* __restrict__ W4, const float* __restrict__ b4) {
    const int stride = gridDim.x * blockDim.x;
    const int id = blockIdx.x * blockDim.x + threadIdx.x;
    for (int i = id; i < 320 * 128; i += stride) { int n = i >> 7, k = i & 127;
        g_W1b[i] = (n < 300) ? f2bf(W1[n * 128 + k]) : 0; }
    for (int i = id; i < 128 * 320; i += stride) { int n = i / 320, k = i - n * 320;
        g_W2b[i] = (n < 100 && k < 300) ? f2bf(W2[n * 300 + k]) : 0; }
    for (int i = id; i < 64 * 128; i += stride) { int n = i >> 7, k = i & 127;
        g_W3b[i] = (n < 50 && k < 100) ? f2bf(W3[n * 100 + k]) : 0; }
    for (int i = id; i < 112 * 1024; i += stride) { int n = i >> 10, k = i & 1023;
        g_W4b[i] = (n < 100 && k < 1000) ? f2bf(W4[n * 1000 + k]) : 0; }
    for (int i = id; i < 320; i += stride) g_b1p[i] = (i < 300) ? b1[i] : 0.f;
    for (int i = id; i < 128; i += stride) g_b2p[i] = (i < 100) ? b2[i] : 0.f;
    for (int i = id; i < 64;  i += stride) g_b3p[i] = (i < 50)  ? b3[i] : 0.f;
    for (int i = id; i < 112; i += stride) g_b4p[i] = (i < 100) ? b4[i] : 0.f;
}

// ---------------- kNN layer 1: MFMA Gram on fp16 hi/lo split (verified r8) --
__global__ __launch_bounds__(NT)
void knn1_mfma_kernel(const float* __restrict__ x) {
    __shared__ float Gs[8][P * 21];
    __shared__ unsigned int hist[P * P];
    const int t = threadIdx.x, w = t >> 6, lane = t & 63;
    const int m31 = lane & 31, half = lane >> 5;
    // Rows 20..31 are MFMA padding; clamp the load to row 19 (x has no tail
    // pad and is an exact page multiple — an unclamped read walks off the
    // allocation for the last sample). Clamped rows are never stored.
    const int mrow = (m31 < P) ? m31 : (P - 1);
    for (int i = t; i < P * P; i += NT) hist[i] = 0;
    for (int pass = 0; pass < 2; ++pass) {
        const size_t s = (size_t)blockIdx.x * 16 + pass * 8 + w;
        const float* rp = x + s * (size_t)(P * 128) + (size_t)mrow * 128 + half * 8;
        f32x16 acc;
#pragma unroll
        for (int i = 0; i < 16; ++i) acc[i] = 0.f;
#pragma unroll
        for (int ks = 0; ks < 8; ++ks) {
            float4 f0 = *(const float4*)(rp + ks * 16);
            float4 f1 = *(const float4*)(rp + ks * 16 + 4);
            float fv[8] = {f0.x, f0.y, f0.z, f0.w, f1.x, f1.y, f1.z, f1.w};
            v8h hi, lo;
#pragma unroll
            for (int j = 0; j < 8; ++j) {
                _Float16 hv = (_Float16)fv[j];
                hi[j] = hv;
                lo[j] = (_Float16)(fv[j] - (float)hv);
            }
            acc = __builtin_amdgcn_mfma_f32_32x32x16_f16(hi, hi, acc, 0, 0, 0);
            acc = __builtin_amdgcn_mfma_f32_32x32x16_f16(hi, lo, acc, 0, 0, 0);
            acc = __builtin_amdgcn_mfma_f32_32x32x16_f16(lo, hi, acc, 0, 0, 0);
            acc = __builtin_amdgcn_mfma_f32_32x32x16_f16(lo, lo, acc, 0, 0, 0);
        }
        float* G = &Gs[w][0];
        if (m31 < P) {
#pragma unroll
            for (int r = 0; r < 16; ++r) {
                int row = (r & 3) + 8 * (r >> 2) + 4 * half;
                if (row < P) G[row * 21 + m31] = acc[r];
            }
        }
        __syncthreads();
        if (lane < P) {
            const int p = lane;
            float d2[P];
            const float gpp = G[p * 21 + p];
#pragma unroll
            for (int u = 0; u < P; ++u)
                d2[u] = (u == p) ? 0.f : gpp + G[u * 21 + u] - 2.f * G[p * 21 + u];
            float pv = -3.0e38f; int pi = -1;
            for (int it = 0; it < 6; ++it) {
                float best = 3.0e38f; int bq = 0;
#pragma unroll
                for (int u = 0; u < P; ++u) {
                    float vu = d2[u];
                    bool cand = (vu > pv) || (vu == pv && u > pi);
                    if (cand && vu < best) { best = vu; bq = u; }
                }
                if (it > 0) atomicAdd(&hist[bq * P + p], 1u);
                pv = best; pi = bq;
            }
        }
        __syncthreads();
    }
    if (t < P * P && hist[t]) atomicAdd(&g_C[0][t], hist[t]);
}

// ---------------- kNN via MFMA Gram: G = Z Z^T per sample (verified r6) -----
template<int D, int CIDX>
__global__ __launch_bounds__(NT)
void knn_mfma_kernel() {
    __shared__ float Gs[8][P * 21];
    __shared__ unsigned int hist[P * P];
    const int t = threadIdx.x, w = t >> 6, lane = t & 63;
    const int m31 = lane & 31, half = lane >> 5;
    for (int i = t; i < P * P; i += NT) hist[i] = 0;
    for (int pass = 0; pass < 2; ++pass) {
        const size_t s = (size_t)blockIdx.x * 16 + pass * 8 + w;
        const unsigned short* rp = g_bufB + s * (P * D) + (size_t)m31 * D + half * 8;
        f32x16 acc;
#pragma unroll
        for (int i = 0; i < 16; ++i) acc[i] = 0.f;
        for (int ks = 0; ks < D / 16; ++ks) {
            v8s z = *(const v8s*)(rp + ks * 16);
            acc = __builtin_amdgcn_mfma_f32_32x32x16_bf16(z, z, acc, 0, 0, 0);
        }
        float* G = &Gs[w][0];
        if (m31 < P) {
#pragma unroll
            for (int r = 0; r < 16; ++r) {
                int row = (r & 3) + 8 * (r >> 2) + 4 * half;
                if (row < P) G[row * 21 + m31] = acc[r];
            }
        }
        __syncthreads();
        if (lane < P) {
            const int p = lane;
            float d2[P];
            const float gpp = G[p * 21 + p];
#pragma unroll
            for (int u = 0; u < P; ++u)
                d2[u] = (u == p) ? 0.f : gpp + G[u * 21 + u] - 2.f * G[p * 21 + u];
            float pv = -3.0e38f; int pi = -1;
            for (int it = 0; it < 6; ++it) {
                float best = 3.0e38f; int bq = 0;
#pragma unroll
                for (int u = 0; u < P; ++u) {
                    float vu = d2[u];
                    bool cand = (vu > pv) || (vu == pv && u > pi);
                    if (cand && vu < best) { best = vu; bq = u; }
                }
                if (it > 0) atomicAdd(&hist[bq * P + p], 1u);
                pv = best; pi = bq;
            }
        }
        __syncthreads();
    }
    if (t < P * P && hist[t]) atomicAdd(&g_C[CIDX][t], hist[t]);
}

// compute_M for 256-thread blocks (strided loops)
__device__ inline void compute_M_256(const unsigned int* __restrict__ Cg,
                                     float* Ms, float* dinv, int t) {
    for (int i = t; i < P * P; i += 256) Ms[i] = (float)Cg[i];
    __syncthreads();
    if (t < P) {
        float deg = 1.f;
        for (int u = 0; u < P; ++u) deg += Ms[t * P + u];
        dinv[t] = 1.f / sqrtf(deg);
    }
    __syncthreads();
    for (int i = t; i < P * P; i += 256) {
        int v = i / P, u = i - v * P;
        float m = dinv[v] * Ms[i] * dinv[u];
        if (v == u) m += dinv[v] * dinv[v];
        Ms[i] = m;
    }
    __syncthreads();
}

// ---------------- agg: LDS-staged, vectorized (round-7 rewrite) -------------
template<int D, bool INF32, int CIDX, int SAMP>
__global__ __launch_bounds__(256)
void agg_kernel(const float* __restrict__ xin) {
    __shared__ float Ms[P * P];
    __shared__ float dinv[P];
    __shared__ __align__(16) float hsf[SAMP][P][D];
    const int t = threadIdx.x;
    compute_M_256(g_C[CIDX], Ms, dinv, t);
    constexpr int C4 = D / 4;               // float4 chunks per row
    for (long s0 = (long)blockIdx.x * SAMP; s0 < BB; s0 += (long)gridDim.x * SAMP) {
        __syncthreads();                    // hsf reuse guard
        if (INF32) {
            const float4* src = (const float4*)(xin + s0 * (P * D));
            for (int i = t; i < SAMP * P * C4; i += 256) {
                float4 v = src[i];
                int r = i / C4, c = i - r * C4;
                *(float4*)&hsf[r / P][r % P][c * 4] = v;
            }
        } else {
            const ushort4* src = (const ushort4*)(g_bufB + s0 * (P * D));
            for (int i = t; i < SAMP * P * C4; i += 256) {
                ushort4 u = src[i];
                int r = i / C4, c = i - r * C4;
                float4 f; f.x = bf2f(u.x); f.y = bf2f(u.y);
                f.z = bf2f(u.z); f.w = bf2f(u.w);
                *(float4*)&hsf[r / P][r % P][c * 4] = f;
            }
        }
        __syncthreads();
        // items: (smp, vg of 4 v's, c4). 5 v-groups per sample.
        for (int i = t; i < SAMP * 5 * C4; i += 256) {
            const int c4 = i % C4;
            const int g = i / C4;
            const int smp = g / 5, v0 = (g - smp * 5) * 4;
            float4 a0 = {0,0,0,0}, a1 = {0,0,0,0}, a2 = {0,0,0,0}, a3 = {0,0,0,0};
#pragma unroll
            for (int u = 0; u < P; ++u) {
                float4 h = *(const float4*)&hsf[smp][u][c4 * 4];
                float m0 = Ms[(v0 + 0) * P + u], m1 = Ms[(v0 + 1) * P + u];
                float m2 = Ms[(v0 + 2) * P + u], m3 = Ms[(v0 + 3) * P + u];
                a0.x += m0*h.x; a0.y += m0*h.y; a0.z += m0*h.z; a0.w += m0*h.w;
                a1.x += m1*h.x; a1.y += m1*h.y; a1.z += m1*h.z; a1.w += m1*h.w;
                a2.x += m2*h.x; a2.y += m2*h.y; a2.z += m2*h.z; a2.w += m2*h.w;
                a3.x += m3*h.x; a3.y += m3*h.y; a3.z += m3*h.z; a3.w += m3*h.w;
            }
            unsigned short* zb = g_bufA + (s0 + smp) * (size_t)(P * D) + c4 * 4;
            ushort4 o;
            o.x = f2bf(a0.x); o.y = f2bf(a0.y); o.z = f2bf(a0.z); o.w = f2bf(a0.w);
            *(ushort4*)(zb + (size_t)(v0 + 0) * D) = o;
            o.x = f2bf(a1.x); o.y = f2bf(a1.y); o.z = f2bf(a1.z); o.w = f2bf(a1.w);
            *(ushort4*)(zb + (size_t)(v0 + 1) * D) = o;
            o.x = f2bf(a2.x); o.y = f2bf(a2.y); o.z = f2bf(a2.z); o.w = f2bf(a2.w);
            *(ushort4*)(zb + (size_t)(v0 + 2) * D) = o;
            o.x = f2bf(a3.x); o.y = f2bf(a3.y); o.z = f2bf(a3.z); o.w = f2bf(a3.w);
            *(ushort4*)(zb + (size_t)(v0 + 3) * D) = o;
        }
    }
}

// ---------------- barrier-free streaming MFMA GEMM (round-9: N-split + -----
// 1-step A prefetch). NSPLIT slices the N dimension across blockIdx.y so the
// per-wave accumulator (ZR * Np/16/NSPLIT * 4 regs) fits the unified VGPR
// file at >=2 waves/SIMD (round-8's acc[2][20]=160 AGPRs forced 1 wave/SIMD
// -> full latency exposure, Occupancy 11%, MfmaUtil 4.6%). A-slices re-read
// NSPLIT times come from L3. Prefetch keeps next K-step's A (HBM) in flight
// under the current MFMA burst. Math per output is unchanged (bit-exact).
template<int Kp, int Np, int ZR, bool FLAT, int WSEL, bool ATOB, int NSPLIT>
__global__ __launch_bounds__(256)
void gemm_kernel() {
    constexpr int NF = Np / 16 / NSPLIT, KS = Kp / 32;
    const unsigned short* __restrict__ Wb =
        (WSEL == 1) ? g_W1b : (WSEL == 2) ? g_W2b : (WSEL == 3) ? g_W3b : g_W4b;
    const float* __restrict__ bp =
        (WSEL == 1) ? g_b1p : (WSEL == 2) ? g_b2p : (WSEL == 3) ? g_b3p : g_b4p;
    const unsigned short* __restrict__ A = ATOB ? g_bufA : g_bufB;
    unsigned short* __restrict__ Hout = ATOB ? g_bufB : g_bufA;
    const int t = threadIdx.x, w = t >> 6, lane = t & 63;
    const int m15 = lane & 15, q = lane >> 4;
    const int n0 = blockIdx.y * (Np / NSPLIT);
    const long row0 = (long)blockIdx.x * (4 * ZR * 16) + w * (ZR * 16);
    f32x4 acc[ZR][NF];
#pragma unroll
    for (int zr = 0; zr < ZR; ++zr)
#pragma unroll
        for (int nf = 0; nf < NF; ++nf) acc[zr][nf] = 0.f;
    const unsigned short* aBase = A + (row0 + m15) * Kp + q * 8;
    const unsigned short* wBase = Wb + (size_t)(n0 + m15) * Kp + q * 8;
    v8s bzc[ZR];
#pragma unroll
    for (int zr = 0; zr < ZR; ++zr)
        bzc[zr] = *(const v8s*)(aBase + (size_t)zr * 16 * Kp);
    for (int ks = 0; ks < KS; ++ks) {
        v8s bzn[ZR];
        if (ks + 1 < KS) {
#pragma unroll
            for (int zr = 0; zr < ZR; ++zr)
                bzn[zr] = *(const v8s*)(aBase + (size_t)zr * 16 * Kp + (ks + 1) * 32);
        }
#pragma unroll
        for (int nf = 0; nf < NF; ++nf) {
            v8s a = *(const v8s*)(wBase + (size_t)nf * 16 * Kp + ks * 32);
#pragma unroll
            for (int zr = 0; zr < ZR; ++zr)
                acc[zr][nf] = __builtin_amdgcn_mfma_f32_16x16x32_bf16(
                    a, bzc[zr], acc[zr][nf], 0, 0, 0);
        }
        if (ks + 1 < KS) {
#pragma unroll
            for (int zr = 0; zr < ZR; ++zr) bzc[zr] = bzn[zr];
        }
    }
#pragma unroll
    for (int zr = 0; zr < ZR; ++zr) {
        const long m = row0 + zr * 16 + m15;
#pragma unroll
        for (int nf = 0; nf < NF; ++nf) {
            f32x4 b4 = *(const f32x4*)(bp + n0 + nf * 16 + q * 4);
            f32x4 c = acc[zr][nf];
            float v0 = fmaxf(c[0] + b4[0], 0.f), v1 = fmaxf(c[1] + b4[1], 0.f);
            float v2 = fmaxf(c[2] + b4[2], 0.f), v3 = fmaxf(c[3] + b4[3], 0.f);
            if (!FLAT) {
                ushort4 o; o.x = f2bf(v0); o.y = f2bf(v1); o.z = f2bf(v2); o.w = f2bf(v3);
                *(ushort4*)(Hout + (size_t)m * Np + n0 + nf * 16 + q * 4) = o;
            } else {
                const int n0f = nf * 16 + q * 4;   // FLAT only used with NSPLIT=1
                if (n0f <= 48) {
                    const long s = m / 20; const int u = (int)(m - s * 20);
                    unsigned short* base = Hout + (size_t)s * 1024 + u * 50 + n0f;
                    unsigned int lo = (unsigned int)f2bf(v0) | ((unsigned int)f2bf(v1) << 16);
                    *(unsigned int*)(base) = lo;
                    if (n0f < 48) {
                        unsigned int hi = (unsigned int)f2bf(v2) | ((unsigned int)f2bf(v3) << 16);
                        *(unsigned int*)(base + 2) = hi;
                    }
                }
            }
        }
    }
}

// logits = W5 h4 + b5; softmax -> out. h4 in g_bufA (112-padded rows).
__global__ __launch_bounds__(256)
void head_kernel(const float* __restrict__ W5, const float* __restrict__ b5,
                 float* __restrict__ out) {
    __shared__ float w5s[300];
    __shared__ float b5s[3];
    const int t = threadIdx.x;
    for (int i = t; i < 300; i += 256) w5s[i] = W5[i];
    if (t < 3) b5s[t] = b5[t];
    __syncthreads();
    const int s = blockIdx.x * 256 + t;
    const unsigned short* h = g_bufA + (size_t)s * 112;
    float a0 = b5s[0], a1 = b5s[1], a2 = b5s[2];
    for (int k = 0; k < 100; ++k) {
        float hv = bf2f(h[k]);
        a0 += hv * w5s[k]; a1 += hv * w5s[100 + k]; a2 += hv * w5s[200 + k];
    }
    float m = fmaxf(a0, fmaxf(a1, a2));
    float e0 = expf(a0 - m), e1 = expf(a1 - m), e2 = expf(a2 - m);
    float inv = 1.f / (e0 + e1 + e2);
    out[(size_t)s * 3 + 0] = e0 * inv;
    out[(size_t)s * 3 + 1] = e1 * inv;
    out[(size_t)s * 3 + 2] = e2 * inv;
}

extern "C" void kernel_launch(void* const* d_in, const int* in_sizes, int n_in,
                              void* d_out, int out_size, void* d_ws, size_t ws_size,
                              hipStream_t stream) {
    const float* x  = (const float*)d_in[0];
    const float* W1 = (const float*)d_in[1];
    const float* b1 = (const float*)d_in[2];
    const float* W2 = (const float*)d_in[3];
    const float* b2 = (const float*)d_in[4];
    const float* W3 = (const float*)d_in[5];
    const float* b3 = (const float*)d_in[6];
    const float* W4 = (const float*)d_in[7];
    const float* b4 = (const float*)d_in[8];
    const float* W5 = (const float*)d_in[9];
    const float* b5 = (const float*)d_in[10];
    float* out = (float*)d_out;

    zero_C_kernel<<<3, P * P, 0, stream>>>();
    prep_kernel<<<256, 256, 0, stream>>>(W1, b1, W2, b2, W3, b3, W4, b4);

    knn1_mfma_kernel<<<BB / 16, NT, 0, stream>>>(x);                 // x -> C0
    agg_kernel<128, true, 0, 4><<<1024, 256, 0, stream>>>(x);        // x -> z1(A)
    // 128 rows/block, N split in 2 -> acc 80 regs, 2 waves/SIMD
    gemm_kernel<128, 320, 2, false, 1, true, 2>
        <<<dim3(2560, 2), 256, 0, stream>>>();                       // z1 -> h1(B)

    knn_mfma_kernel<320, 1><<<BB / 16, NT, 0, stream>>>();           // h1 -> C1
    agg_kernel<320, false, 1, 2><<<1024, 256, 0, stream>>>(nullptr); // h1 -> z2(A)
    // ZR 4->2 + N split 2 -> acc 32 regs, high occupancy
    gemm_kernel<320, 128, 2, false, 2, true, 2>
        <<<dim3(2560, 2), 256, 0, stream>>>();                       // z2 -> h2(B)

    knn_mfma_kernel<128, 2><<<BB / 16, NT, 0, stream>>>();           // h2 -> C2
    agg_kernel<128, false, 2, 4><<<1024, 256, 0, stream>>>(nullptr); // h2 -> z3(A)
    gemm_kernel<128, 64, 4, true, 3, true, 1>
        <<<dim3(1280, 1), 256, 0, stream>>>();                       // z3 -> h3f(B)

    // N split in 7 (NF=1, acc 4 regs): 1792 blocks instead of 256
    gemm_kernel<1024, 112, 1, false, 4, false, 7>
        <<<dim3(256, 7), 256, 0, stream>>>();                        // h3f -> h4(A)
    head_kernel<<<BB / 256, 256, 0, stream>>>(W5, b5, out);
}

// Round 3
// 1213.127 us; speedup vs baseline: 1.0434x; 1.0434x over previous
//
#include <hip/hip_runtime.h>
#include <math.h>

#define BB 16384
#define P 20
#define NT 512

typedef short v8s __attribute__((ext_vector_type(8)));
typedef _Float16 v8h __attribute__((ext_vector_type(8)));
typedef float f32x4 __attribute__((ext_vector_type(4)));
typedef float f32x16 __attribute__((ext_vector_type(16)));

// ---- static device buffers: referenced ONLY inside device code (never passed
// as kernel args from host — that passes the host shadow and faults). ----
// +4096 pad: knn_mfma reads rows m=20..31 of the last samples (garbage, unused).
#define NELEM ((size_t)BB * P * 320)          // 209.7 MB each
__device__ unsigned int g_C[3][P * P];
__device__ __align__(16) unsigned short g_bufA[NELEM + 4096];  // z1 / z2 / z3 / h4
__device__ __align__(16) unsigned short g_bufB[NELEM + 4096];  // h1 / h2 / h3f
__device__ __align__(16) unsigned short g_W1b[320 * 128];
__device__ __align__(16) unsigned short g_W2b[128 * 320];
__device__ __align__(16) unsigned short g_W3b[64 * 128];
__device__ __align__(16) unsigned short g_W4b[112 * 1024];
__device__ __align__(16) float g_b1p[320];
__device__ __align__(16) float g_b2p[128];
__device__ __align__(16) float g_b3p[64];
__device__ __align__(16) float g_b4p[112];

__device__ inline float bf2f(unsigned short u) {
    union { unsigned int i; float f; } c; c.i = ((unsigned int)u) << 16; return c.f;
}
__device__ inline unsigned short f2bf(float f) {
    union { float f; unsigned int i; } c; c.f = f;
    unsigned int u = c.i + 0x7fffu + ((c.i >> 16) & 1u);  // RNE (no NaN in data)
    return (unsigned short)(u >> 16);
}

__global__ void zero_C_kernel() { g_C[blockIdx.x][threadIdx.x] = 0u; }

// Pad+convert weights/biases to bf16 (zero pads -> pad outputs relu(0+0)=0).
__global__ void prep_kernel(const float* __restrict__ W1, const float* __restrict__ b1,
                            const float* __restrict__ W2, const float* __restrict__ b2,
                            const float* __restrict__ W3, const float* __restrict__ b3,
                            const float* __restrict__ W4, const float* __restrict__ b4) {
    const int stride = gridDim.x * blockDim.x;
    const int id = blockIdx.x * blockDim.x + threadIdx.x;
    for (int i = id; i < 320 * 128; i += stride) { int n = i >> 7, k = i & 127;
        g_W1b[i] = (n < 300) ? f2bf(W1[n * 128 + k]) : 0; }
    for (int i = id; i < 128 * 320; i += stride) { int n = i / 320, k = i - n * 320;
        g_W2b[i] = (n < 100 && k < 300) ? f2bf(W2[n * 300 + k]) : 0; }
    for (int i = id; i < 64 * 128; i += stride) { int n = i >> 7, k = i & 127;
        g_W3b[i] = (n < 50 && k < 100) ? f2bf(W3[n * 100 + k]) : 0; }
    for (int i = id; i < 112 * 1024; i += stride) { int n = i >> 10, k = i & 1023;
        g_W4b[i] = (n < 100 && k < 1000) ? f2bf(W4[n * 1000 + k]) : 0; }
    for (int i = id; i < 320; i += stride) g_b1p[i] = (i < 300) ? b1[i] : 0.f;
    for (int i = id; i < 128; i += stride) g_b2p[i] = (i < 100) ? b2[i] : 0.f;
    for (int i = id; i < 64;  i += stride) g_b3p[i] = (i < 50)  ? b3[i] : 0.f;
    for (int i = id; i < 112; i += stride) g_b4p[i] = (i < 100) ? b4[i] : 0.f;
}

// ---------------- kNN layer 1: MFMA Gram on fp16 hi/lo split (verified r8) --
__global__ __launch_bounds__(NT)
void knn1_mfma_kernel(const float* __restrict__ x) {
    __shared__ float Gs[8][P * 21];
    __shared__ unsigned int hist[P * P];
    const int t = threadIdx.x, w = t >> 6, lane = t & 63;
    const int m31 = lane & 31, half = lane >> 5;
    // Rows 20..31 are MFMA padding; clamp the load to row 19 (x has no tail
    // pad and is an exact page multiple — an unclamped read walks off the
    // allocation for the last sample). Clamped rows are never stored.
    const int mrow = (m31 < P) ? m31 : (P - 1);
    for (int i = t; i < P * P; i += NT) hist[i] = 0;
    for (int pass = 0; pass < 2; ++pass) {
        const size_t s = (size_t)blockIdx.x * 16 + pass * 8 + w;
        const float* rp = x + s * (size_t)(P * 128) + (size_t)mrow * 128 + half * 8;
        f32x16 acc;
#pragma unroll
        for (int i = 0; i < 16; ++i) acc[i] = 0.f;
#pragma unroll
        for (int ks = 0; ks < 8; ++ks) {
            float4 f0 = *(const float4*)(rp + ks * 16);
            float4 f1 = *(const float4*)(rp + ks * 16 + 4);
            float fv[8] = {f0.x, f0.y, f0.z, f0.w, f1.x, f1.y, f1.z, f1.w};
            v8h hi, lo;
#pragma unroll
            for (int j = 0; j < 8; ++j) {
                _Float16 hv = (_Float16)fv[j];
                hi[j] = hv;
                lo[j] = (_Float16)(fv[j] - (float)hv);
            }
            acc = __builtin_amdgcn_mfma_f32_32x32x16_f16(hi, hi, acc, 0, 0, 0);
            acc = __builtin_amdgcn_mfma_f32_32x32x16_f16(hi, lo, acc, 0, 0, 0);
            acc = __builtin_amdgcn_mfma_f32_32x32x16_f16(lo, hi, acc, 0, 0, 0);
            acc = __builtin_amdgcn_mfma_f32_32x32x16_f16(lo, lo, acc, 0, 0, 0);
        }
        float* G = &Gs[w][0];
        if (m31 < P) {
#pragma unroll
            for (int r = 0; r < 16; ++r) {
                int row = (r & 3) + 8 * (r >> 2) + 4 * half;
                if (row < P) G[row * 21 + m31] = acc[r];
            }
        }
        __syncthreads();
        if (lane < P) {
            const int p = lane;
            float d2[P];
            const float gpp = G[p * 21 + p];
#pragma unroll
            for (int u = 0; u < P; ++u)
                d2[u] = (u == p) ? 0.f : gpp + G[u * 21 + u] - 2.f * G[p * 21 + u];
            float pv = -3.0e38f; int pi = -1;
            for (int it = 0; it < 6; ++it) {
                float best = 3.0e38f; int bq = 0;
#pragma unroll
                for (int u = 0; u < P; ++u) {
                    float vu = d2[u];
                    bool cand = (vu > pv) || (vu == pv && u > pi);
                    if (cand && vu < best) { best = vu; bq = u; }
                }
                if (it > 0) atomicAdd(&hist[bq * P + p], 1u);
                pv = best; pi = bq;
            }
        }
        __syncthreads();
    }
    if (t < P * P && hist[t]) atomicAdd(&g_C[0][t], hist[t]);
}

// ---------------- kNN via MFMA Gram: G = Z Z^T per sample (verified r6) -----
template<int D, int CIDX>
__global__ __launch_bounds__(NT)
void knn_mfma_kernel() {
    __shared__ float Gs[8][P * 21];
    __shared__ unsigned int hist[P * P];
    const int t = threadIdx.x, w = t >> 6, lane = t & 63;
    const int m31 = lane & 31, half = lane >> 5;
    for (int i = t; i < P * P; i += NT) hist[i] = 0;
    for (int pass = 0; pass < 2; ++pass) {
        const size_t s = (size_t)blockIdx.x * 16 + pass * 8 + w;
        const unsigned short* rp = g_bufB + s * (P * D) + (size_t)m31 * D + half * 8;
        f32x16 acc;
#pragma unroll
        for (int i = 0; i < 16; ++i) acc[i] = 0.f;
        for (int ks = 0; ks < D / 16; ++ks) {
            v8s z = *(const v8s*)(rp + ks * 16);
            acc = __builtin_amdgcn_mfma_f32_32x32x16_bf16(z, z, acc, 0, 0, 0);
        }
        float* G = &Gs[w][0];
        if (m31 < P) {
#pragma unroll
            for (int r = 0; r < 16; ++r) {
                int row = (r & 3) + 8 * (r >> 2) + 4 * half;
                if (row < P) G[row * 21 + m31] = acc[r];
            }
        }
        __syncthreads();
        if (lane < P) {
            const int p = lane;
            float d2[P];
            const float gpp = G[p * 21 + p];
#pragma unroll
            for (int u = 0; u < P; ++u)
                d2[u] = (u == p) ? 0.f : gpp + G[u * 21 + u] - 2.f * G[p * 21 + u];
            float pv = -3.0e38f; int pi = -1;
            for (int it = 0; it < 6; ++it) {
                float best = 3.0e38f; int bq = 0;
#pragma unroll
                for (int u = 0; u < P; ++u) {
                    float vu = d2[u];
                    bool cand = (vu > pv) || (vu == pv && u > pi);
                    if (cand && vu < best) { best = vu; bq = u; }
                }
                if (it > 0) atomicAdd(&hist[bq * P + p], 1u);
                pv = best; pi = bq;
            }
        }
        __syncthreads();
    }
    if (t < P * P && hist[t]) atomicAdd(&g_C[CIDX][t], hist[t]);
}

// compute_M for 256-thread blocks (strided loops)
__device__ inline void compute_M_256(const unsigned int* __restrict__ Cg,
                                     float* Ms, float* dinv, int t) {
    for (int i = t; i < P * P; i += 256) Ms[i] = (float)Cg[i];
    __syncthreads();
    if (t < P) {
        float deg = 1.f;
        for (int u = 0; u < P; ++u) deg += Ms[t * P + u];
        dinv[t] = 1.f / sqrtf(deg);
    }
    __syncthreads();
    for (int i = t; i < P * P; i += 256) {
        int v = i / P, u = i - v * P;
        float m = dinv[v] * Ms[i] * dinv[u];
        if (v == u) m += dinv[v] * dinv[v];
        Ms[i] = m;
    }
    __syncthreads();
}

// ---------------- agg: LDS-staged, vectorized (round-7 rewrite) -------------
template<int D, bool INF32, int CIDX, int SAMP>
__global__ __launch_bounds__(256)
void agg_kernel(const float* __restrict__ xin) {
    __shared__ float Ms[P * P];
    __shared__ float dinv[P];
    __shared__ __align__(16) float hsf[SAMP][P][D];
    const int t = threadIdx.x;
    compute_M_256(g_C[CIDX], Ms, dinv, t);
    constexpr int C4 = D / 4;               // float4 chunks per row
    for (long s0 = (long)blockIdx.x * SAMP; s0 < BB; s0 += (long)gridDim.x * SAMP) {
        __syncthreads();                    // hsf reuse guard
        if (INF32) {
            const float4* src = (const float4*)(xin + s0 * (P * D));
            for (int i = t; i < SAMP * P * C4; i += 256) {
                float4 v = src[i];
                int r = i / C4, c = i - r * C4;
                *(float4*)&hsf[r / P][r % P][c * 4] = v;
            }
        } else {
            const ushort4* src = (const ushort4*)(g_bufB + s0 * (P * D));
            for (int i = t; i < SAMP * P * C4; i += 256) {
                ushort4 u = src[i];
                int r = i / C4, c = i - r * C4;
                float4 f; f.x = bf2f(u.x); f.y = bf2f(u.y);
                f.z = bf2f(u.z); f.w = bf2f(u.w);
                *(float4*)&hsf[r / P][r % P][c * 4] = f;
            }
        }
        __syncthreads();
        // items: (smp, vg of 4 v's, c4). 5 v-groups per sample.
        for (int i = t; i < SAMP * 5 * C4; i += 256) {
            const int c4 = i % C4;
            const int g = i / C4;
            const int smp = g / 5, v0 = (g - smp * 5) * 4;
            float4 a0 = {0,0,0,0}, a1 = {0,0,0,0}, a2 = {0,0,0,0}, a3 = {0,0,0,0};
#pragma unroll
            for (int u = 0; u < P; ++u) {
                float4 h = *(const float4*)&hsf[smp][u][c4 * 4];
                float m0 = Ms[(v0 + 0) * P + u], m1 = Ms[(v0 + 1) * P + u];
                float m2 = Ms[(v0 + 2) * P + u], m3 = Ms[(v0 + 3) * P + u];
                a0.x += m0*h.x; a0.y += m0*h.y; a0.z += m0*h.z; a0.w += m0*h.w;
                a1.x += m1*h.x; a1.y += m1*h.y; a1.z += m1*h.z; a1.w += m1*h.w;
                a2.x += m2*h.x; a2.y += m2*h.y; a2.z += m2*h.z; a2.w += m2*h.w;
                a3.x += m3*h.x; a3.y += m3*h.y; a3.z += m3*h.z; a3.w += m3*h.w;
            }
            unsigned short* zb = g_bufA + (s0 + smp) * (size_t)(P * D) + c4 * 4;
            ushort4 o;
            o.x = f2bf(a0.x); o.y = f2bf(a0.y); o.z = f2bf(a0.z); o.w = f2bf(a0.w);
            *(ushort4*)(zb + (size_t)(v0 + 0) * D) = o;
            o.x = f2bf(a1.x); o.y = f2bf(a1.y); o.z = f2bf(a1.z); o.w = f2bf(a1.w);
            *(ushort4*)(zb + (size_t)(v0 + 1) * D) = o;
            o.x = f2bf(a2.x); o.y = f2bf(a2.y); o.z = f2bf(a2.z); o.w = f2bf(a2.w);
            *(ushort4*)(zb + (size_t)(v0 + 2) * D) = o;
            o.x = f2bf(a3.x); o.y = f2bf(a3.y); o.z = f2bf(a3.z); o.w = f2bf(a3.w);
            *(ushort4*)(zb + (size_t)(v0 + 3) * D) = o;
        }
    }
}

// ---------------- streaming MFMA GEMM, round-10: chunked full-hoist ---------
// Round-2 lesson: per-K-step load->wait->MFMA leaves ~2-4 loads in flight ->
// pure latency exposure (MfmaUtil == FLOP-floor%, BW 1.9 TB/s). Fix: hoist
// ALL A-fragments of a K-chunk (KSC steps) into registers BEFORE any MFMA --
// up to ZR*KSC independent 16B HBM loads in flight per wave (20 for gemm2).
// NSPLIT only where A is L3-resident (gemm1: 84MB z1, gemm4: 33MB h3f);
// gemm2 reverted to single-pass (round-2's NSPLIT=2 streamed 420MB -> thrash).
// Per-output accumulation order (ascending ks) unchanged -> bit-exact.
template<int Kp, int Np, int ZR, bool FLAT, int WSEL, bool ATOB, int NSPLIT, int KSC>
__global__ __launch_bounds__(256)
void gemm_kernel() {
    constexpr int NF = Np / 16 / NSPLIT, KS = Kp / 32;
    static_assert(KS % KSC == 0, "KSC must divide KS");
    const unsigned short* __restrict__ Wb =
        (WSEL == 1) ? g_W1b : (WSEL == 2) ? g_W2b : (WSEL == 3) ? g_W3b : g_W4b;
    const float* __restrict__ bp =
        (WSEL == 1) ? g_b1p : (WSEL == 2) ? g_b2p : (WSEL == 3) ? g_b3p : g_b4p;
    const unsigned short* __restrict__ A = ATOB ? g_bufA : g_bufB;
    unsigned short* __restrict__ Hout = ATOB ? g_bufB : g_bufA;
    const int t = threadIdx.x, w = t >> 6, lane = t & 63;
    const int m15 = lane & 15, q = lane >> 4;
    const int n0 = blockIdx.y * (Np / NSPLIT);
    const long row0 = (long)blockIdx.x * (4 * ZR * 16) + w * (ZR * 16);
    f32x4 acc[ZR][NF];
#pragma unroll
    for (int zr = 0; zr < ZR; ++zr)
#pragma unroll
        for (int nf = 0; nf < NF; ++nf) acc[zr][nf] = 0.f;
    const unsigned short* aBase = A + (row0 + m15) * Kp + q * 8;
    const unsigned short* wBase = Wb + (size_t)(n0 + m15) * Kp + q * 8;
    for (int kc = 0; kc < KS; kc += KSC) {
        // hoist the entire K-chunk of A: ZR*KSC independent HBM loads in flight
        v8s aReg[ZR][KSC];
#pragma unroll
        for (int zr = 0; zr < ZR; ++zr)
#pragma unroll
            for (int ks = 0; ks < KSC; ++ks)
                aReg[zr][ks] = *(const v8s*)(aBase + (size_t)zr * 16 * Kp + (kc + ks) * 32);
#pragma unroll
        for (int nf = 0; nf < NF; ++nf) {
            v8s wr[KSC];
#pragma unroll
            for (int ks = 0; ks < KSC; ++ks)
                wr[ks] = *(const v8s*)(wBase + (size_t)nf * 16 * Kp + (kc + ks) * 32);
#pragma unroll
            for (int ks = 0; ks < KSC; ++ks)
#pragma unroll
                for (int zr = 0; zr < ZR; ++zr)
                    acc[zr][nf] = __builtin_amdgcn_mfma_f32_16x16x32_bf16(
                        wr[ks], aReg[zr][ks], acc[zr][nf], 0, 0, 0);
        }
    }
#pragma unroll
    for (int zr = 0; zr < ZR; ++zr) {
        const long m = row0 + zr * 16 + m15;
#pragma unroll
        for (int nf = 0; nf < NF; ++nf) {
            f32x4 b4 = *(const f32x4*)(bp + n0 + nf * 16 + q * 4);
            f32x4 c = acc[zr][nf];
            float v0 = fmaxf(c[0] + b4[0], 0.f), v1 = fmaxf(c[1] + b4[1], 0.f);
            float v2 = fmaxf(c[2] + b4[2], 0.f), v3 = fmaxf(c[3] + b4[3], 0.f);
            if (!FLAT) {
                ushort4 o; o.x = f2bf(v0); o.y = f2bf(v1); o.z = f2bf(v2); o.w = f2bf(v3);
                *(ushort4*)(Hout + (size_t)m * Np + n0 + nf * 16 + q * 4) = o;
            } else {
                const int n0f = nf * 16 + q * 4;   // FLAT only used with NSPLIT=1
                if (n0f <= 48) {
                    const long s = m / 20; const int u = (int)(m - s * 20);
                    unsigned short* base = Hout + (size_t)s * 1024 + u * 50 + n0f;
                    unsigned int lo = (unsigned int)f2bf(v0) | ((unsigned int)f2bf(v1) << 16);
                    *(unsigned int*)(base) = lo;
                    if (n0f < 48) {
                        unsigned int hi = (unsigned int)f2bf(v2) | ((unsigned int)f2bf(v3) << 16);
                        *(unsigned int*)(base + 2) = hi;
                    }
                }
            }
        }
    }
}

// logits = W5 h4 + b5; softmax -> out. h4 in g_bufA (112-padded rows).
__global__ __launch_bounds__(256)
void head_kernel(const float* __restrict__ W5, const float* __restrict__ b5,
                 float* __restrict__ out) {
    __shared__ float w5s[300];
    __shared__ float b5s[3];
    const int t = threadIdx.x;
    for (int i = t; i < 300; i += 256) w5s[i] = W5[i];
    if (t < 3) b5s[t] = b5[t];
    __syncthreads();
    const int s = blockIdx.x * 256 + t;
    const unsigned short* h = g_bufA + (size_t)s * 112;
    float a0 = b5s[0], a1 = b5s[1], a2 = b5s[2];
    for (int k = 0; k < 100; ++k) {
        float hv = bf2f(h[k]);
        a0 += hv * w5s[k]; a1 += hv * w5s[100 + k]; a2 += hv * w5s[200 + k];
    }
    float m = fmaxf(a0, fmaxf(a1, a2));
    float e0 = expf(a0 - m), e1 = expf(a1 - m), e2 = expf(a2 - m);
    float inv = 1.f / (e0 + e1 + e2);
    out[(size_t)s * 3 + 0] = e0 * inv;
    out[(size_t)s * 3 + 1] = e1 * inv;
    out[(size_t)s * 3 + 2] = e2 * inv;
}

extern "C" void kernel_launch(void* const* d_in, const int* in_sizes, int n_in,
                              void* d_out, int out_size, void* d_ws, size_t ws_size,
                              hipStream_t stream) {
    const float* x  = (const float*)d_in[0];
    const float* W1 = (const float*)d_in[1];
    const float* b1 = (const float*)d_in[2];
    const float* W2 = (const float*)d_in[3];
    const float* b2 = (const float*)d_in[4];
    const float* W3 = (const float*)d_in[5];
    const float* b3 = (const float*)d_in[6];
    const float* W4 = (const float*)d_in[7];
    const float* b4 = (const float*)d_in[8];
    const float* W5 = (const float*)d_in[9];
    const float* b5 = (const float*)d_in[10];
    float* out = (float*)d_out;

    zero_C_kernel<<<3, P * P, 0, stream>>>();
    prep_kernel<<<256, 256, 0, stream>>>(W1, b1, W2, b2, W3, b3, W4, b4);

    knn1_mfma_kernel<<<BB / 16, NT, 0, stream>>>(x);                 // x -> C0
    agg_kernel<128, true, 0, 4><<<1024, 256, 0, stream>>>(x);        // x -> z1(A)
    // z1 (84MB) is L3-resident -> NSPLIT=2 ok. 8 hoisted A loads, acc=80.
    gemm_kernel<128, 320, 2, false, 1, true, 2, 4>
        <<<dim3(2560, 2), 256, 0, stream>>>();                       // z1 -> h1(B)

    knn_mfma_kernel<320, 1><<<BB / 16, NT, 0, stream>>>();           // h1 -> C1
    agg_kernel<320, false, 1, 2><<<1024, 256, 0, stream>>>(nullptr); // h1 -> z2(A)
    // z2 (210MB, NOT L3-resident) -> single pass. 20 hoisted A loads, acc=64.
    gemm_kernel<320, 128, 2, false, 2, true, 1, 10>
        <<<dim3(2560, 1), 256, 0, stream>>>();                       // z2 -> h2(B)

    knn_mfma_kernel<128, 2><<<BB / 16, NT, 0, stream>>>();           // h2 -> C2
    agg_kernel<128, false, 2, 4><<<1024, 256, 0, stream>>>(nullptr); // h2 -> z3(A)
    // ZR 4->2 (acc 32, light), 8 hoisted loads.
    gemm_kernel<128, 64, 2, true, 3, true, 1, 4>
        <<<dim3(2560, 1), 256, 0, stream>>>();                       // z3 -> h3f(B)

    // h3f (33MB) L3-resident -> NSPLIT=7 ok; K chunked by 8 (8 hoisted loads).
    gemm_kernel<1024, 112, 1, false, 4, false, 7, 8>
        <<<dim3(256, 7), 256, 0, stream>>>();                        // h3f -> h4(A)
    head_kernel<<<BB / 256, 256, 0, stream>>>(W5, b5, out);
}

// Round 4
// 1173.542 us; speedup vs baseline: 1.0786x; 1.0337x over previous
//
#include <hip/hip_runtime.h>
#include <math.h>

#define BB 16384
#define P 20
#define NT 512

typedef short v8s __attribute__((ext_vector_type(8)));
typedef _Float16 v8h __attribute__((ext_vector_type(8)));
typedef float f32x4 __attribute__((ext_vector_type(4)));
typedef float f32x16 __attribute__((ext_vector_type(16)));

// ---- static device buffers: referenced ONLY inside device code (never passed
// as kernel args from host — that passes the host shadow and faults). ----
// +4096 pad: knn_mfma reads rows m=20..31 of the last samples (garbage, unused).
#define NELEM ((size_t)BB * P * 320)          // 209.7 MB each
__device__ unsigned int g_C[3][P * P];
__device__ __align__(16) unsigned short g_bufA[NELEM + 4096];  // z1 / z2 / z3 / h4
__device__ __align__(16) unsigned short g_bufB[NELEM + 4096];  // h1 / h2 / h3f
__device__ __align__(16) unsigned short g_W1b[320 * 128];
__device__ __align__(16) unsigned short g_W2b[128 * 320];
__device__ __align__(16) unsigned short g_W3b[64 * 128];
__device__ __align__(16) unsigned short g_W4b[112 * 1024];
__device__ __align__(16) float g_b1p[320];
__device__ __align__(16) float g_b2p[128];
__device__ __align__(16) float g_b3p[64];
__device__ __align__(16) float g_b4p[112];

__device__ inline float bf2f(unsigned short u) {
    union { unsigned int i; float f; } c; c.i = ((unsigned int)u) << 16; return c.f;
}
__device__ inline unsigned short f2bf(float f) {
    union { float f; unsigned int i; } c; c.f = f;
    unsigned int u = c.i + 0x7fffu + ((c.i >> 16) & 1u);  // RNE (no NaN in data)
    return (unsigned short)(u >> 16);
}

__global__ void zero_C_kernel() { g_C[blockIdx.x][threadIdx.x] = 0u; }

// Pad+convert weights/biases to bf16 (zero pads -> pad outputs relu(0+0)=0).
__global__ void prep_kernel(const float* __restrict__ W1, const float* __restrict__ b1,
                            const float* __restrict__ W2, const float* __restrict__ b2,
                            const float* __restrict__ W3, const float* __restrict__ b3,
                            const float* __restrict__ W4, const float* __restrict__ b4) {
    const int stride = gridDim.x * blockDim.x;
    const int id = blockIdx.x * blockDim.x + threadIdx.x;
    for (int i = id; i < 320 * 128; i += stride) { int n = i >> 7, k = i & 127;
        g_W1b[i] = (n < 300) ? f2bf(W1[n * 128 + k]) : 0; }
    for (int i = id; i < 128 * 320; i += stride) { int n = i / 320, k = i - n * 320;
        g_W2b[i] = (n < 100 && k < 300) ? f2bf(W2[n * 300 + k]) : 0; }
    for (int i = id; i < 64 * 128; i += stride) { int n = i >> 7, k = i & 127;
        g_W3b[i] = (n < 50 && k < 100) ? f2bf(W3[n * 100 + k]) : 0; }
    for (int i = id; i < 112 * 1024; i += stride) { int n = i >> 10, k = i & 1023;
        g_W4b[i] = (n < 100 && k < 1000) ? f2bf(W4[n * 1000 + k]) : 0; }
    for (int i = id; i < 320; i += stride) g_b1p[i] = (i < 300) ? b1[i] : 0.f;
    for (int i = id; i < 128; i += stride) g_b2p[i] = (i < 100) ? b2[i] : 0.f;
    for (int i = id; i < 64;  i += stride) g_b3p[i] = (i < 50)  ? b3[i] : 0.f;
    for (int i = id; i < 112; i += stride) g_b4p[i] = (i < 100) ? b4[i] : 0.f;
}

// ---------------- kNN layer 1: MFMA Gram on fp16 hi/lo split (verified r8) --
__global__ __launch_bounds__(NT)
void knn1_mfma_kernel(const float* __restrict__ x) {
    __shared__ float Gs[8][P * 21];
    __shared__ unsigned int hist[P * P];
    const int t = threadIdx.x, w = t >> 6, lane = t & 63;
    const int m31 = lane & 31, half = lane >> 5;
    // Rows 20..31 are MFMA padding; clamp the load to row 19 (x has no tail
    // pad and is an exact page multiple — an unclamped read walks off the
    // allocation for the last sample). Clamped rows are never stored.
    const int mrow = (m31 < P) ? m31 : (P - 1);
    for (int i = t; i < P * P; i += NT) hist[i] = 0;
    for (int pass = 0; pass < 2; ++pass) {
        const size_t s = (size_t)blockIdx.x * 16 + pass * 8 + w;
        const float* rp = x + s * (size_t)(P * 128) + (size_t)mrow * 128 + half * 8;
        f32x16 acc;
#pragma unroll
        for (int i = 0; i < 16; ++i) acc[i] = 0.f;
#pragma unroll
        for (int ks = 0; ks < 8; ++ks) {
            float4 f0 = *(const float4*)(rp + ks * 16);
            float4 f1 = *(const float4*)(rp + ks * 16 + 4);
            float fv[8] = {f0.x, f0.y, f0.z, f0.w, f1.x, f1.y, f1.z, f1.w};
            v8h hi, lo;
#pragma unroll
            for (int j = 0; j < 8; ++j) {
                _Float16 hv = (_Float16)fv[j];
                hi[j] = hv;
                lo[j] = (_Float16)(fv[j] - (float)hv);
            }
            acc = __builtin_amdgcn_mfma_f32_32x32x16_f16(hi, hi, acc, 0, 0, 0);
            acc = __builtin_amdgcn_mfma_f32_32x32x16_f16(hi, lo, acc, 0, 0, 0);
            acc = __builtin_amdgcn_mfma_f32_32x32x16_f16(lo, hi, acc, 0, 0, 0);
            acc = __builtin_amdgcn_mfma_f32_32x32x16_f16(lo, lo, acc, 0, 0, 0);
        }
        float* G = &Gs[w][0];
        if (m31 < P) {
#pragma unroll
            for (int r = 0; r < 16; ++r) {
                int row = (r & 3) + 8 * (r >> 2) + 4 * half;
                if (row < P) G[row * 21 + m31] = acc[r];
            }
        }
        __syncthreads();
        if (lane < P) {
            const int p = lane;
            float d2[P];
            const float gpp = G[p * 21 + p];
#pragma unroll
            for (int u = 0; u < P; ++u)
                d2[u] = (u == p) ? 0.f : gpp + G[u * 21 + u] - 2.f * G[p * 21 + u];
            float pv = -3.0e38f; int pi = -1;
            for (int it = 0; it < 6; ++it) {
                float best = 3.0e38f; int bq = 0;
#pragma unroll
                for (int u = 0; u < P; ++u) {
                    float vu = d2[u];
                    bool cand = (vu > pv) || (vu == pv && u > pi);
                    if (cand && vu < best) { best = vu; bq = u; }
                }
                if (it > 0) atomicAdd(&hist[bq * P + p], 1u);
                pv = best; pi = bq;
            }
        }
        __syncthreads();
    }
    if (t < P * P && hist[t]) atomicAdd(&g_C[0][t], hist[t]);
}

// ---------------- kNN via MFMA Gram: G = Z Z^T per sample (verified r6) -----
template<int D, int CIDX>
__global__ __launch_bounds__(NT)
void knn_mfma_kernel() {
    __shared__ float Gs[8][P * 21];
    __shared__ unsigned int hist[P * P];
    const int t = threadIdx.x, w = t >> 6, lane = t & 63;
    const int m31 = lane & 31, half = lane >> 5;
    for (int i = t; i < P * P; i += NT) hist[i] = 0;
    for (int pass = 0; pass < 2; ++pass) {
        const size_t s = (size_t)blockIdx.x * 16 + pass * 8 + w;
        const unsigned short* rp = g_bufB + s * (P * D) + (size_t)m31 * D + half * 8;
        f32x16 acc;
#pragma unroll
        for (int i = 0; i < 16; ++i) acc[i] = 0.f;
        for (int ks = 0; ks < D / 16; ++ks) {
            v8s z = *(const v8s*)(rp + ks * 16);
            acc = __builtin_amdgcn_mfma_f32_32x32x16_bf16(z, z, acc, 0, 0, 0);
        }
        float* G = &Gs[w][0];
        if (m31 < P) {
#pragma unroll
            for (int r = 0; r < 16; ++r) {
                int row = (r & 3) + 8 * (r >> 2) + 4 * half;
                if (row < P) G[row * 21 + m31] = acc[r];
            }
        }
        __syncthreads();
        if (lane < P) {
            const int p = lane;
            float d2[P];
            const float gpp = G[p * 21 + p];
#pragma unroll
            for (int u = 0; u < P; ++u)
                d2[u] = (u == p) ? 0.f : gpp + G[u * 21 + u] - 2.f * G[p * 21 + u];
            float pv = -3.0e38f; int pi = -1;
            for (int it = 0; it < 6; ++it) {
                float best = 3.0e38f; int bq = 0;
#pragma unroll
                for (int u = 0; u < P; ++u) {
                    float vu = d2[u];
                    bool cand = (vu > pv) || (vu == pv && u > pi);
                    if (cand && vu < best) { best = vu; bq = u; }
                }
                if (it > 0) atomicAdd(&hist[bq * P + p], 1u);
                pv = best; pi = bq;
            }
        }
        __syncthreads();
    }
    if (t < P * P && hist[t]) atomicAdd(&g_C[CIDX][t], hist[t]);
}

// compute_M for 256-thread blocks (strided loops)
__device__ inline void compute_M_256(const unsigned int* __restrict__ Cg,
                                     float* Ms, float* dinv, int t) {
    for (int i = t; i < P * P; i += 256) Ms[i] = (float)Cg[i];
    __syncthreads();
    if (t < P) {
        float deg = 1.f;
        for (int u = 0; u < P; ++u) deg += Ms[t * P + u];
        dinv[t] = 1.f / sqrtf(deg);
    }
    __syncthreads();
    for (int i = t; i < P * P; i += 256) {
        int v = i / P, u = i - v * P;
        float m = dinv[v] * Ms[i] * dinv[u];
        if (v == u) m += dinv[v] * dinv[v];
        Ms[i] = m;
    }
    __syncthreads();
}

// ---------------- agg: LDS-staged, vectorized (round-7 rewrite) -------------
template<int D, bool INF32, int CIDX, int SAMP>
__global__ __launch_bounds__(256)
void agg_kernel(const float* __restrict__ xin) {
    __shared__ float Ms[P * P];
    __shared__ float dinv[P];
    __shared__ __align__(16) float hsf[SAMP][P][D];
    const int t = threadIdx.x;
    compute_M_256(g_C[CIDX], Ms, dinv, t);
    constexpr int C4 = D / 4;               // float4 chunks per row
    for (long s0 = (long)blockIdx.x * SAMP; s0 < BB; s0 += (long)gridDim.x * SAMP) {
        __syncthreads();                    // hsf reuse guard
        if (INF32) {
            const float4* src = (const float4*)(xin + s0 * (P * D));
            for (int i = t; i < SAMP * P * C4; i += 256) {
                float4 v = src[i];
                int r = i / C4, c = i - r * C4;
                *(float4*)&hsf[r / P][r % P][c * 4] = v;
            }
        } else {
            const ushort4* src = (const ushort4*)(g_bufB + s0 * (P * D));
            for (int i = t; i < SAMP * P * C4; i += 256) {
                ushort4 u = src[i];
                int r = i / C4, c = i - r * C4;
                float4 f; f.x = bf2f(u.x); f.y = bf2f(u.y);
                f.z = bf2f(u.z); f.w = bf2f(u.w);
                *(float4*)&hsf[r / P][r % P][c * 4] = f;
            }
        }
        __syncthreads();
        // items: (smp, vg of 4 v's, c4). 5 v-groups per sample.
        for (int i = t; i < SAMP * 5 * C4; i += 256) {
            const int c4 = i % C4;
            const int g = i / C4;
            const int smp = g / 5, v0 = (g - smp * 5) * 4;
            float4 a0 = {0,0,0,0}, a1 = {0,0,0,0}, a2 = {0,0,0,0}, a3 = {0,0,0,0};
#pragma unroll
            for (int u = 0; u < P; ++u) {
                float4 h = *(const float4*)&hsf[smp][u][c4 * 4];
                float m0 = Ms[(v0 + 0) * P + u], m1 = Ms[(v0 + 1) * P + u];
                float m2 = Ms[(v0 + 2) * P + u], m3 = Ms[(v0 + 3) * P + u];
                a0.x += m0*h.x; a0.y += m0*h.y; a0.z += m0*h.z; a0.w += m0*h.w;
                a1.x += m1*h.x; a1.y += m1*h.y; a1.z += m1*h.z; a1.w += m1*h.w;
                a2.x += m2*h.x; a2.y += m2*h.y; a2.z += m2*h.z; a2.w += m2*h.w;
                a3.x += m3*h.x; a3.y += m3*h.y; a3.z += m3*h.z; a3.w += m3*h.w;
            }
            unsigned short* zb = g_bufA + (s0 + smp) * (size_t)(P * D) + c4 * 4;
            ushort4 o;
            o.x = f2bf(a0.x); o.y = f2bf(a0.y); o.z = f2bf(a0.z); o.w = f2bf(a0.w);
            *(ushort4*)(zb + (size_t)(v0 + 0) * D) = o;
            o.x = f2bf(a1.x); o.y = f2bf(a1.y); o.z = f2bf(a1.z); o.w = f2bf(a1.w);
            *(ushort4*)(zb + (size_t)(v0 + 1) * D) = o;
            o.x = f2bf(a2.x); o.y = f2bf(a2.y); o.z = f2bf(a2.z); o.w = f2bf(a2.w);
            *(ushort4*)(zb + (size_t)(v0 + 2) * D) = o;
            o.x = f2bf(a3.x); o.y = f2bf(a3.y); o.z = f2bf(a3.z); o.w = f2bf(a3.w);
            *(ushort4*)(zb + (size_t)(v0 + 3) * D) = o;
        }
    }
}

// ---------------- streaming MFMA GEMM, round-11: W-in-LDS + persistent ------
// Round-3 lesson: A-loads were batched but W-loads formed a serial L2-latency
// chain (4 loads -> ~220cy wait -> 40cy MFMA, x10 per chunk) -> MfmaUtil ==
// FLOP floor, 1.6 TB/s. Fix: (1) stage the block's W-slice in LDS ONCE
// (+8-elem row pad -> 2-way ds_read conflicts = free), inner loop becomes
// ds_read+MFMA, fully lgkmcnt-pipelined; (2) persistent grid-stride blocks;
// (3) next tile/chunk's A-fragments issued BEFORE current MFMA phase (~8-10
// independent 1KB loads/wave in flight -> HBM latency hidden). Per-output
// accumulation order (ascending ks) unchanged -> bit-exact vs r1-r3.
template<int Kp, int Np, int ZR, bool FLAT, int WSEL, bool ATOB, int NSPLIT,
         int KSC, int NTHR, long MROWS>
__global__ __launch_bounds__(NTHR)
void gemm_kernel() {
    constexpr int BN = Np / NSPLIT;          // cols handled by this block
    constexpr int NF = BN / 16;
    constexpr int KS = Kp / 32;
    constexpr int CPT = KS / KSC;            // chunks per tile
    constexpr int KL = Kp + 8;               // padded LDS row (elems, 16B step)
    constexpr int NW = NTHR / 64;
    constexpr int TM = NW * ZR * 16;         // rows per tile
    constexpr long NTILE = MROWS / TM;
    static_assert(KS % KSC == 0, "KSC must divide KS");
    __shared__ __align__(16) unsigned short Ws[BN * KL];
    __shared__ __align__(16) float bs[BN];
    const unsigned short* __restrict__ Wb =
        (WSEL == 1) ? g_W1b : (WSEL == 2) ? g_W2b : (WSEL == 3) ? g_W3b : g_W4b;
    const float* __restrict__ bp =
        (WSEL == 1) ? g_b1p : (WSEL == 2) ? g_b2p : (WSEL == 3) ? g_b3p : g_b4p;
    const unsigned short* __restrict__ A = ATOB ? g_bufA : g_bufB;
    unsigned short* __restrict__ Hout = ATOB ? g_bufB : g_bufA;
    const int t = threadIdx.x, w = t >> 6, lane = t & 63;
    const int m15 = lane & 15, q = lane >> 4;
    const int n0 = blockIdx.y * BN;
    // ---- stage W slice + bias to LDS (once per block) ----
    for (int i = t; i < BN * (Kp / 8); i += NTHR) {
        int r = i / (Kp / 8), c = i - r * (Kp / 8);
        *(v8s*)(&Ws[r * KL + c * 8]) = *(const v8s*)(Wb + (size_t)(n0 + r) * Kp + c * 8);
    }
    for (int i = t; i < BN; i += NTHR) bs[i] = bp[n0 + i];
    __syncthreads();

    v8s aC[ZR][KSC], aN[ZR][KSC];
    long tile = (long)blockIdx.x;
    if (tile < NTILE) {
        const unsigned short* ab =
            A + (size_t)(tile * TM + w * (ZR * 16) + m15) * Kp + q * 8;
#pragma unroll
        for (int zr = 0; zr < ZR; ++zr)
#pragma unroll
            for (int ks = 0; ks < KSC; ++ks)
                aC[zr][ks] = *(const v8s*)(ab + (size_t)zr * 16 * Kp + ks * 32);
    }
    for (; tile < NTILE; tile += gridDim.x) {
        f32x4 acc[ZR][NF];
#pragma unroll
        for (int zr = 0; zr < ZR; ++zr)
#pragma unroll
            for (int nf = 0; nf < NF; ++nf) acc[zr][nf] = 0.f;
        for (int c = 0; c < CPT; ++c) {
            // issue next chunk's A loads before consuming the current chunk
            const long ntile = (c + 1 < CPT) ? tile : tile + (long)gridDim.x;
            const int nk0 = (c + 1 < CPT) ? (c + 1) * KSC : 0;
            const bool hasNext = (ntile < NTILE);
            if (hasNext) {
                const unsigned short* ab =
                    A + (size_t)(ntile * TM + w * (ZR * 16) + m15) * Kp + nk0 * 32 + q * 8;
#pragma unroll
                for (int zr = 0; zr < ZR; ++zr)
#pragma unroll
                    for (int ks = 0; ks < KSC; ++ks)
                        aN[zr][ks] = *(const v8s*)(ab + (size_t)zr * 16 * Kp + ks * 32);
            }
#pragma unroll
            for (int nf = 0; nf < NF; ++nf) {
                v8s wr[KSC];
#pragma unroll
                for (int ks = 0; ks < KSC; ++ks)
                    wr[ks] = *(const v8s*)(&Ws[(nf * 16 + m15) * KL + (c * KSC + ks) * 32 + q * 8]);
#pragma unroll
                for (int ks = 0; ks < KSC; ++ks)
#pragma unroll
                    for (int zr = 0; zr < ZR; ++zr)
                        acc[zr][nf] = __builtin_amdgcn_mfma_f32_16x16x32_bf16(
                            wr[ks], aC[zr][ks], acc[zr][nf], 0, 0, 0);
            }
            if (hasNext) {
#pragma unroll
                for (int zr = 0; zr < ZR; ++zr)
#pragma unroll
                    for (int ks = 0; ks < KSC; ++ks) aC[zr][ks] = aN[zr][ks];
            }
        }
        // ---- epilogue: bias + relu + store ----
#pragma unroll
        for (int zr = 0; zr < ZR; ++zr) {
            const long m = tile * TM + w * (ZR * 16) + zr * 16 + m15;
#pragma unroll
            for (int nf = 0; nf < NF; ++nf) {
                f32x4 b4 = *(const f32x4*)(&bs[nf * 16 + q * 4]);
                f32x4 cc = acc[zr][nf];
                float v0 = fmaxf(cc[0] + b4[0], 0.f), v1 = fmaxf(cc[1] + b4[1], 0.f);
                float v2 = fmaxf(cc[2] + b4[2], 0.f), v3 = fmaxf(cc[3] + b4[3], 0.f);
                if (!FLAT) {
                    ushort4 o; o.x = f2bf(v0); o.y = f2bf(v1); o.z = f2bf(v2); o.w = f2bf(v3);
                    *(ushort4*)(Hout + (size_t)m * Np + n0 + nf * 16 + q * 4) = o;
                } else {
                    const int n0f = nf * 16 + q * 4;   // FLAT only with NSPLIT=1
                    if (n0f <= 48) {
                        const long s = m / 20; const int u = (int)(m - s * 20);
                        unsigned short* base = Hout + (size_t)s * 1024 + u * 50 + n0f;
                        unsigned int lo = (unsigned int)f2bf(v0) | ((unsigned int)f2bf(v1) << 16);
                        *(unsigned int*)(base) = lo;
                        if (n0f < 48) {
                            unsigned int hi = (unsigned int)f2bf(v2) | ((unsigned int)f2bf(v3) << 16);
                            *(unsigned int*)(base + 2) = hi;
                        }
                    }
                }
            }
        }
    }
}

// logits = W5 h4 + b5; softmax -> out. h4 in g_bufA (112-padded rows).
__global__ __launch_bounds__(256)
void head_kernel(const float* __restrict__ W5, const float* __restrict__ b5,
                 float* __restrict__ out) {
    __shared__ float w5s[300];
    __shared__ float b5s[3];
    const int t = threadIdx.x;
    for (int i = t; i < 300; i += 256) w5s[i] = W5[i];
    if (t < 3) b5s[t] = b5[t];
    __syncthreads();
    const int s = blockIdx.x * 256 + t;
    const unsigned short* h = g_bufA + (size_t)s * 112;
    float a0 = b5s[0], a1 = b5s[1], a2 = b5s[2];
    for (int k = 0; k < 100; ++k) {
        float hv = bf2f(h[k]);
        a0 += hv * w5s[k]; a1 += hv * w5s[100 + k]; a2 += hv * w5s[200 + k];
    }
    float m = fmaxf(a0, fmaxf(a1, a2));
    float e0 = expf(a0 - m), e1 = expf(a1 - m), e2 = expf(a2 - m);
    float inv = 1.f / (e0 + e1 + e2);
    out[(size_t)s * 3 + 0] = e0 * inv;
    out[(size_t)s * 3 + 1] = e1 * inv;
    out[(size_t)s * 3 + 2] = e2 * inv;
}

extern "C" void kernel_launch(void* const* d_in, const int* in_sizes, int n_in,
                              void* d_out, int out_size, void* d_ws, size_t ws_size,
                              hipStream_t stream) {
    const float* x  = (const float*)d_in[0];
    const float* W1 = (const float*)d_in[1];
    const float* b1 = (const float*)d_in[2];
    const float* W2 = (const float*)d_in[3];
    const float* b2 = (const float*)d_in[4];
    const float* W3 = (const float*)d_in[5];
    const float* b3 = (const float*)d_in[6];
    const float* W4 = (const float*)d_in[7];
    const float* b4 = (const float*)d_in[8];
    const float* W5 = (const float*)d_in[9];
    const float* b5 = (const float*)d_in[10];
    float* out = (float*)d_out;

    zero_C_kernel<<<3, P * P, 0, stream>>>();
    prep_kernel<<<256, 256, 0, stream>>>(W1, b1, W2, b2, W3, b3, W4, b4);

    knn1_mfma_kernel<<<BB / 16, NT, 0, stream>>>(x);                 // x -> C0
    agg_kernel<128, true, 0, 4><<<1024, 256, 0, stream>>>(x);        // x -> z1(A)
    // W slice 160x136 bf16 in LDS (42.5KB); NSPLIT=2 (z1 84MB, L3-resident);
    // 512 blocks x 5 tiles, full-K hoist (KSC=KS=4) + cross-tile prefetch.
    gemm_kernel<128, 320, 2, false, 1, true, 2, 4, 256, 327680L>
        <<<dim3(512, 2), 256, 0, stream>>>();                        // z1 -> h1(B)

    knn_mfma_kernel<320, 1><<<BB / 16, NT, 0, stream>>>();           // h1 -> C1
    agg_kernel<320, false, 1, 2><<<1024, 256, 0, stream>>>(nullptr); // h1 -> z2(A)
    // W2 full 128x328 bf16 in LDS (84KB, 1 block/CU); 512-thr blocks, ZR=1;
    // z2 (210MB) single pass; 10 hoisted A loads + cross-tile prefetch.
    gemm_kernel<320, 128, 1, false, 2, true, 1, 10, 512, 327680L>
        <<<dim3(256, 1), 512, 0, stream>>>();                        // z2 -> h2(B)

    knn_mfma_kernel<128, 2><<<BB / 16, NT, 0, stream>>>();           // h2 -> C2
    agg_kernel<128, false, 2, 4><<<1024, 256, 0, stream>>>(nullptr); // h2 -> z3(A)
    gemm_kernel<128, 64, 2, true, 3, true, 1, 4, 256, 327680L>
        <<<dim3(512, 1), 256, 0, stream>>>();                        // z3 -> h3f(B)

    // NSPLIT=7 (h3f 33MB L3-resident); W slice 16x1032 (33KB); chunked K.
    gemm_kernel<1024, 112, 1, false, 4, false, 7, 8, 256, 16384L>
        <<<dim3(256, 7), 256, 0, stream>>>();                        // h3f -> h4(A)
    head_kernel<<<BB / 256, 256, 0, stream>>>(W5, b5, out);
}

// Round 5
// 1079.841 us; speedup vs baseline: 1.1722x; 1.0868x over previous
//
#include <hip/hip_runtime.h>
#include <math.h>

#define BB 16384
#define P 20
#define NT 512

typedef short v8s __attribute__((ext_vector_type(8)));
typedef _Float16 v8h __attribute__((ext_vector_type(8)));
typedef float f32x4 __attribute__((ext_vector_type(4)));
typedef float f32x16 __attribute__((ext_vector_type(16)));

// ---- static device buffers: referenced ONLY inside device code (never passed
// as kernel args from host — that passes the host shadow and faults). ----
// +4096 pad: knn_mfma reads rows m=20..31 of the last samples (garbage, unused).
#define NELEM ((size_t)BB * P * 320)          // 209.7 MB each
__device__ unsigned int g_C[3][P * P];
__device__ __align__(16) unsigned short g_bufA[NELEM + 4096];  // z1 / z2 / z3 / h4
__device__ __align__(16) unsigned short g_bufB[NELEM + 4096];  // h1 / h2 / h3f
__device__ __align__(16) unsigned short g_W1b[320 * 128];
__device__ __align__(16) unsigned short g_W2b[128 * 320];
__device__ __align__(16) unsigned short g_W3b[64 * 128];
__device__ __align__(16) unsigned short g_W4b[112 * 1024];
__device__ __align__(16) float g_b1p[320];
__device__ __align__(16) float g_b2p[128];
__device__ __align__(16) float g_b3p[64];
__device__ __align__(16) float g_b4p[112];

__device__ inline float bf2f(unsigned short u) {
    union { unsigned int i; float f; } c; c.i = ((unsigned int)u) << 16; return c.f;
}
__device__ inline unsigned short f2bf(float f) {
    union { float f; unsigned int i; } c; c.f = f;
    unsigned int u = c.i + 0x7fffu + ((c.i >> 16) & 1u);  // RNE (no NaN in data)
    return (unsigned short)(u >> 16);
}

__global__ void zero_C_kernel() { g_C[blockIdx.x][threadIdx.x] = 0u; }

// Pad+convert weights/biases to bf16 (zero pads -> pad outputs relu(0+0)=0).
__global__ void prep_kernel(const float* __restrict__ W1, const float* __restrict__ b1,
                            const float* __restrict__ W2, const float* __restrict__ b2,
                            const float* __restrict__ W3, const float* __restrict__ b3,
                            const float* __restrict__ W4, const float* __restrict__ b4) {
    const int stride = gridDim.x * blockDim.x;
    const int id = blockIdx.x * blockDim.x + threadIdx.x;
    for (int i = id; i < 320 * 128; i += stride) { int n = i >> 7, k = i & 127;
        g_W1b[i] = (n < 300) ? f2bf(W1[n * 128 + k]) : 0; }
    for (int i = id; i < 128 * 320; i += stride) { int n = i / 320, k = i - n * 320;
        g_W2b[i] = (n < 100 && k < 300) ? f2bf(W2[n * 300 + k]) : 0; }
    for (int i = id; i < 64 * 128; i += stride) { int n = i >> 7, k = i & 127;
        g_W3b[i] = (n < 50 && k < 100) ? f2bf(W3[n * 100 + k]) : 0; }
    for (int i = id; i < 112 * 1024; i += stride) { int n = i >> 10, k = i & 1023;
        g_W4b[i] = (n < 100 && k < 1000) ? f2bf(W4[n * 1000 + k]) : 0; }
    for (int i = id; i < 320; i += stride) g_b1p[i] = (i < 300) ? b1[i] : 0.f;
    for (int i = id; i < 128; i += stride) g_b2p[i] = (i < 100) ? b2[i] : 0.f;
    for (int i = id; i < 64;  i += stride) g_b3p[i] = (i < 50)  ? b3[i] : 0.f;
    for (int i = id; i < 112; i += stride) g_b4p[i] = (i < 100) ? b4[i] : 0.f;
}

// ---------------- kNN layer 1: MFMA Gram on fp16 hi/lo split (verified r8) --
__global__ __launch_bounds__(NT)
void knn1_mfma_kernel(const float* __restrict__ x) {
    __shared__ float Gs[8][P * 21];
    __shared__ unsigned int hist[P * P];
    const int t = threadIdx.x, w = t >> 6, lane = t & 63;
    const int m31 = lane & 31, half = lane >> 5;
    // Rows 20..31 are MFMA padding; clamp the load to row 19 (x has no tail
    // pad and is an exact page multiple — an unclamped read walks off the
    // allocation for the last sample). Clamped rows are never stored.
    const int mrow = (m31 < P) ? m31 : (P - 1);
    for (int i = t; i < P * P; i += NT) hist[i] = 0;
    for (int pass = 0; pass < 2; ++pass) {
        const size_t s = (size_t)blockIdx.x * 16 + pass * 8 + w;
        const float* rp = x + s * (size_t)(P * 128) + (size_t)mrow * 128 + half * 8;
        f32x16 acc;
#pragma unroll
        for (int i = 0; i < 16; ++i) acc[i] = 0.f;
#pragma unroll
        for (int ks = 0; ks < 8; ++ks) {
            float4 f0 = *(const float4*)(rp + ks * 16);
            float4 f1 = *(const float4*)(rp + ks * 16 + 4);
            float fv[8] = {f0.x, f0.y, f0.z, f0.w, f1.x, f1.y, f1.z, f1.w};
            v8h hi, lo;
#pragma unroll
            for (int j = 0; j < 8; ++j) {
                _Float16 hv = (_Float16)fv[j];
                hi[j] = hv;
                lo[j] = (_Float16)(fv[j] - (float)hv);
            }
            acc = __builtin_amdgcn_mfma_f32_32x32x16_f16(hi, hi, acc, 0, 0, 0);
            acc = __builtin_amdgcn_mfma_f32_32x32x16_f16(hi, lo, acc, 0, 0, 0);
            acc = __builtin_amdgcn_mfma_f32_32x32x16_f16(lo, hi, acc, 0, 0, 0);
            acc = __builtin_amdgcn_mfma_f32_32x32x16_f16(lo, lo, acc, 0, 0, 0);
        }
        float* G = &Gs[w][0];
        if (m31 < P) {
#pragma unroll
            for (int r = 0; r < 16; ++r) {
                int row = (r & 3) + 8 * (r >> 2) + 4 * half;
                if (row < P) G[row * 21 + m31] = acc[r];
            }
        }
        __syncthreads();
        if (lane < P) {
            const int p = lane;
            float d2[P];
            const float gpp = G[p * 21 + p];
#pragma unroll
            for (int u = 0; u < P; ++u)
                d2[u] = (u == p) ? 0.f : gpp + G[u * 21 + u] - 2.f * G[p * 21 + u];
            float pv = -3.0e38f; int pi = -1;
            for (int it = 0; it < 6; ++it) {
                float best = 3.0e38f; int bq = 0;
#pragma unroll
                for (int u = 0; u < P; ++u) {
                    float vu = d2[u];
                    bool cand = (vu > pv) || (vu == pv && u > pi);
                    if (cand && vu < best) { best = vu; bq = u; }
                }
                if (it > 0) atomicAdd(&hist[bq * P + p], 1u);
                pv = best; pi = bq;
            }
        }
        __syncthreads();
    }
    if (t < P * P && hist[t]) atomicAdd(&g_C[0][t], hist[t]);
}

// ---------------- kNN via MFMA Gram: G = Z Z^T per sample (verified r6) -----
template<int D, int CIDX>
__global__ __launch_bounds__(NT)
void knn_mfma_kernel() {
    __shared__ float Gs[8][P * 21];
    __shared__ unsigned int hist[P * P];
    const int t = threadIdx.x, w = t >> 6, lane = t & 63;
    const int m31 = lane & 31, half = lane >> 5;
    for (int i = t; i < P * P; i += NT) hist[i] = 0;
    for (int pass = 0; pass < 2; ++pass) {
        const size_t s = (size_t)blockIdx.x * 16 + pass * 8 + w;
        const unsigned short* rp = g_bufB + s * (P * D) + (size_t)m31 * D + half * 8;
        f32x16 acc;
#pragma unroll
        for (int i = 0; i < 16; ++i) acc[i] = 0.f;
        for (int ks = 0; ks < D / 16; ++ks) {
            v8s z = *(const v8s*)(rp + ks * 16);
            acc = __builtin_amdgcn_mfma_f32_32x32x16_bf16(z, z, acc, 0, 0, 0);
        }
        float* G = &Gs[w][0];
        if (m31 < P) {
#pragma unroll
            for (int r = 0; r < 16; ++r) {
                int row = (r & 3) + 8 * (r >> 2) + 4 * half;
                if (row < P) G[row * 21 + m31] = acc[r];
            }
        }
        __syncthreads();
        if (lane < P) {
            const int p = lane;
            float d2[P];
            const float gpp = G[p * 21 + p];
#pragma unroll
            for (int u = 0; u < P; ++u)
                d2[u] = (u == p) ? 0.f : gpp + G[u * 21 + u] - 2.f * G[p * 21 + u];
            float pv = -3.0e38f; int pi = -1;
            for (int it = 0; it < 6; ++it) {
                float best = 3.0e38f; int bq = 0;
#pragma unroll
                for (int u = 0; u < P; ++u) {
                    float vu = d2[u];
                    bool cand = (vu > pv) || (vu == pv && u > pi);
                    if (cand && vu < best) { best = vu; bq = u; }
                }
                if (it > 0) atomicAdd(&hist[bq * P + p], 1u);
                pv = best; pi = bq;
            }
        }
        __syncthreads();
    }
    if (t < P * P && hist[t]) atomicAdd(&g_C[CIDX][t], hist[t]);
}

// compute_M for 256-thread blocks (strided loops)
__device__ inline void compute_M_256(const unsigned int* __restrict__ Cg,
                                     float* Ms, float* dinv, int t) {
    for (int i = t; i < P * P; i += 256) Ms[i] = (float)Cg[i];
    __syncthreads();
    if (t < P) {
        float deg = 1.f;
        for (int u = 0; u < P; ++u) deg += Ms[t * P + u];
        dinv[t] = 1.f / sqrtf(deg);
    }
    __syncthreads();
    for (int i = t; i < P * P; i += 256) {
        int v = i / P, u = i - v * P;
        float m = dinv[v] * Ms[i] * dinv[u];
        if (v == u) m += dinv[v] * dinv[v];
        Ms[i] = m;
    }
    __syncthreads();
}

// ---------------- agg: LDS-staged, vectorized (round-7 rewrite) -------------
template<int D, bool INF32, int CIDX, int SAMP>
__global__ __launch_bounds__(256)
void agg_kernel(const float* __restrict__ xin) {
    __shared__ float Ms[P * P];
    __shared__ float dinv[P];
    __shared__ __align__(16) float hsf[SAMP][P][D];
    const int t = threadIdx.x;
    compute_M_256(g_C[CIDX], Ms, dinv, t);
    constexpr int C4 = D / 4;               // float4 chunks per row
    for (long s0 = (long)blockIdx.x * SAMP; s0 < BB; s0 += (long)gridDim.x * SAMP) {
        __syncthreads();                    // hsf reuse guard
        if (INF32) {
            const float4* src = (const float4*)(xin + s0 * (P * D));
            for (int i = t; i < SAMP * P * C4; i += 256) {
                float4 v = src[i];
                int r = i / C4, c = i - r * C4;
                *(float4*)&hsf[r / P][r % P][c * 4] = v;
            }
        } else {
            const ushort4* src = (const ushort4*)(g_bufB + s0 * (P * D));
            for (int i = t; i < SAMP * P * C4; i += 256) {
                ushort4 u = src[i];
                int r = i / C4, c = i - r * C4;
                float4 f; f.x = bf2f(u.x); f.y = bf2f(u.y);
                f.z = bf2f(u.z); f.w = bf2f(u.w);
                *(float4*)&hsf[r / P][r % P][c * 4] = f;
            }
        }
        __syncthreads();
        // items: (smp, vg of 4 v's, c4). 5 v-groups per sample.
        for (int i = t; i < SAMP * 5 * C4; i += 256) {
            const int c4 = i % C4;
            const int g = i / C4;
            const int smp = g / 5, v0 = (g - smp * 5) * 4;
            float4 a0 = {0,0,0,0}, a1 = {0,0,0,0}, a2 = {0,0,0,0}, a3 = {0,0,0,0};
#pragma unroll
            for (int u = 0; u < P; ++u) {
                float4 h = *(const float4*)&hsf[smp][u][c4 * 4];
                float m0 = Ms[(v0 + 0) * P + u], m1 = Ms[(v0 + 1) * P + u];
                float m2 = Ms[(v0 + 2) * P + u], m3 = Ms[(v0 + 3) * P + u];
                a0.x += m0*h.x; a0.y += m0*h.y; a0.z += m0*h.z; a0.w += m0*h.w;
                a1.x += m1*h.x; a1.y += m1*h.y; a1.z += m1*h.z; a1.w += m1*h.w;
                a2.x += m2*h.x; a2.y += m2*h.y; a2.z += m2*h.z; a2.w += m2*h.w;
                a3.x += m3*h.x; a3.y += m3*h.y; a3.z += m3*h.z; a3.w += m3*h.w;
            }
            unsigned short* zb = g_bufA + (s0 + smp) * (size_t)(P * D) + c4 * 4;
            ushort4 o;
            o.x = f2bf(a0.x); o.y = f2bf(a0.y); o.z = f2bf(a0.z); o.w = f2bf(a0.w);
            *(ushort4*)(zb + (size_t)(v0 + 0) * D) = o;
            o.x = f2bf(a1.x); o.y = f2bf(a1.y); o.z = f2bf(a1.z); o.w = f2bf(a1.w);
            *(ushort4*)(zb + (size_t)(v0 + 1) * D) = o;
            o.x = f2bf(a2.x); o.y = f2bf(a2.y); o.z = f2bf(a2.z); o.w = f2bf(a2.w);
            *(ushort4*)(zb + (size_t)(v0 + 2) * D) = o;
            o.x = f2bf(a3.x); o.y = f2bf(a3.y); o.z = f2bf(a3.z); o.w = f2bf(a3.w);
            *(ushort4*)(zb + (size_t)(v0 + 3) * D) = o;
        }
    }
}

// ---------------- gemm2 (round-12): canonical LDS-staged tiled GEMM ---------
// Round-4 lesson: W-in-LDS @84KB -> 1 block/CU (22% occ); direct-to-register
// fragment loads (16 rows x 64B @ 640B stride per instr) + persistent-stride
// tile walk -> 3x read / 2.3x write amplification (FETCH 656MB vs 210MB input).
// Fix (canonical m97 shape): tile 128M x 128N, K chunked by 64; BOTH operands
// staged global->LDS with lane-contiguous 128B-aligned runs; fragments come
// from LDS rows padded to 72 elems (144B stride -> 2-way bank alias = free).
// LDS 36KB -> 4 blocks/CU. W2 (82KB) stays hot in L2; restaging 16KB/chunk
// from L2 costs ~6us aggregate. K ascending (chunk, sub-step) -> accumulation
// order identical to rounds 1-4 -> bit-exact.
__global__ __launch_bounds__(256)
void gemm2_kernel() {
    constexpr int KL = 72;                   // padded LDS row, elems
    __shared__ __align__(16) unsigned short As[128 * KL];
    __shared__ __align__(16) unsigned short Wsh[128 * KL];
    const int t = threadIdx.x, w = t >> 6, lane = t & 63;
    const int m15 = lane & 15, q = lane >> 4;
    const long row0 = (long)blockIdx.x * 128;
    f32x4 acc[2][8];
#pragma unroll
    for (int zr = 0; zr < 2; ++zr)
#pragma unroll
        for (int nf = 0; nf < 8; ++nf) acc[zr][nf] = 0.f;
    for (int kc = 0; kc < 5; ++kc) {         // K chunks of 64 elems
        __syncthreads();                     // guard LDS reuse
        for (int i = t; i < 1024; i += 256) {
            const int r = i >> 3, c8 = i & 7;
            *(v8s*)&As[r * KL + c8 * 8] =
                *(const v8s*)(g_bufA + (size_t)(row0 + r) * 320 + kc * 64 + c8 * 8);
            *(v8s*)&Wsh[r * KL + c8 * 8] =
                *(const v8s*)(g_W2b + (size_t)r * 320 + kc * 64 + c8 * 8);
        }
        __syncthreads();
#pragma unroll
        for (int ks = 0; ks < 2; ++ks) {     // 32-elem MFMA sub-steps
            v8s af[2];
#pragma unroll
            for (int zr = 0; zr < 2; ++zr)
                af[zr] = *(const v8s*)&As[(w * 32 + zr * 16 + m15) * KL + ks * 32 + q * 8];
#pragma unroll
            for (int nf = 0; nf < 8; ++nf) {
                v8s wf = *(const v8s*)&Wsh[(nf * 16 + m15) * KL + ks * 32 + q * 8];
#pragma unroll
                for (int zr = 0; zr < 2; ++zr)
                    acc[zr][nf] = __builtin_amdgcn_mfma_f32_16x16x32_bf16(
                        wf, af[zr], acc[zr][nf], 0, 0, 0);
            }
        }
    }
#pragma unroll
    for (int zr = 0; zr < 2; ++zr) {
        const long m = row0 + w * 32 + zr * 16 + m15;
#pragma unroll
        for (int nf = 0; nf < 8; ++nf) {
            f32x4 b4 = *(const f32x4*)(g_b2p + nf * 16 + q * 4);
            f32x4 c = acc[zr][nf];
            float v0 = fmaxf(c[0] + b4[0], 0.f), v1 = fmaxf(c[1] + b4[1], 0.f);
            float v2 = fmaxf(c[2] + b4[2], 0.f), v3 = fmaxf(c[3] + b4[3], 0.f);
            ushort4 o; o.x = f2bf(v0); o.y = f2bf(v1); o.z = f2bf(v2); o.w = f2bf(v3);
            *(ushort4*)(g_bufB + (size_t)m * 128 + nf * 16 + q * 4) = o;
        }
    }
}

// ---------------- streaming MFMA GEMM (round-11 form, gemm1/3/4) ------------
template<int Kp, int Np, int ZR, bool FLAT, int WSEL, bool ATOB, int NSPLIT,
         int KSC, int NTHR, long MROWS>
__global__ __launch_bounds__(NTHR)
void gemm_kernel() {
    constexpr int BN = Np / NSPLIT;          // cols handled by this block
    constexpr int NF = BN / 16;
    constexpr int KS = Kp / 32;
    constexpr int CPT = KS / KSC;            // chunks per tile
    constexpr int KL = Kp + 8;               // padded LDS row (elems, 16B step)
    constexpr int NW = NTHR / 64;
    constexpr int TM = NW * ZR * 16;         // rows per tile
    constexpr long NTILE = MROWS / TM;
    static_assert(KS % KSC == 0, "KSC must divide KS");
    __shared__ __align__(16) unsigned short Ws[BN * KL];
    __shared__ __align__(16) float bs[BN];
    const unsigned short* __restrict__ Wb =
        (WSEL == 1) ? g_W1b : (WSEL == 2) ? g_W2b : (WSEL == 3) ? g_W3b : g_W4b;
    const float* __restrict__ bp =
        (WSEL == 1) ? g_b1p : (WSEL == 2) ? g_b2p : (WSEL == 3) ? g_b3p : g_b4p;
    const unsigned short* __restrict__ A = ATOB ? g_bufA : g_bufB;
    unsigned short* __restrict__ Hout = ATOB ? g_bufB : g_bufA;
    const int t = threadIdx.x, w = t >> 6, lane = t & 63;
    const int m15 = lane & 15, q = lane >> 4;
    const int n0 = blockIdx.y * BN;
    // ---- stage W slice + bias to LDS (once per block) ----
    for (int i = t; i < BN * (Kp / 8); i += NTHR) {
        int r = i / (Kp / 8), c = i - r * (Kp / 8);
        *(v8s*)(&Ws[r * KL + c * 8]) = *(const v8s*)(Wb + (size_t)(n0 + r) * Kp + c * 8);
    }
    for (int i = t; i < BN; i += NTHR) bs[i] = bp[n0 + i];
    __syncthreads();

    v8s aC[ZR][KSC], aN[ZR][KSC];
    long tile = (long)blockIdx.x;
    if (tile < NTILE) {
        const unsigned short* ab =
            A + (size_t)(tile * TM + w * (ZR * 16) + m15) * Kp + q * 8;
#pragma unroll
        for (int zr = 0; zr < ZR; ++zr)
#pragma unroll
            for (int ks = 0; ks < KSC; ++ks)
                aC[zr][ks] = *(const v8s*)(ab + (size_t)zr * 16 * Kp + ks * 32);
    }
    for (; tile < NTILE; tile += gridDim.x) {
        f32x4 acc[ZR][NF];
#pragma unroll
        for (int zr = 0; zr < ZR; ++zr)
#pragma unroll
            for (int nf = 0; nf < NF; ++nf) acc[zr][nf] = 0.f;
        for (int c = 0; c < CPT; ++c) {
            // issue next chunk's A loads before consuming the current chunk
            const long ntile = (c + 1 < CPT) ? tile : tile + (long)gridDim.x;
            const int nk0 = (c + 1 < CPT) ? (c + 1) * KSC : 0;
            const bool hasNext = (ntile < NTILE);
            if (hasNext) {
                const unsigned short* ab =
                    A + (size_t)(ntile * TM + w * (ZR * 16) + m15) * Kp + nk0 * 32 + q * 8;
#pragma unroll
                for (int zr = 0; zr < ZR; ++zr)
#pragma unroll
                    for (int ks = 0; ks < KSC; ++ks)
                        aN[zr][ks] = *(const v8s*)(ab + (size_t)zr * 16 * Kp + ks * 32);
            }
#pragma unroll
            for (int nf = 0; nf < NF; ++nf) {
                v8s wr[KSC];
#pragma unroll
                for (int ks = 0; ks < KSC; ++ks)
                    wr[ks] = *(const v8s*)(&Ws[(nf * 16 + m15) * KL + (c * KSC + ks) * 32 + q * 8]);
#pragma unroll
                for (int ks = 0; ks < KSC; ++ks)
#pragma unroll
                    for (int zr = 0; zr < ZR; ++zr)
                        acc[zr][nf] = __builtin_amdgcn_mfma_f32_16x16x32_bf16(
                            wr[ks], aC[zr][ks], acc[zr][nf], 0, 0, 0);
            }
            if (hasNext) {
#pragma unroll
                for (int zr = 0; zr < ZR; ++zr)
#pragma unroll
                    for (int ks = 0; ks < KSC; ++ks) aC[zr][ks] = aN[zr][ks];
            }
        }
        // ---- epilogue: bias + relu + store ----
#pragma unroll
        for (int zr = 0; zr < ZR; ++zr) {
            const long m = tile * TM + w * (ZR * 16) + zr * 16 + m15;
#pragma unroll
            for (int nf = 0; nf < NF; ++nf) {
                f32x4 b4 = *(const f32x4*)(&bs[nf * 16 + q * 4]);
                f32x4 cc = acc[zr][nf];
                float v0 = fmaxf(cc[0] + b4[0], 0.f), v1 = fmaxf(cc[1] + b4[1], 0.f);
                float v2 = fmaxf(cc[2] + b4[2], 0.f), v3 = fmaxf(cc[3] + b4[3], 0.f);
                if (!FLAT) {
                    ushort4 o; o.x = f2bf(v0); o.y = f2bf(v1); o.z = f2bf(v2); o.w = f2bf(v3);
                    *(ushort4*)(Hout + (size_t)m * Np + n0 + nf * 16 + q * 4) = o;
                } else {
                    const int n0f = nf * 16 + q * 4;   // FLAT only with NSPLIT=1
                    if (n0f <= 48) {
                        const long s = m / 20; const int u = (int)(m - s * 20);
                        unsigned short* base = Hout + (size_t)s * 1024 + u * 50 + n0f;
                        unsigned int lo = (unsigned int)f2bf(v0) | ((unsigned int)f2bf(v1) << 16);
                        *(unsigned int*)(base) = lo;
                        if (n0f < 48) {
                            unsigned int hi = (unsigned int)f2bf(v2) | ((unsigned int)f2bf(v3) << 16);
                            *(unsigned int*)(base + 2) = hi;
                        }
                    }
                }
            }
        }
    }
}

// logits = W5 h4 + b5; softmax -> out. h4 in g_bufA (112-padded rows).
__global__ __launch_bounds__(256)
void head_kernel(const float* __restrict__ W5, const float* __restrict__ b5,
                 float* __restrict__ out) {
    __shared__ float w5s[300];
    __shared__ float b5s[3];
    const int t = threadIdx.x;
    for (int i = t; i < 300; i += 256) w5s[i] = W5[i];
    if (t < 3) b5s[t] = b5[t];
    __syncthreads();
    const int s = blockIdx.x * 256 + t;
    const unsigned short* h = g_bufA + (size_t)s * 112;
    float a0 = b5s[0], a1 = b5s[1], a2 = b5s[2];
    for (int k = 0; k < 100; ++k) {
        float hv = bf2f(h[k]);
        a0 += hv * w5s[k]; a1 += hv * w5s[100 + k]; a2 += hv * w5s[200 + k];
    }
    float m = fmaxf(a0, fmaxf(a1, a2));
    float e0 = expf(a0 - m), e1 = expf(a1 - m), e2 = expf(a2 - m);
    float inv = 1.f / (e0 + e1 + e2);
    out[(size_t)s * 3 + 0] = e0 * inv;
    out[(size_t)s * 3 + 1] = e1 * inv;
    out[(size_t)s * 3 + 2] = e2 * inv;
}

extern "C" void kernel_launch(void* const* d_in, const int* in_sizes, int n_in,
                              void* d_out, int out_size, void* d_ws, size_t ws_size,
                              hipStream_t stream) {
    const float* x  = (const float*)d_in[0];
    const float* W1 = (const float*)d_in[1];
    const float* b1 = (const float*)d_in[2];
    const float* W2 = (const float*)d_in[3];
    const float* b2 = (const float*)d_in[4];
    const float* W3 = (const float*)d_in[5];
    const float* b3 = (const float*)d_in[6];
    const float* W4 = (const float*)d_in[7];
    const float* b4 = (const float*)d_in[8];
    const float* W5 = (const float*)d_in[9];
    const float* b5 = (const float*)d_in[10];
    float* out = (float*)d_out;

    zero_C_kernel<<<3, P * P, 0, stream>>>();
    prep_kernel<<<256, 256, 0, stream>>>(W1, b1, W2, b2, W3, b3, W4, b4);

    knn1_mfma_kernel<<<BB / 16, NT, 0, stream>>>(x);                 // x -> C0
    agg_kernel<128, true, 0, 4><<<1024, 256, 0, stream>>>(x);        // x -> z1(A)
    // W slice 160x136 bf16 in LDS (42.5KB); NSPLIT=2 (z1 84MB, L3-resident);
    // 512 blocks x 5 tiles, full-K hoist (KSC=KS=4) + cross-tile prefetch.
    gemm_kernel<128, 320, 2, false, 1, true, 2, 4, 256, 327680L>
        <<<dim3(512, 2), 256, 0, stream>>>();                        // z1 -> h1(B)

    knn_mfma_kernel<320, 1><<<BB / 16, NT, 0, stream>>>();           // h1 -> C1
    agg_kernel<320, false, 1, 2><<<1024, 256, 0, stream>>>(nullptr); // h1 -> z2(A)
    // round-12: canonical LDS-staged tile GEMM, 2560 blocks x 1 tile.
    gemm2_kernel<<<2560, 256, 0, stream>>>();                        // z2 -> h2(B)

    knn_mfma_kernel<128, 2><<<BB / 16, NT, 0, stream>>>();           // h2 -> C2
    agg_kernel<128, false, 2, 4><<<1024, 256, 0, stream>>>(nullptr); // h2 -> z3(A)
    gemm_kernel<128, 64, 2, true, 3, true, 1, 4, 256, 327680L>
        <<<dim3(512, 1), 256, 0, stream>>>();                        // z3 -> h3f(B)

    // NSPLIT=7 (h3f 33MB L3-resident); W slice 16x1032 (33KB); chunked K.
    gemm_kernel<1024, 112, 1, false, 4, false, 7, 8, 256, 16384L>
        <<<dim3(256, 7), 256, 0, stream>>>();                        // h3f -> h4(A)
    head_kernel<<<BB / 256, 256, 0, stream>>>(W5, b5, out);
}

// Round 6
// 1006.538 us; speedup vs baseline: 1.2576x; 1.0728x over previous
//
#include <hip/hip_runtime.h>
#include <math.h>

#define BB 16384
#define P 20
#define NT 512

typedef short v8s __attribute__((ext_vector_type(8)));
typedef _Float16 v8h __attribute__((ext_vector_type(8)));
typedef float f32x4 __attribute__((ext_vector_type(4)));
typedef float f32x16 __attribute__((ext_vector_type(16)));

// ---- static device buffers: referenced ONLY inside device code (never passed
// as kernel args from host — that passes the host shadow and faults). ----
// +4096 pad: knn_mfma/agg_mfma read rows u=20..31 of the last samples (garbage,
// multiplied by zero-padded M columns / never stored).
#define NELEM ((size_t)BB * P * 320)          // 209.7 MB each
__device__ unsigned int g_C[3][P * P];
__device__ __align__(16) unsigned short g_bufA[NELEM + 4096];  // z1 / z2 / z3 / h4
__device__ __align__(16) unsigned short g_bufB[NELEM + 4096];  // h1 / h2 / h3f
__device__ __align__(16) unsigned short g_W1b[320 * 128];
__device__ __align__(16) unsigned short g_W2b[128 * 320];
__device__ __align__(16) unsigned short g_W3b[64 * 128];
__device__ __align__(16) unsigned short g_W4b[112 * 1024];
__device__ __align__(16) float g_b1p[320];
__device__ __align__(16) float g_b2p[128];
__device__ __align__(16) float g_b3p[64];
__device__ __align__(16) float g_b4p[112];

__device__ inline float bf2f(unsigned short u) {
    union { unsigned int i; float f; } c; c.i = ((unsigned int)u) << 16; return c.f;
}
__device__ inline unsigned short f2bf(float f) {
    union { float f; unsigned int i; } c; c.f = f;
    unsigned int u = c.i + 0x7fffu + ((c.i >> 16) & 1u);  // RNE (no NaN in data)
    return (unsigned short)(u >> 16);
}

__global__ void zero_C_kernel() { g_C[blockIdx.x][threadIdx.x] = 0u; }

// Pad+convert weights/biases to bf16 (zero pads -> pad outputs relu(0+0)=0).
__global__ void prep_kernel(const float* __restrict__ W1, const float* __restrict__ b1,
                            const float* __restrict__ W2, const float* __restrict__ b2,
                            const float* __restrict__ W3, const float* __restrict__ b3,
                            const float* __restrict__ W4, const float* __restrict__ b4) {
    const int stride = gridDim.x * blockDim.x;
    const int id = blockIdx.x * blockDim.x + threadIdx.x;
    for (int i = id; i < 320 * 128; i += stride) { int n = i >> 7, k = i & 127;
        g_W1b[i] = (n < 300) ? f2bf(W1[n * 128 + k]) : 0; }
    for (int i = id; i < 128 * 320; i += stride) { int n = i / 320, k = i - n * 320;
        g_W2b[i] = (n < 100 && k < 300) ? f2bf(W2[n * 300 + k]) : 0; }
    for (int i = id; i < 64 * 128; i += stride) { int n = i >> 7, k = i & 127;
        g_W3b[i] = (n < 50 && k < 100) ? f2bf(W3[n * 100 + k]) : 0; }
    for (int i = id; i < 112 * 1024; i += stride) { int n = i >> 10, k = i & 1023;
        g_W4b[i] = (n < 100 && k < 1000) ? f2bf(W4[n * 1000 + k]) : 0; }
    for (int i = id; i < 320; i += stride) g_b1p[i] = (i < 300) ? b1[i] : 0.f;
    for (int i = id; i < 128; i += stride) g_b2p[i] = (i < 100) ? b2[i] : 0.f;
    for (int i = id; i < 64;  i += stride) g_b3p[i] = (i < 50)  ? b3[i] : 0.f;
    for (int i = id; i < 112; i += stride) g_b4p[i] = (i < 100) ? b4[i] : 0.f;
}

// ---------------- kNN layer 1: MFMA Gram on fp16 hi/lo split (verified r8) --
__global__ __launch_bounds__(NT)
void knn1_mfma_kernel(const float* __restrict__ x) {
    __shared__ float Gs[8][P * 21];
    __shared__ unsigned int hist[P * P];
    const int t = threadIdx.x, w = t >> 6, lane = t & 63;
    const int m31 = lane & 31, half = lane >> 5;
    // Rows 20..31 are MFMA padding; clamp the load to row 19 (x has no tail
    // pad and is an exact page multiple — an unclamped read walks off the
    // allocation for the last sample). Clamped rows are never stored.
    const int mrow = (m31 < P) ? m31 : (P - 1);
    for (int i = t; i < P * P; i += NT) hist[i] = 0;
    for (int pass = 0; pass < 2; ++pass) {
        const size_t s = (size_t)blockIdx.x * 16 + pass * 8 + w;
        const float* rp = x + s * (size_t)(P * 128) + (size_t)mrow * 128 + half * 8;
        f32x16 acc;
#pragma unroll
        for (int i = 0; i < 16; ++i) acc[i] = 0.f;
#pragma unroll
        for (int ks = 0; ks < 8; ++ks) {
            float4 f0 = *(const float4*)(rp + ks * 16);
            float4 f1 = *(const float4*)(rp + ks * 16 + 4);
            float fv[8] = {f0.x, f0.y, f0.z, f0.w, f1.x, f1.y, f1.z, f1.w};
            v8h hi, lo;
#pragma unroll
            for (int j = 0; j < 8; ++j) {
                _Float16 hv = (_Float16)fv[j];
                hi[j] = hv;
                lo[j] = (_Float16)(fv[j] - (float)hv);
            }
            acc = __builtin_amdgcn_mfma_f32_32x32x16_f16(hi, hi, acc, 0, 0, 0);
            acc = __builtin_amdgcn_mfma_f32_32x32x16_f16(hi, lo, acc, 0, 0, 0);
            acc = __builtin_amdgcn_mfma_f32_32x32x16_f16(lo, hi, acc, 0, 0, 0);
            acc = __builtin_amdgcn_mfma_f32_32x32x16_f16(lo, lo, acc, 0, 0, 0);
        }
        float* G = &Gs[w][0];
        if (m31 < P) {
#pragma unroll
            for (int r = 0; r < 16; ++r) {
                int row = (r & 3) + 8 * (r >> 2) + 4 * half;
                if (row < P) G[row * 21 + m31] = acc[r];
            }
        }
        __syncthreads();
        if (lane < P) {
            const int p = lane;
            float d2[P];
            const float gpp = G[p * 21 + p];
#pragma unroll
            for (int u = 0; u < P; ++u)
                d2[u] = (u == p) ? 0.f : gpp + G[u * 21 + u] - 2.f * G[p * 21 + u];
            float pv = -3.0e38f; int pi = -1;
            for (int it = 0; it < 6; ++it) {
                float best = 3.0e38f; int bq = 0;
#pragma unroll
                for (int u = 0; u < P; ++u) {
                    float vu = d2[u];
                    bool cand = (vu > pv) || (vu == pv && u > pi);
                    if (cand && vu < best) { best = vu; bq = u; }
                }
                if (it > 0) atomicAdd(&hist[bq * P + p], 1u);
                pv = best; pi = bq;
            }
        }
        __syncthreads();
    }
    if (t < P * P && hist[t]) atomicAdd(&g_C[0][t], hist[t]);
}

// ---------------- kNN via MFMA Gram: G = Z Z^T per sample (verified r6) -----
template<int D, int CIDX>
__global__ __launch_bounds__(NT)
void knn_mfma_kernel() {
    __shared__ float Gs[8][P * 21];
    __shared__ unsigned int hist[P * P];
    const int t = threadIdx.x, w = t >> 6, lane = t & 63;
    const int m31 = lane & 31, half = lane >> 5;
    for (int i = t; i < P * P; i += NT) hist[i] = 0;
    for (int pass = 0; pass < 2; ++pass) {
        const size_t s = (size_t)blockIdx.x * 16 + pass * 8 + w;
        const unsigned short* rp = g_bufB + s * (P * D) + (size_t)m31 * D + half * 8;
        f32x16 acc;
#pragma unroll
        for (int i = 0; i < 16; ++i) acc[i] = 0.f;
        for (int ks = 0; ks < D / 16; ++ks) {
            v8s z = *(const v8s*)(rp + ks * 16);
            acc = __builtin_amdgcn_mfma_f32_32x32x16_bf16(z, z, acc, 0, 0, 0);
        }
        float* G = &Gs[w][0];
        if (m31 < P) {
#pragma unroll
            for (int r = 0; r < 16; ++r) {
                int row = (r & 3) + 8 * (r >> 2) + 4 * half;
                if (row < P) G[row * 21 + m31] = acc[r];
            }
        }
        __syncthreads();
        if (lane < P) {
            const int p = lane;
            float d2[P];
            const float gpp = G[p * 21 + p];
#pragma unroll
            for (int u = 0; u < P; ++u)
                d2[u] = (u == p) ? 0.f : gpp + G[u * 21 + u] - 2.f * G[p * 21 + u];
            float pv = -3.0e38f; int pi = -1;
            for (int it = 0; it < 6; ++it) {
                float best = 3.0e38f; int bq = 0;
#pragma unroll
                for (int u = 0; u < P; ++u) {
                    float vu = d2[u];
                    bool cand = (vu > pv) || (vu == pv && u > pi);
                    if (cand && vu < best) { best = vu; bq = u; }
                }
                if (it > 0) atomicAdd(&hist[bq * P + p], 1u);
                pv = best; pi = bq;
            }
        }
        __syncthreads();
    }
    if (t < P * P && hist[t]) atomicAdd(&g_C[CIDX][t], hist[t]);
}

// compute_M for 512-thread blocks (strided loops)
__device__ inline void compute_M_512(const unsigned int* __restrict__ Cg,
                                     float* Ms, float* dinv, int t) {
    for (int i = t; i < P * P; i += 512) Ms[i] = (float)Cg[i];
    __syncthreads();
    if (t < P) {
        float deg = 1.f;
        for (int u = 0; u < P; ++u) deg += Ms[t * P + u];
        dinv[t] = 1.f / sqrtf(deg);
    }
    __syncthreads();
    for (int i = t; i < P * P; i += 512) {
        int v = i / P, u = i - v * P;
        float m = dinv[v] * Ms[i] * dinv[u];
        if (v == u) m += dinv[v] * dinv[v];
        Ms[i] = m;
    }
    __syncthreads();
}

// ---------------- agg via MFMA (round-13): z[s] = M @ h[s] ------------------
// Round-5 lesson: VALU agg was phase-serialized latency-bound (52KB LDS -> 3
// blk/CU, VALUBusy 30%, BW 27%, Occ 20%). M is ONE global 20x20 matrix ->
// batched GEMM on the matrix pipe. A = M zero-padded to 32x32, bf16 hi/lo
// split (err ~2^-17, knn1's verified trick). Every h element feeds exactly
// ONE B-fragment -> no reuse -> NO LDS staging: B-frags built from 64B-run
// scalar global loads (h is L2/L3-hot), one sample/wave, no hot barriers.
// Operand maps ground-truthed vs knn_mfma (mfma(z,z)=ZZ^T fixes layouts):
//   A: lane=row v(lane&31), slot j = u(kc*16+half*8+j)
//   B: lane=col d(lane&31), slot j = h[u(kc*16+half*8+j)][d0+lane&31]
//   C: reg r -> row (r&3)+8*(r>>2)+4*half, col lane&31.
// INF32 (layer 1): x fp32 -> bf16 hi/lo B-frags, 4-term MFMA product; kc=1
// row clamp to 19 (x has no tail pad; M's zero cols neutralize the dup row).
template<int D, bool INF32, int CIDX>
__global__ __launch_bounds__(512)
void agg_mfma_kernel(const float* __restrict__ xin) {
    constexpr int NCB = D / 32;              // 32-col blocks
    __shared__ float Ms[P * P];
    __shared__ float dinv[P];
    const int t = threadIdx.x, w = t >> 6, lane = t & 63;
    const int n31 = lane & 31, half = lane >> 5;
    compute_M_512(g_C[CIDX], Ms, dinv, t);
    // A fragments: M hi/lo for k-chunks u0 = 0, 16 (zero-padded past P)
    v8s mhi[2], mlo[2];
#pragma unroll
    for (int kc = 0; kc < 2; ++kc)
#pragma unroll
        for (int j = 0; j < 8; ++j) {
            const int u = kc * 16 + half * 8 + j;
            const int v = n31;
            const float m = (v < P && u < P) ? Ms[v * P + u] : 0.f;
            const unsigned short h16 = f2bf(m);
            mhi[kc][j] = (short)h16;
            mlo[kc][j] = (short)f2bf(m - bf2f(h16));
        }
    const size_t s = (size_t)blockIdx.x * 8 + w;
    unsigned short* zout = g_bufA + s * (size_t)(P * D);
    if (!INF32) {
        const unsigned short* hin = g_bufB + s * (size_t)(P * D);
#pragma unroll
        for (int cb = 0; cb < NCB; ++cb) {
            v8s b0, b1;
#pragma unroll
            for (int j = 0; j < 8; ++j) {
                b0[j] = (short)hin[(size_t)(half * 8 + j) * D + cb * 32 + n31];
                b1[j] = (short)hin[(size_t)(16 + half * 8 + j) * D + cb * 32 + n31];
            }
            f32x16 acc;
#pragma unroll
            for (int i = 0; i < 16; ++i) acc[i] = 0.f;
            acc = __builtin_amdgcn_mfma_f32_32x32x16_bf16(mhi[0], b0, acc, 0, 0, 0);
            acc = __builtin_amdgcn_mfma_f32_32x32x16_bf16(mlo[0], b0, acc, 0, 0, 0);
            acc = __builtin_amdgcn_mfma_f32_32x32x16_bf16(mhi[1], b1, acc, 0, 0, 0);
            acc = __builtin_amdgcn_mfma_f32_32x32x16_bf16(mlo[1], b1, acc, 0, 0, 0);
#pragma unroll
            for (int r = 0; r < 16; ++r) {
                const int row = (r & 3) + 8 * (r >> 2) + 4 * half;
                if (row < P)
                    zout[(size_t)row * D + cb * 32 + n31] = f2bf(acc[r]);
            }
        }
    } else {
        const float* xr = xin + s * (size_t)(P * D);
#pragma unroll
        for (int cb = 0; cb < NCB; ++cb) {
            v8s bh0, bl0, bh1, bl1;
#pragma unroll
            for (int j = 0; j < 8; ++j) {
                const int u0 = half * 8 + j;                 // < 16, always valid
                int u1 = 16 + half * 8 + j; if (u1 > P - 1) u1 = P - 1;  // clamp
                const float x0 = xr[(size_t)u0 * D + cb * 32 + n31];
                const float x1 = xr[(size_t)u1 * D + cb * 32 + n31];
                const unsigned short h0 = f2bf(x0), h1 = f2bf(x1);
                bh0[j] = (short)h0; bl0[j] = (short)f2bf(x0 - bf2f(h0));
                bh1[j] = (short)h1; bl1[j] = (short)f2bf(x1 - bf2f(h1));
            }
            f32x16 acc;
#pragma unroll
            for (int i = 0; i < 16; ++i) acc[i] = 0.f;
            acc = __builtin_amdgcn_mfma_f32_32x32x16_bf16(mhi[0], bh0, acc, 0, 0, 0);
            acc = __builtin_amdgcn_mfma_f32_32x32x16_bf16(mhi[0], bl0, acc, 0, 0, 0);
            acc = __builtin_amdgcn_mfma_f32_32x32x16_bf16(mlo[0], bh0, acc, 0, 0, 0);
            acc = __builtin_amdgcn_mfma_f32_32x32x16_bf16(mlo[0], bl0, acc, 0, 0, 0);
            acc = __builtin_amdgcn_mfma_f32_32x32x16_bf16(mhi[1], bh1, acc, 0, 0, 0);
            acc = __builtin_amdgcn_mfma_f32_32x32x16_bf16(mhi[1], bl1, acc, 0, 0, 0);
            acc = __builtin_amdgcn_mfma_f32_32x32x16_bf16(mlo[1], bh1, acc, 0, 0, 0);
            acc = __builtin_amdgcn_mfma_f32_32x32x16_bf16(mlo[1], bl1, acc, 0, 0, 0);
#pragma unroll
            for (int r = 0; r < 16; ++r) {
                const int row = (r & 3) + 8 * (r >> 2) + 4 * half;
                if (row < P)
                    zout[(size_t)row * D + cb * 32 + n31] = f2bf(acc[r]);
            }
        }
    }
}

// ---------------- gemm2 (round-12): canonical LDS-staged tiled GEMM ---------
__global__ __launch_bounds__(256)
void gemm2_kernel() {
    constexpr int KL = 72;                   // padded LDS row, elems
    __shared__ __align__(16) unsigned short As[128 * KL];
    __shared__ __align__(16) unsigned short Wsh[128 * KL];
    const int t = threadIdx.x, w = t >> 6, lane = t & 63;
    const int m15 = lane & 15, q = lane >> 4;
    const long row0 = (long)blockIdx.x * 128;
    f32x4 acc[2][8];
#pragma unroll
    for (int zr = 0; zr < 2; ++zr)
#pragma unroll
        for (int nf = 0; nf < 8; ++nf) acc[zr][nf] = 0.f;
    for (int kc = 0; kc < 5; ++kc) {         // K chunks of 64 elems
        __syncthreads();                     // guard LDS reuse
        for (int i = t; i < 1024; i += 256) {
            const int r = i >> 3, c8 = i & 7;
            *(v8s*)&As[r * KL + c8 * 8] =
                *(const v8s*)(g_bufA + (size_t)(row0 + r) * 320 + kc * 64 + c8 * 8);
            *(v8s*)&Wsh[r * KL + c8 * 8] =
                *(const v8s*)(g_W2b + (size_t)r * 320 + kc * 64 + c8 * 8);
        }
        __syncthreads();
#pragma unroll
        for (int ks = 0; ks < 2; ++ks) {     // 32-elem MFMA sub-steps
            v8s af[2];
#pragma unroll
            for (int zr = 0; zr < 2; ++zr)
                af[zr] = *(const v8s*)&As[(w * 32 + zr * 16 + m15) * KL + ks * 32 + q * 8];
#pragma unroll
            for (int nf = 0; nf < 8; ++nf) {
                v8s wf = *(const v8s*)&Wsh[(nf * 16 + m15) * KL + ks * 32 + q * 8];
#pragma unroll
                for (int zr = 0; zr < 2; ++zr)
                    acc[zr][nf] = __builtin_amdgcn_mfma_f32_16x16x32_bf16(
                        wf, af[zr], acc[zr][nf], 0, 0, 0);
            }
        }
    }
#pragma unroll
    for (int zr = 0; zr < 2; ++zr) {
        const long m = row0 + w * 32 + zr * 16 + m15;
#pragma unroll
        for (int nf = 0; nf < 8; ++nf) {
            f32x4 b4 = *(const f32x4*)(g_b2p + nf * 16 + q * 4);
            f32x4 c = acc[zr][nf];
            float v0 = fmaxf(c[0] + b4[0], 0.f), v1 = fmaxf(c[1] + b4[1], 0.f);
            float v2 = fmaxf(c[2] + b4[2], 0.f), v3 = fmaxf(c[3] + b4[3], 0.f);
            ushort4 o; o.x = f2bf(v0); o.y = f2bf(v1); o.z = f2bf(v2); o.w = f2bf(v3);
            *(ushort4*)(g_bufB + (size_t)m * 128 + nf * 16 + q * 4) = o;
        }
    }
}

// ---------------- streaming MFMA GEMM (round-11 form, gemm1/3/4) ------------
template<int Kp, int Np, int ZR, bool FLAT, int WSEL, bool ATOB, int NSPLIT,
         int KSC, int NTHR, long MROWS>
__global__ __launch_bounds__(NTHR)
void gemm_kernel() {
    constexpr int BN = Np / NSPLIT;          // cols handled by this block
    constexpr int NF = BN / 16;
    constexpr int KS = Kp / 32;
    constexpr int CPT = KS / KSC;            // chunks per tile
    constexpr int KL = Kp + 8;               // padded LDS row (elems, 16B step)
    constexpr int NW = NTHR / 64;
    constexpr int TM = NW * ZR * 16;         // rows per tile
    constexpr long NTILE = MROWS / TM;
    static_assert(KS % KSC == 0, "KSC must divide KS");
    __shared__ __align__(16) unsigned short Ws[BN * KL];
    __shared__ __align__(16) float bs[BN];
    const unsigned short* __restrict__ Wb =
        (WSEL == 1) ? g_W1b : (WSEL == 2) ? g_W2b : (WSEL == 3) ? g_W3b : g_W4b;
    const float* __restrict__ bp =
        (WSEL == 1) ? g_b1p : (WSEL == 2) ? g_b2p : (WSEL == 3) ? g_b3p : g_b4p;
    const unsigned short* __restrict__ A = ATOB ? g_bufA : g_bufB;
    unsigned short* __restrict__ Hout = ATOB ? g_bufB : g_bufA;
    const int t = threadIdx.x, w = t >> 6, lane = t & 63;
    const int m15 = lane & 15, q = lane >> 4;
    const int n0 = blockIdx.y * BN;
    // ---- stage W slice + bias to LDS (once per block) ----
    for (int i = t; i < BN * (Kp / 8); i += NTHR) {
        int r = i / (Kp / 8), c = i - r * (Kp / 8);
        *(v8s*)(&Ws[r * KL + c * 8]) = *(const v8s*)(Wb + (size_t)(n0 + r) * Kp + c * 8);
    }
    for (int i = t; i < BN; i += NTHR) bs[i] = bp[n0 + i];
    __syncthreads();

    v8s aC[ZR][KSC], aN[ZR][KSC];
    long tile = (long)blockIdx.x;
    if (tile < NTILE) {
        const unsigned short* ab =
            A + (size_t)(tile * TM + w * (ZR * 16) + m15) * Kp + q * 8;
#pragma unroll
        for (int zr = 0; zr < ZR; ++zr)
#pragma unroll
            for (int ks = 0; ks < KSC; ++ks)
                aC[zr][ks] = *(const v8s*)(ab + (size_t)zr * 16 * Kp + ks * 32);
    }
    for (; tile < NTILE; tile += gridDim.x) {
        f32x4 acc[ZR][NF];
#pragma unroll
        for (int zr = 0; zr < ZR; ++zr)
#pragma unroll
            for (int nf = 0; nf < NF; ++nf) acc[zr][nf] = 0.f;
        for (int c = 0; c < CPT; ++c) {
            // issue next chunk's A loads before consuming the current chunk
            const long ntile = (c + 1 < CPT) ? tile : tile + (long)gridDim.x;
            const int nk0 = (c + 1 < CPT) ? (c + 1) * KSC : 0;
            const bool hasNext = (ntile < NTILE);
            if (hasNext) {
                const unsigned short* ab =
                    A + (size_t)(ntile * TM + w * (ZR * 16) + m15) * Kp + nk0 * 32 + q * 8;
#pragma unroll
                for (int zr = 0; zr < ZR; ++zr)
#pragma unroll
                    for (int ks = 0; ks < KSC; ++ks)
                        aN[zr][ks] = *(const v8s*)(ab + (size_t)zr * 16 * Kp + ks * 32);
            }
#pragma unroll
            for (int nf = 0; nf < NF; ++nf) {
                v8s wr[KSC];
#pragma unroll
                for (int ks = 0; ks < KSC; ++ks)
                    wr[ks] = *(const v8s*)(&Ws[(nf * 16 + m15) * KL + (c * KSC + ks) * 32 + q * 8]);
#pragma unroll
                for (int ks = 0; ks < KSC; ++ks)
#pragma unroll
                    for (int zr = 0; zr < ZR; ++zr)
                        acc[zr][nf] = __builtin_amdgcn_mfma_f32_16x16x32_bf16(
                            wr[ks], aC[zr][ks], acc[zr][nf], 0, 0, 0);
            }
            if (hasNext) {
#pragma unroll
                for (int zr = 0; zr < ZR; ++zr)
#pragma unroll
                    for (int ks = 0; ks < KSC; ++ks) aC[zr][ks] = aN[zr][ks];
            }
        }
        // ---- epilogue: bias + relu + store ----
#pragma unroll
        for (int zr = 0; zr < ZR; ++zr) {
            const long m = tile * TM + w * (ZR * 16) + zr * 16 + m15;
#pragma unroll
            for (int nf = 0; nf < NF; ++nf) {
                f32x4 b4 = *(const f32x4*)(&bs[nf * 16 + q * 4]);
                f32x4 cc = acc[zr][nf];
                float v0 = fmaxf(cc[0] + b4[0], 0.f), v1 = fmaxf(cc[1] + b4[1], 0.f);
                float v2 = fmaxf(cc[2] + b4[2], 0.f), v3 = fmaxf(cc[3] + b4[3], 0.f);
                if (!FLAT) {
                    ushort4 o; o.x = f2bf(v0); o.y = f2bf(v1); o.z = f2bf(v2); o.w = f2bf(v3);
                    *(ushort4*)(Hout + (size_t)m * Np + n0 + nf * 16 + q * 4) = o;
                } else {
                    const int n0f = nf * 16 + q * 4;   // FLAT only with NSPLIT=1
                    if (n0f <= 48) {
                        const long s = m / 20; const int u = (int)(m - s * 20);
                        unsigned short* base = Hout + (size_t)s * 1024 + u * 50 + n0f;
                        unsigned int lo = (unsigned int)f2bf(v0) | ((unsigned int)f2bf(v1) << 16);
                        *(unsigned int*)(base) = lo;
                        if (n0f < 48) {
                            unsigned int hi = (unsigned int)f2bf(v2) | ((unsigned int)f2bf(v3) << 16);
                            *(unsigned int*)(base + 2) = hi;
                        }
                    }
                }
            }
        }
    }
}

// logits = W5 h4 + b5; softmax -> out. h4 in g_bufA (112-padded rows).
__global__ __launch_bounds__(256)
void head_kernel(const float* __restrict__ W5, const float* __restrict__ b5,
                 float* __restrict__ out) {
    __shared__ float w5s[300];
    __shared__ float b5s[3];
    const int t = threadIdx.x;
    for (int i = t; i < 300; i += 256) w5s[i] = W5[i];
    if (t < 3) b5s[t] = b5[t];
    __syncthreads();
    const int s = blockIdx.x * 256 + t;
    const unsigned short* h = g_bufA + (size_t)s * 112;
    float a0 = b5s[0], a1 = b5s[1], a2 = b5s[2];
    for (int k = 0; k < 100; ++k) {
        float hv = bf2f(h[k]);
        a0 += hv * w5s[k]; a1 += hv * w5s[100 + k]; a2 += hv * w5s[200 + k];
    }
    float m = fmaxf(a0, fmaxf(a1, a2));
    float e0 = expf(a0 - m), e1 = expf(a1 - m), e2 = expf(a2 - m);
    float inv = 1.f / (e0 + e1 + e2);
    out[(size_t)s * 3 + 0] = e0 * inv;
    out[(size_t)s * 3 + 1] = e1 * inv;
    out[(size_t)s * 3 + 2] = e2 * inv;
}

extern "C" void kernel_launch(void* const* d_in, const int* in_sizes, int n_in,
                              void* d_out, int out_size, void* d_ws, size_t ws_size,
                              hipStream_t stream) {
    const float* x  = (const float*)d_in[0];
    const float* W1 = (const float*)d_in[1];
    const float* b1 = (const float*)d_in[2];
    const float* W2 = (const float*)d_in[3];
    const float* b2 = (const float*)d_in[4];
    const float* W3 = (const float*)d_in[5];
    const float* b3 = (const float*)d_in[6];
    const float* W4 = (const float*)d_in[7];
    const float* b4 = (const float*)d_in[8];
    const float* W5 = (const float*)d_in[9];
    const float* b5 = (const float*)d_in[10];
    float* out = (float*)d_out;

    zero_C_kernel<<<3, P * P, 0, stream>>>();
    prep_kernel<<<256, 256, 0, stream>>>(W1, b1, W2, b2, W3, b3, W4, b4);

    knn1_mfma_kernel<<<BB / 16, NT, 0, stream>>>(x);                 // x -> C0
    agg_mfma_kernel<128, true, 0><<<BB / 8, 512, 0, stream>>>(x);    // x -> z1(A)
    // W slice 160x136 bf16 in LDS (42.5KB); NSPLIT=2 (z1 84MB, L3-resident);
    // 512 blocks x 5 tiles, full-K hoist (KSC=KS=4) + cross-tile prefetch.
    gemm_kernel<128, 320, 2, false, 1, true, 2, 4, 256, 327680L>
        <<<dim3(512, 2), 256, 0, stream>>>();                        // z1 -> h1(B)

    knn_mfma_kernel<320, 1><<<BB / 16, NT, 0, stream>>>();           // h1 -> C1
    agg_mfma_kernel<320, false, 1><<<BB / 8, 512, 0, stream>>>(nullptr); // h1 -> z2(A)
    // round-12: canonical LDS-staged tile GEMM, 2560 blocks x 1 tile.
    gemm2_kernel<<<2560, 256, 0, stream>>>();                        // z2 -> h2(B)

    knn_mfma_kernel<128, 2><<<BB / 16, NT, 0, stream>>>();           // h2 -> C2
    agg_mfma_kernel<128, false, 2><<<BB / 8, 512, 0, stream>>>(nullptr); // h2 -> z3(A)
    gemm_kernel<128, 64, 2, true, 3, true, 1, 4, 256, 327680L>
        <<<dim3(512, 1), 256, 0, stream>>>();                        // z3 -> h3f(B)

    // NSPLIT=7 (h3f 33MB L3-resident); W slice 16x1032 (33KB); chunked K.
    gemm_kernel<1024, 112, 1, false, 4, false, 7, 8, 256, 16384L>
        <<<dim3(256, 7), 256, 0, stream>>>();                        // h3f -> h4(A)
    head_kernel<<<BB / 256, 256, 0, stream>>>(W5, b5, out);
}

// Round 7
// 943.051 us; speedup vs baseline: 1.3422x; 1.0673x over previous
//
#include <hip/hip_runtime.h>
#include <math.h>

#define BB 16384
#define P 20
#define NT 512

typedef short v8s __attribute__((ext_vector_type(8)));
typedef _Float16 v8h __attribute__((ext_vector_type(8)));
typedef float f32x4 __attribute__((ext_vector_type(4)));
typedef float f32x16 __attribute__((ext_vector_type(16)));

// ---- static device buffers: referenced ONLY inside device code (never passed
// as kernel args from host — that passes the host shadow and faults). ----
// +4096 pad: knn_mfma/agg_mfma read rows u=20..31 of the last samples (garbage,
// multiplied by zero-padded M columns / never stored).
#define NELEM ((size_t)BB * P * 320)          // 209.7 MB each
__device__ unsigned int g_C[3][P * P];
__device__ __align__(16) unsigned short g_bufA[NELEM + 4096];  // z1 / y2(f32) / y3(f32) / h4
__device__ __align__(16) unsigned short g_bufB[NELEM + 4096];  // h1 / h2 / h3f
__device__ __align__(16) unsigned short g_W1b[320 * 128];
__device__ __align__(16) unsigned short g_W2b[128 * 320];
__device__ __align__(16) unsigned short g_W3b[64 * 128];
__device__ __align__(16) unsigned short g_W4b[112 * 1024];
__device__ __align__(16) float g_b1p[320];
__device__ __align__(16) float g_b2p[128];
__device__ __align__(16) float g_b3p[64];
__device__ __align__(16) float g_b4p[112];

__device__ inline float bf2f(unsigned short u) {
    union { unsigned int i; float f; } c; c.i = ((unsigned int)u) << 16; return c.f;
}
__device__ inline unsigned short f2bf(float f) {
    union { float f; unsigned int i; } c; c.f = f;
    unsigned int u = c.i + 0x7fffu + ((c.i >> 16) & 1u);  // RNE (no NaN in data)
    return (unsigned short)(u >> 16);
}

__global__ void zero_C_kernel() { g_C[blockIdx.x][threadIdx.x] = 0u; }

// Pad+convert weights/biases to bf16 (zero pads -> pad outputs relu(0+0)=0).
__global__ void prep_kernel(const float* __restrict__ W1, const float* __restrict__ b1,
                            const float* __restrict__ W2, const float* __restrict__ b2,
                            const float* __restrict__ W3, const float* __restrict__ b3,
                            const float* __restrict__ W4, const float* __restrict__ b4) {
    const int stride = gridDim.x * blockDim.x;
    const int id = blockIdx.x * blockDim.x + threadIdx.x;
    for (int i = id; i < 320 * 128; i += stride) { int n = i >> 7, k = i & 127;
        g_W1b[i] = (n < 300) ? f2bf(W1[n * 128 + k]) : 0; }
    for (int i = id; i < 128 * 320; i += stride) { int n = i / 320, k = i - n * 320;
        g_W2b[i] = (n < 100 && k < 300) ? f2bf(W2[n * 300 + k]) : 0; }
    for (int i = id; i < 64 * 128; i += stride) { int n = i >> 7, k = i & 127;
        g_W3b[i] = (n < 50 && k < 100) ? f2bf(W3[n * 100 + k]) : 0; }
    for (int i = id; i < 112 * 1024; i += stride) { int n = i >> 10, k = i & 1023;
        g_W4b[i] = (n < 100 && k < 1000) ? f2bf(W4[n * 1000 + k]) : 0; }
    for (int i = id; i < 320; i += stride) g_b1p[i] = (i < 300) ? b1[i] : 0.f;
    for (int i = id; i < 128; i += stride) g_b2p[i] = (i < 100) ? b2[i] : 0.f;
    for (int i = id; i < 64;  i += stride) g_b3p[i] = (i < 50)  ? b3[i] : 0.f;
    for (int i = id; i < 112; i += stride) g_b4p[i] = (i < 100) ? b4[i] : 0.f;
}

// ---------------- kNN layer 1: MFMA Gram on fp16 hi/lo split (verified r8) --
__global__ __launch_bounds__(NT)
void knn1_mfma_kernel(const float* __restrict__ x) {
    __shared__ float Gs[8][P * 21];
    __shared__ unsigned int hist[P * P];
    const int t = threadIdx.x, w = t >> 6, lane = t & 63;
    const int m31 = lane & 31, half = lane >> 5;
    const int mrow = (m31 < P) ? m31 : (P - 1);
    for (int i = t; i < P * P; i += NT) hist[i] = 0;
    for (int pass = 0; pass < 2; ++pass) {
        const size_t s = (size_t)blockIdx.x * 16 + pass * 8 + w;
        const float* rp = x + s * (size_t)(P * 128) + (size_t)mrow * 128 + half * 8;
        f32x16 acc;
#pragma unroll
        for (int i = 0; i < 16; ++i) acc[i] = 0.f;
#pragma unroll
        for (int ks = 0; ks < 8; ++ks) {
            float4 f0 = *(const float4*)(rp + ks * 16);
            float4 f1 = *(const float4*)(rp + ks * 16 + 4);
            float fv[8] = {f0.x, f0.y, f0.z, f0.w, f1.x, f1.y, f1.z, f1.w};
            v8h hi, lo;
#pragma unroll
            for (int j = 0; j < 8; ++j) {
                _Float16 hv = (_Float16)fv[j];
                hi[j] = hv;
                lo[j] = (_Float16)(fv[j] - (float)hv);
            }
            acc = __builtin_amdgcn_mfma_f32_32x32x16_f16(hi, hi, acc, 0, 0, 0);
            acc = __builtin_amdgcn_mfma_f32_32x32x16_f16(hi, lo, acc, 0, 0, 0);
            acc = __builtin_amdgcn_mfma_f32_32x32x16_f16(lo, hi, acc, 0, 0, 0);
            acc = __builtin_amdgcn_mfma_f32_32x32x16_f16(lo, lo, acc, 0, 0, 0);
        }
        float* G = &Gs[w][0];
        if (m31 < P) {
#pragma unroll
            for (int r = 0; r < 16; ++r) {
                int row = (r & 3) + 8 * (r >> 2) + 4 * half;
                if (row < P) G[row * 21 + m31] = acc[r];
            }
        }
        __syncthreads();
        if (lane < P) {
            const int p = lane;
            float d2[P];
            const float gpp = G[p * 21 + p];
#pragma unroll
            for (int u = 0; u < P; ++u)
                d2[u] = (u == p) ? 0.f : gpp + G[u * 21 + u] - 2.f * G[p * 21 + u];
            float pv = -3.0e38f; int pi = -1;
            for (int it = 0; it < 6; ++it) {
                float best = 3.0e38f; int bq = 0;
#pragma unroll
                for (int u = 0; u < P; ++u) {
                    float vu = d2[u];
                    bool cand = (vu > pv) || (vu == pv && u > pi);
                    if (cand && vu < best) { best = vu; bq = u; }
                }
                if (it > 0) atomicAdd(&hist[bq * P + p], 1u);
                pv = best; pi = bq;
            }
        }
        __syncthreads();
    }
    if (t < P * P && hist[t]) atomicAdd(&g_C[0][t], hist[t]);
}

// ---------------- kNN via MFMA Gram: G = Z Z^T per sample (verified r6) -----
template<int D, int CIDX>
__global__ __launch_bounds__(NT)
void knn_mfma_kernel() {
    __shared__ float Gs[8][P * 21];
    __shared__ unsigned int hist[P * P];
    const int t = threadIdx.x, w = t >> 6, lane = t & 63;
    const int m31 = lane & 31, half = lane >> 5;
    for (int i = t; i < P * P; i += NT) hist[i] = 0;
    for (int pass = 0; pass < 2; ++pass) {
        const size_t s = (size_t)blockIdx.x * 16 + pass * 8 + w;
        const unsigned short* rp = g_bufB + s * (P * D) + (size_t)m31 * D + half * 8;
        f32x16 acc;
#pragma unroll
        for (int i = 0; i < 16; ++i) acc[i] = 0.f;
        for (int ks = 0; ks < D / 16; ++ks) {
            v8s z = *(const v8s*)(rp + ks * 16);
            acc = __builtin_amdgcn_mfma_f32_32x32x16_bf16(z, z, acc, 0, 0, 0);
        }
        float* G = &Gs[w][0];
        if (m31 < P) {
#pragma unroll
            for (int r = 0; r < 16; ++r) {
                int row = (r & 3) + 8 * (r >> 2) + 4 * half;
                if (row < P) G[row * 21 + m31] = acc[r];
            }
        }
        __syncthreads();
        if (lane < P) {
            const int p = lane;
            float d2[P];
            const float gpp = G[p * 21 + p];
#pragma unroll
            for (int u = 0; u < P; ++u)
                d2[u] = (u == p) ? 0.f : gpp + G[u * 21 + u] - 2.f * G[p * 21 + u];
            float pv = -3.0e38f; int pi = -1;
            for (int it = 0; it < 6; ++it) {
                float best = 3.0e38f; int bq = 0;
#pragma unroll
                for (int u = 0; u < P; ++u) {
                    float vu = d2[u];
                    bool cand = (vu > pv) || (vu == pv && u > pi);
                    if (cand && vu < best) { best = vu; bq = u; }
                }
                if (it > 0) atomicAdd(&hist[bq * P + p], 1u);
                pv = best; pi = bq;
            }
        }
        __syncthreads();
    }
    if (t < P * P && hist[t]) atomicAdd(&g_C[CIDX][t], hist[t]);
}

// compute_M for 512-thread blocks (strided loops)
__device__ inline void compute_M_512(const unsigned int* __restrict__ Cg,
                                     float* Ms, float* dinv, int t) {
    for (int i = t; i < P * P; i += 512) Ms[i] = (float)Cg[i];
    __syncthreads();
    if (t < P) {
        float deg = 1.f;
        for (int u = 0; u < P; ++u) deg += Ms[t * P + u];
        dinv[t] = 1.f / sqrtf(deg);
    }
    __syncthreads();
    for (int i = t; i < P * P; i += 512) {
        int v = i / P, u = i - v * P;
        float m = dinv[v] * Ms[i] * dinv[u];
        if (v == u) m += dinv[v] * dinv[v];
        Ms[i] = m;
    }
    __syncthreads();
}

// ---------------- agg via MFMA (verified r13): z1 = M @ x, layer 1 only -----
// A = M zero-padded to 32x32, bf16 hi/lo split; B built from x fp32 hi/lo.
// Operand maps ground-truthed vs knn_mfma. kc=1 row clamp to 19.
template<int D, int CIDX>
__global__ __launch_bounds__(512)
void agg_mfma_kernel(const float* __restrict__ xin) {
    constexpr int NCB = D / 32;              // 32-col blocks
    __shared__ float Ms[P * P];
    __shared__ float dinv[P];
    const int t = threadIdx.x, w = t >> 6, lane = t & 63;
    const int n31 = lane & 31, half = lane >> 5;
    compute_M_512(g_C[CIDX], Ms, dinv, t);
    v8s mhi[2], mlo[2];
#pragma unroll
    for (int kc = 0; kc < 2; ++kc)
#pragma unroll
        for (int j = 0; j < 8; ++j) {
            const int u = kc * 16 + half * 8 + j;
            const int v = n31;
            const float m = (v < P && u < P) ? Ms[v * P + u] : 0.f;
            const unsigned short h16 = f2bf(m);
            mhi[kc][j] = (short)h16;
            mlo[kc][j] = (short)f2bf(m - bf2f(h16));
        }
    const size_t s = (size_t)blockIdx.x * 8 + w;
    unsigned short* zout = g_bufA + s * (size_t)(P * D);
    const float* xr = xin + s * (size_t)(P * D);
#pragma unroll
    for (int cb = 0; cb < NCB; ++cb) {
        v8s bh0, bl0, bh1, bl1;
#pragma unroll
        for (int j = 0; j < 8; ++j) {
            const int u0 = half * 8 + j;                 // < 16, always valid
            int u1 = 16 + half * 8 + j; if (u1 > P - 1) u1 = P - 1;  // clamp
            const float x0 = xr[(size_t)u0 * D + cb * 32 + n31];
            const float x1 = xr[(size_t)u1 * D + cb * 32 + n31];
            const unsigned short h0 = f2bf(x0), h1 = f2bf(x1);
            bh0[j] = (short)h0; bl0[j] = (short)f2bf(x0 - bf2f(h0));
            bh1[j] = (short)h1; bl1[j] = (short)f2bf(x1 - bf2f(h1));
        }
        f32x16 acc;
#pragma unroll
        for (int i = 0; i < 16; ++i) acc[i] = 0.f;
        acc = __builtin_amdgcn_mfma_f32_32x32x16_bf16(mhi[0], bh0, acc, 0, 0, 0);
        acc = __builtin_amdgcn_mfma_f32_32x32x16_bf16(mhi[0], bl0, acc, 0, 0, 0);
        acc = __builtin_amdgcn_mfma_f32_32x32x16_bf16(mlo[0], bh0, acc, 0, 0, 0);
        acc = __builtin_amdgcn_mfma_f32_32x32x16_bf16(mlo[0], bl0, acc, 0, 0, 0);
        acc = __builtin_amdgcn_mfma_f32_32x32x16_bf16(mhi[1], bh1, acc, 0, 0, 0);
        acc = __builtin_amdgcn_mfma_f32_32x32x16_bf16(mhi[1], bl1, acc, 0, 0, 0);
        acc = __builtin_amdgcn_mfma_f32_32x32x16_bf16(mlo[1], bh1, acc, 0, 0, 0);
        acc = __builtin_amdgcn_mfma_f32_32x32x16_bf16(mlo[1], bl1, acc, 0, 0, 0);
#pragma unroll
        for (int r = 0; r < 16; ++r) {
            const int row = (r & 3) + 8 * (r >> 2) + 4 * half;
            if (row < P)
                zout[(size_t)row * D + cb * 32 + n31] = f2bf(acc[r]);
        }
    }
}

// ---------------- agg-after-gemm (round-14): h = relu(M @ y + b) ------------
// Linearity reorder: relu(M*h*W^T+b) == relu(M*(h*W^T)+b). The GEMM runs
// FIRST storing raw f32 y (no intermediate bf16 rounding -> strictly fewer
// roundings than the round-6 chain), then this kernel aggregates the SMALLER
// y (D=128/64 instead of 320/128), adds bias, relu, stores bf16 h.
// FLATOUT (layer 3): h3f packed rows s*1024 + v*50 + d, d<50.
template<int D, int CIDX, bool FLATOUT>
__global__ __launch_bounds__(512)
void agg_out_kernel() {
    constexpr int NCB = D / 32;
    __shared__ float Ms[P * P];
    __shared__ float dinv[P];
    const int t = threadIdx.x, w = t >> 6, lane = t & 63;
    const int n31 = lane & 31, half = lane >> 5;
    const float* __restrict__ bp = (CIDX == 1) ? g_b2p : g_b3p;
    compute_M_512(g_C[CIDX], Ms, dinv, t);
    v8s mhi[2], mlo[2];
#pragma unroll
    for (int kc = 0; kc < 2; ++kc)
#pragma unroll
        for (int j = 0; j < 8; ++j) {
            const int u = kc * 16 + half * 8 + j;
            const int v = n31;
            const float m = (v < P && u < P) ? Ms[v * P + u] : 0.f;
            const unsigned short h16 = f2bf(m);
            mhi[kc][j] = (short)h16;
            mlo[kc][j] = (short)f2bf(m - bf2f(h16));
        }
    const size_t s = (size_t)blockIdx.x * 8 + w;
    const float* yr = (const float*)g_bufA + s * (size_t)(P * D);
#pragma unroll
    for (int cb = 0; cb < NCB; ++cb) {
        v8s bh0, bl0, bh1, bl1;
#pragma unroll
        for (int j = 0; j < 8; ++j) {
            const int u0 = half * 8 + j;                 // < 16, always valid
            int u1 = 16 + half * 8 + j; if (u1 > P - 1) u1 = P - 1;  // clamp
            const float x0 = yr[(size_t)u0 * D + cb * 32 + n31];
            const float x1 = yr[(size_t)u1 * D + cb * 32 + n31];
            const unsigned short h0 = f2bf(x0), h1 = f2bf(x1);
            bh0[j] = (short)h0; bl0[j] = (short)f2bf(x0 - bf2f(h0));
            bh1[j] = (short)h1; bl1[j] = (short)f2bf(x1 - bf2f(h1));
        }
        f32x16 acc;
#pragma unroll
        for (int i = 0; i < 16; ++i) acc[i] = 0.f;
        acc = __builtin_amdgcn_mfma_f32_32x32x16_bf16(mhi[0], bh0, acc, 0, 0, 0);
        acc = __builtin_amdgcn_mfma_f32_32x32x16_bf16(mhi[0], bl0, acc, 0, 0, 0);
        acc = __builtin_amdgcn_mfma_f32_32x32x16_bf16(mlo[0], bh0, acc, 0, 0, 0);
        acc = __builtin_amdgcn_mfma_f32_32x32x16_bf16(mlo[0], bl0, acc, 0, 0, 0);
        acc = __builtin_amdgcn_mfma_f32_32x32x16_bf16(mhi[1], bh1, acc, 0, 0, 0);
        acc = __builtin_amdgcn_mfma_f32_32x32x16_bf16(mhi[1], bl1, acc, 0, 0, 0);
        acc = __builtin_amdgcn_mfma_f32_32x32x16_bf16(mlo[1], bh1, acc, 0, 0, 0);
        acc = __builtin_amdgcn_mfma_f32_32x32x16_bf16(mlo[1], bl1, acc, 0, 0, 0);
        const float bv = bp[cb * 32 + n31];
#pragma unroll
        for (int r = 0; r < 16; ++r) {
            const int row = (r & 3) + 8 * (r >> 2) + 4 * half;
            if (row < P) {
                const float val = fmaxf(acc[r] + bv, 0.f);
                if (FLATOUT) {
                    const int d = cb * 32 + n31;
                    if (d < 50)
                        g_bufB[s * 1024 + (size_t)row * 50 + d] = f2bf(val);
                } else {
                    g_bufB[(s * (size_t)P + row) * D + cb * 32 + n31] = f2bf(val);
                }
            }
        }
    }
}

// ---------------- gemm2' (round-14): y2 = h1 @ W2^T, raw f32 out ------------
// Canonical LDS-staged tile (verified r12 shape). Input h1 (bufB), output
// raw f32 y2 (bufA) — no bias/relu (moved into agg_out).
__global__ __launch_bounds__(256)
void gemm2_kernel() {
    constexpr int KL = 72;                   // padded LDS row, elems
    __shared__ __align__(16) unsigned short As[128 * KL];
    __shared__ __align__(16) unsigned short Wsh[128 * KL];
    const int t = threadIdx.x, w = t >> 6, lane = t & 63;
    const int m15 = lane & 15, q = lane >> 4;
    const long row0 = (long)blockIdx.x * 128;
    f32x4 acc[2][8];
#pragma unroll
    for (int zr = 0; zr < 2; ++zr)
#pragma unroll
        for (int nf = 0; nf < 8; ++nf) acc[zr][nf] = 0.f;
    for (int kc = 0; kc < 5; ++kc) {         // K chunks of 64 elems
        __syncthreads();                     // guard LDS reuse
        for (int i = t; i < 1024; i += 256) {
            const int r = i >> 3, c8 = i & 7;
            *(v8s*)&As[r * KL + c8 * 8] =
                *(const v8s*)(g_bufB + (size_t)(row0 + r) * 320 + kc * 64 + c8 * 8);
            *(v8s*)&Wsh[r * KL + c8 * 8] =
                *(const v8s*)(g_W2b + (size_t)r * 320 + kc * 64 + c8 * 8);
        }
        __syncthreads();
#pragma unroll
        for (int ks = 0; ks < 2; ++ks) {     // 32-elem MFMA sub-steps
            v8s af[2];
#pragma unroll
            for (int zr = 0; zr < 2; ++zr)
                af[zr] = *(const v8s*)&As[(w * 32 + zr * 16 + m15) * KL + ks * 32 + q * 8];
#pragma unroll
            for (int nf = 0; nf < 8; ++nf) {
                v8s wf = *(const v8s*)&Wsh[(nf * 16 + m15) * KL + ks * 32 + q * 8];
#pragma unroll
                for (int zr = 0; zr < 2; ++zr)
                    acc[zr][nf] = __builtin_amdgcn_mfma_f32_16x16x32_bf16(
                        wf, af[zr], acc[zr][nf], 0, 0, 0);
            }
        }
    }
    float* yf = (float*)g_bufA;
#pragma unroll
    for (int zr = 0; zr < 2; ++zr) {
        const long m = row0 + w * 32 + zr * 16 + m15;
#pragma unroll
        for (int nf = 0; nf < 8; ++nf)
            *(f32x4*)(yf + (size_t)m * 128 + nf * 16 + q * 4) = acc[zr][nf];
    }
}

// ---------------- streaming MFMA GEMM (round-11 form; + RAWF32 f32-out) -----
template<int Kp, int Np, int ZR, bool FLAT, int WSEL, bool ATOB, int NSPLIT,
         int KSC, int NTHR, long MROWS, bool RAWF32>
__global__ __launch_bounds__(NTHR)
void gemm_kernel() {
    constexpr int BN = Np / NSPLIT;          // cols handled by this block
    constexpr int NF = BN / 16;
    constexpr int KS = Kp / 32;
    constexpr int CPT = KS / KSC;            // chunks per tile
    constexpr int KL = Kp + 8;               // padded LDS row (elems, 16B step)
    constexpr int NW = NTHR / 64;
    constexpr int TM = NW * ZR * 16;         // rows per tile
    constexpr long NTILE = MROWS / TM;
    static_assert(KS % KSC == 0, "KSC must divide KS");
    __shared__ __align__(16) unsigned short Ws[BN * KL];
    __shared__ __align__(16) float bs[BN];
    const unsigned short* __restrict__ Wb =
        (WSEL == 1) ? g_W1b : (WSEL == 2) ? g_W2b : (WSEL == 3) ? g_W3b : g_W4b;
    const float* __restrict__ bp =
        (WSEL == 1) ? g_b1p : (WSEL == 2) ? g_b2p : (WSEL == 3) ? g_b3p : g_b4p;
    const unsigned short* __restrict__ A = ATOB ? g_bufA : g_bufB;
    unsigned short* __restrict__ Hout = ATOB ? g_bufB : g_bufA;
    const int t = threadIdx.x, w = t >> 6, lane = t & 63;
    const int m15 = lane & 15, q = lane >> 4;
    const int n0 = blockIdx.y * BN;
    // ---- stage W slice + bias to LDS (once per block) ----
    for (int i = t; i < BN * (Kp / 8); i += NTHR) {
        int r = i / (Kp / 8), c = i - r * (Kp / 8);
        *(v8s*)(&Ws[r * KL + c * 8]) = *(const v8s*)(Wb + (size_t)(n0 + r) * Kp + c * 8);
    }
    for (int i = t; i < BN; i += NTHR) bs[i] = bp[n0 + i];
    __syncthreads();

    v8s aC[ZR][KSC], aN[ZR][KSC];
    long tile = (long)blockIdx.x;
    if (tile < NTILE) {
        const unsigned short* ab =
            A + (size_t)(tile * TM + w * (ZR * 16) + m15) * Kp + q * 8;
#pragma unroll
        for (int zr = 0; zr < ZR; ++zr)
#pragma unroll
            for (int ks = 0; ks < KSC; ++ks)
                aC[zr][ks] = *(const v8s*)(ab + (size_t)zr * 16 * Kp + ks * 32);
    }
    for (; tile < NTILE; tile += gridDim.x) {
        f32x4 acc[ZR][NF];
#pragma unroll
        for (int zr = 0; zr < ZR; ++zr)
#pragma unroll
            for (int nf = 0; nf < NF; ++nf) acc[zr][nf] = 0.f;
        for (int c = 0; c < CPT; ++c) {
            // issue next chunk's A loads before consuming the current chunk
            const long ntile = (c + 1 < CPT) ? tile : tile + (long)gridDim.x;
            const int nk0 = (c + 1 < CPT) ? (c + 1) * KSC : 0;
            const bool hasNext = (ntile < NTILE);
            if (hasNext) {
                const unsigned short* ab =
                    A + (size_t)(ntile * TM + w * (ZR * 16) + m15) * Kp + nk0 * 32 + q * 8;
#pragma unroll
                for (int zr = 0; zr < ZR; ++zr)
#pragma unroll
                    for (int ks = 0; ks < KSC; ++ks)
                        aN[zr][ks] = *(const v8s*)(ab + (size_t)zr * 16 * Kp + ks * 32);
            }
#pragma unroll
            for (int nf = 0; nf < NF; ++nf) {
                v8s wr[KSC];
#pragma unroll
                for (int ks = 0; ks < KSC; ++ks)
                    wr[ks] = *(const v8s*)(&Ws[(nf * 16 + m15) * KL + (c * KSC + ks) * 32 + q * 8]);
#pragma unroll
                for (int ks = 0; ks < KSC; ++ks)
#pragma unroll
                    for (int zr = 0; zr < ZR; ++zr)
                        acc[zr][nf] = __builtin_amdgcn_mfma_f32_16x16x32_bf16(
                            wr[ks], aC[zr][ks], acc[zr][nf], 0, 0, 0);
            }
            if (hasNext) {
#pragma unroll
                for (int zr = 0; zr < ZR; ++zr)
#pragma unroll
                    for (int ks = 0; ks < KSC; ++ks) aC[zr][ks] = aN[zr][ks];
            }
        }
        // ---- epilogue ----
#pragma unroll
        for (int zr = 0; zr < ZR; ++zr) {
            const long m = tile * TM + w * (ZR * 16) + zr * 16 + m15;
#pragma unroll
            for (int nf = 0; nf < NF; ++nf) {
                f32x4 cc = acc[zr][nf];
                if (RAWF32) {
                    float* fH = (float*)Hout;
                    *(f32x4*)(fH + (size_t)m * Np + n0 + nf * 16 + q * 4) = cc;
                } else {
                    f32x4 b4 = *(const f32x4*)(&bs[nf * 16 + q * 4]);
                    float v0 = fmaxf(cc[0] + b4[0], 0.f), v1 = fmaxf(cc[1] + b4[1], 0.f);
                    float v2 = fmaxf(cc[2] + b4[2], 0.f), v3 = fmaxf(cc[3] + b4[3], 0.f);
                    if (!FLAT) {
                        ushort4 o; o.x = f2bf(v0); o.y = f2bf(v1); o.z = f2bf(v2); o.w = f2bf(v3);
                        *(ushort4*)(Hout + (size_t)m * Np + n0 + nf * 16 + q * 4) = o;
                    } else {
                        const int n0f = nf * 16 + q * 4;   // FLAT only with NSPLIT=1
                        if (n0f <= 48) {
                            const long s = m / 20; const int u = (int)(m - s * 20);
                            unsigned short* base = Hout + (size_t)s * 1024 + u * 50 + n0f;
                            unsigned int lo = (unsigned int)f2bf(v0) | ((unsigned int)f2bf(v1) << 16);
                            *(unsigned int*)(base) = lo;
                            if (n0f < 48) {
                                unsigned int hi = (unsigned int)f2bf(v2) | ((unsigned int)f2bf(v3) << 16);
                                *(unsigned int*)(base + 2) = hi;
                            }
                        }
                    }
                }
            }
        }
    }
}

// logits = W5 h4 + b5; softmax -> out. h4 in g_bufA (112-padded rows).
__global__ __launch_bounds__(256)
void head_kernel(const float* __restrict__ W5, const float* __restrict__ b5,
                 float* __restrict__ out) {
    __shared__ float w5s[300];
    __shared__ float b5s[3];
    const int t = threadIdx.x;
    for (int i = t; i < 300; i += 256) w5s[i] = W5[i];
    if (t < 3) b5s[t] = b5[t];
    __syncthreads();
    const int s = blockIdx.x * 256 + t;
    const unsigned short* h = g_bufA + (size_t)s * 112;
    float a0 = b5s[0], a1 = b5s[1], a2 = b5s[2];
    for (int k = 0; k < 100; ++k) {
        float hv = bf2f(h[k]);
        a0 += hv * w5s[k]; a1 += hv * w5s[100 + k]; a2 += hv * w5s[200 + k];
    }
    float m = fmaxf(a0, fmaxf(a1, a2));
    float e0 = expf(a0 - m), e1 = expf(a1 - m), e2 = expf(a2 - m);
    float inv = 1.f / (e0 + e1 + e2);
    out[(size_t)s * 3 + 0] = e0 * inv;
    out[(size_t)s * 3 + 1] = e1 * inv;
    out[(size_t)s * 3 + 2] = e2 * inv;
}

extern "C" void kernel_launch(void* const* d_in, const int* in_sizes, int n_in,
                              void* d_out, int out_size, void* d_ws, size_t ws_size,
                              hipStream_t stream) {
    const float* x  = (const float*)d_in[0];
    const float* W1 = (const float*)d_in[1];
    const float* b1 = (const float*)d_in[2];
    const float* W2 = (const float*)d_in[3];
    const float* b2 = (const float*)d_in[4];
    const float* W3 = (const float*)d_in[5];
    const float* b3 = (const float*)d_in[6];
    const float* W4 = (const float*)d_in[7];
    const float* b4 = (const float*)d_in[8];
    const float* W5 = (const float*)d_in[9];
    const float* b5 = (const float*)d_in[10];
    float* out = (float*)d_out;

    zero_C_kernel<<<3, P * P, 0, stream>>>();
    prep_kernel<<<256, 256, 0, stream>>>(W1, b1, W2, b2, W3, b3, W4, b4);

    // ---- layer 1 (agg-then-gemm; x is fp32 so reordering would balloon y1) --
    knn1_mfma_kernel<<<BB / 16, NT, 0, stream>>>(x);                 // x -> C0
    agg_mfma_kernel<128, 0><<<BB / 8, 512, 0, stream>>>(x);          // x -> z1(A)
    gemm_kernel<128, 320, 2, false, 1, true, 2, 4, 256, 327680L, false>
        <<<dim3(512, 2), 256, 0, stream>>>();                        // z1 -> h1(B)

    // ---- layer 2 (reordered: gemm first, agg on smaller y2) ----
    knn_mfma_kernel<320, 1><<<BB / 16, NT, 0, stream>>>();           // h1 -> C1
    gemm2_kernel<<<2560, 256, 0, stream>>>();                        // h1 -> y2 f32 (A)
    agg_out_kernel<128, 1, false><<<BB / 8, 512, 0, stream>>>();     // y2 -> h2(B)

    // ---- layer 3 (reordered) ----
    knn_mfma_kernel<128, 2><<<BB / 16, NT, 0, stream>>>();           // h2 -> C2
    gemm_kernel<128, 64, 2, false, 3, false, 1, 4, 256, 327680L, true>
        <<<dim3(512, 1), 256, 0, stream>>>();                        // h2 -> y3 f32 (A)
    agg_out_kernel<64, 2, true><<<BB / 8, 512, 0, stream>>>();       // y3 -> h3f(B) FLAT

    // ---- head MLP ----
    gemm_kernel<1024, 112, 1, false, 4, false, 7, 8, 256, 16384L, false>
        <<<dim3(256, 7), 256, 0, stream>>>();                        // h3f -> h4(A)
    head_kernel<<<BB / 256, 256, 0, stream>>>(W5, b5, out);
}

// Round 8
// 887.404 us; speedup vs baseline: 1.4264x; 1.0627x over previous
//
#include <hip/hip_runtime.h>
#include <math.h>

#define BB 16384
#define P 20
#define NT 512

typedef short v8s __attribute__((ext_vector_type(8)));
typedef _Float16 v8h __attribute__((ext_vector_type(8)));
typedef float f32x4 __attribute__((ext_vector_type(4)));
typedef float f32x16 __attribute__((ext_vector_type(16)));

// ---- static device buffers: referenced ONLY inside device code (never passed
// as kernel args from host — that passes the host shadow and faults). ----
// +4096 pad: knn_mfma/agg_mfma read rows u=20..31 of the last samples (garbage,
// multiplied by zero-padded M columns / never stored).
#define NELEM ((size_t)BB * P * 320)          // 209.7 MB each
__device__ unsigned int g_C[3][P * P];
__device__ __align__(16) unsigned short g_bufA[NELEM + 4096];  // z1 / y2(f32) / y3(f32) / h4
__device__ __align__(16) unsigned short g_bufB[NELEM + 4096];  // h1 / h2 / h3f
__device__ __align__(16) unsigned short g_W1b[320 * 128];
__device__ __align__(16) unsigned short g_W2b[128 * 320];
__device__ __align__(16) unsigned short g_W3b[64 * 128];
__device__ __align__(16) unsigned short g_W4b[112 * 1024];
__device__ __align__(16) float g_b1p[320];
__device__ __align__(16) float g_b2p[128];
__device__ __align__(16) float g_b3p[64];
__device__ __align__(16) float g_b4p[112];

__device__ inline float bf2f(unsigned short u) {
    union { unsigned int i; float f; } c; c.i = ((unsigned int)u) << 16; return c.f;
}
__device__ inline unsigned short f2bf(float f) {
    union { float f; unsigned int i; } c; c.f = f;
    unsigned int u = c.i + 0x7fffu + ((c.i >> 16) & 1u);  // RNE (no NaN in data)
    return (unsigned short)(u >> 16);
}

__global__ void zero_C_kernel() { g_C[blockIdx.x][threadIdx.x] = 0u; }

// Pad+convert weights/biases to bf16 (zero pads -> pad outputs relu(0+0)=0).
__global__ void prep_kernel(const float* __restrict__ W1, const float* __restrict__ b1,
                            const float* __restrict__ W2, const float* __restrict__ b2,
                            const float* __restrict__ W3, const float* __restrict__ b3,
                            const float* __restrict__ W4, const float* __restrict__ b4) {
    const int stride = gridDim.x * blockDim.x;
    const int id = blockIdx.x * blockDim.x + threadIdx.x;
    for (int i = id; i < 320 * 128; i += stride) { int n = i >> 7, k = i & 127;
        g_W1b[i] = (n < 300) ? f2bf(W1[n * 128 + k]) : 0; }
    for (int i = id; i < 128 * 320; i += stride) { int n = i / 320, k = i - n * 320;
        g_W2b[i] = (n < 100 && k < 300) ? f2bf(W2[n * 300 + k]) : 0; }
    for (int i = id; i < 64 * 128; i += stride) { int n = i >> 7, k = i & 127;
        g_W3b[i] = (n < 50 && k < 100) ? f2bf(W3[n * 100 + k]) : 0; }
    for (int i = id; i < 112 * 1024; i += stride) { int n = i >> 10, k = i & 1023;
        g_W4b[i] = (n < 100 && k < 1000) ? f2bf(W4[n * 1000 + k]) : 0; }
    for (int i = id; i < 320; i += stride) g_b1p[i] = (i < 300) ? b1[i] : 0.f;
    for (int i = id; i < 128; i += stride) g_b2p[i] = (i < 100) ? b2[i] : 0.f;
    for (int i = id; i < 64;  i += stride) g_b3p[i] = (i < 50)  ? b3[i] : 0.f;
    for (int i = id; i < 112; i += stride) g_b4p[i] = (i < 100) ? b4[i] : 0.f;
}

// ---------------- kNN layer 1: MFMA Gram on fp16 hi/lo split (verified r8) --
__global__ __launch_bounds__(NT)
void knn1_mfma_kernel(const float* __restrict__ x) {
    __shared__ float Gs[8][P * 21];
    __shared__ unsigned int hist[P * P];
    const int t = threadIdx.x, w = t >> 6, lane = t & 63;
    const int m31 = lane & 31, half = lane >> 5;
    const int mrow = (m31 < P) ? m31 : (P - 1);
    for (int i = t; i < P * P; i += NT) hist[i] = 0;
    for (int pass = 0; pass < 2; ++pass) {
        const size_t s = (size_t)blockIdx.x * 16 + pass * 8 + w;
        const float* rp = x + s * (size_t)(P * 128) + (size_t)mrow * 128 + half * 8;
        f32x16 acc;
#pragma unroll
        for (int i = 0; i < 16; ++i) acc[i] = 0.f;
#pragma unroll
        for (int ks = 0; ks < 8; ++ks) {
            float4 f0 = *(const float4*)(rp + ks * 16);
            float4 f1 = *(const float4*)(rp + ks * 16 + 4);
            float fv[8] = {f0.x, f0.y, f0.z, f0.w, f1.x, f1.y, f1.z, f1.w};
            v8h hi, lo;
#pragma unroll
            for (int j = 0; j < 8; ++j) {
                _Float16 hv = (_Float16)fv[j];
                hi[j] = hv;
                lo[j] = (_Float16)(fv[j] - (float)hv);
            }
            acc = __builtin_amdgcn_mfma_f32_32x32x16_f16(hi, hi, acc, 0, 0, 0);
            acc = __builtin_amdgcn_mfma_f32_32x32x16_f16(hi, lo, acc, 0, 0, 0);
            acc = __builtin_amdgcn_mfma_f32_32x32x16_f16(lo, hi, acc, 0, 0, 0);
            acc = __builtin_amdgcn_mfma_f32_32x32x16_f16(lo, lo, acc, 0, 0, 0);
        }
        float* G = &Gs[w][0];
        if (m31 < P) {
#pragma unroll
            for (int r = 0; r < 16; ++r) {
                int row = (r & 3) + 8 * (r >> 2) + 4 * half;
                if (row < P) G[row * 21 + m31] = acc[r];
            }
        }
        __syncthreads();
        if (lane < P) {
            const int p = lane;
            float d2[P];
            const float gpp = G[p * 21 + p];
#pragma unroll
            for (int u = 0; u < P; ++u)
                d2[u] = (u == p) ? 0.f : gpp + G[u * 21 + u] - 2.f * G[p * 21 + u];
            float pv = -3.0e38f; int pi = -1;
            for (int it = 0; it < 6; ++it) {
                float best = 3.0e38f; int bq = 0;
#pragma unroll
                for (int u = 0; u < P; ++u) {
                    float vu = d2[u];
                    bool cand = (vu > pv) || (vu == pv && u > pi);
                    if (cand && vu < best) { best = vu; bq = u; }
                }
                if (it > 0) atomicAdd(&hist[bq * P + p], 1u);
                pv = best; pi = bq;
            }
        }
        __syncthreads();
    }
    if (t < P * P && hist[t]) atomicAdd(&g_C[0][t], hist[t]);
}

// ---------------- kNN via MFMA Gram: G = Z Z^T per sample (verified r6) -----
template<int D, int CIDX>
__global__ __launch_bounds__(NT)
void knn_mfma_kernel() {
    __shared__ float Gs[8][P * 21];
    __shared__ unsigned int hist[P * P];
    const int t = threadIdx.x, w = t >> 6, lane = t & 63;
    const int m31 = lane & 31, half = lane >> 5;
    for (int i = t; i < P * P; i += NT) hist[i] = 0;
    for (int pass = 0; pass < 2; ++pass) {
        const size_t s = (size_t)blockIdx.x * 16 + pass * 8 + w;
        const unsigned short* rp = g_bufB + s * (P * D) + (size_t)m31 * D + half * 8;
        f32x16 acc;
#pragma unroll
        for (int i = 0; i < 16; ++i) acc[i] = 0.f;
        for (int ks = 0; ks < D / 16; ++ks) {
            v8s z = *(const v8s*)(rp + ks * 16);
            acc = __builtin_amdgcn_mfma_f32_32x32x16_bf16(z, z, acc, 0, 0, 0);
        }
        float* G = &Gs[w][0];
        if (m31 < P) {
#pragma unroll
            for (int r = 0; r < 16; ++r) {
                int row = (r & 3) + 8 * (r >> 2) + 4 * half;
                if (row < P) G[row * 21 + m31] = acc[r];
            }
        }
        __syncthreads();
        if (lane < P) {
            const int p = lane;
            float d2[P];
            const float gpp = G[p * 21 + p];
#pragma unroll
            for (int u = 0; u < P; ++u)
                d2[u] = (u == p) ? 0.f : gpp + G[u * 21 + u] - 2.f * G[p * 21 + u];
            float pv = -3.0e38f; int pi = -1;
            for (int it = 0; it < 6; ++it) {
                float best = 3.0e38f; int bq = 0;
#pragma unroll
                for (int u = 0; u < P; ++u) {
                    float vu = d2[u];
                    bool cand = (vu > pv) || (vu == pv && u > pi);
                    if (cand && vu < best) { best = vu; bq = u; }
                }
                if (it > 0) atomicAdd(&hist[bq * P + p], 1u);
                pv = best; pi = bq;
            }
        }
        __syncthreads();
    }
    if (t < P * P && hist[t]) atomicAdd(&g_C[CIDX][t], hist[t]);
}

// compute_M for 512-thread blocks (strided loops)
__device__ inline void compute_M_512(const unsigned int* __restrict__ Cg,
                                     float* Ms, float* dinv, int t) {
    for (int i = t; i < P * P; i += 512) Ms[i] = (float)Cg[i];
    __syncthreads();
    if (t < P) {
        float deg = 1.f;
        for (int u = 0; u < P; ++u) deg += Ms[t * P + u];
        dinv[t] = 1.f / sqrtf(deg);
    }
    __syncthreads();
    for (int i = t; i < P * P; i += 512) {
        int v = i / P, u = i - v * P;
        float m = dinv[v] * Ms[i] * dinv[u];
        if (v == u) m += dinv[v] * dinv[v];
        Ms[i] = m;
    }
    __syncthreads();
}

// ---------------- agg via MFMA (verified r13): z1 = M @ x, layer 1 only -----
template<int D, int CIDX>
__global__ __launch_bounds__(512)
void agg_mfma_kernel(const float* __restrict__ xin) {
    constexpr int NCB = D / 32;              // 32-col blocks
    __shared__ float Ms[P * P];
    __shared__ float dinv[P];
    const int t = threadIdx.x, w = t >> 6, lane = t & 63;
    const int n31 = lane & 31, half = lane >> 5;
    compute_M_512(g_C[CIDX], Ms, dinv, t);
    v8s mhi[2], mlo[2];
#pragma unroll
    for (int kc = 0; kc < 2; ++kc)
#pragma unroll
        for (int j = 0; j < 8; ++j) {
            const int u = kc * 16 + half * 8 + j;
            const int v = n31;
            const float m = (v < P && u < P) ? Ms[v * P + u] : 0.f;
            const unsigned short h16 = f2bf(m);
            mhi[kc][j] = (short)h16;
            mlo[kc][j] = (short)f2bf(m - bf2f(h16));
        }
    const size_t s = (size_t)blockIdx.x * 8 + w;
    unsigned short* zout = g_bufA + s * (size_t)(P * D);
    const float* xr = xin + s * (size_t)(P * D);
#pragma unroll
    for (int cb = 0; cb < NCB; ++cb) {
        v8s bh0, bl0, bh1, bl1;
#pragma unroll
        for (int j = 0; j < 8; ++j) {
            const int u0 = half * 8 + j;                 // < 16, always valid
            int u1 = 16 + half * 8 + j; if (u1 > P - 1) u1 = P - 1;  // clamp
            const float x0 = xr[(size_t)u0 * D + cb * 32 + n31];
            const float x1 = xr[(size_t)u1 * D + cb * 32 + n31];
            const unsigned short h0 = f2bf(x0), h1 = f2bf(x1);
            bh0[j] = (short)h0; bl0[j] = (short)f2bf(x0 - bf2f(h0));
            bh1[j] = (short)h1; bl1[j] = (short)f2bf(x1 - bf2f(h1));
        }
        f32x16 acc;
#pragma unroll
        for (int i = 0; i < 16; ++i) acc[i] = 0.f;
        acc = __builtin_amdgcn_mfma_f32_32x32x16_bf16(mhi[0], bh0, acc, 0, 0, 0);
        acc = __builtin_amdgcn_mfma_f32_32x32x16_bf16(mhi[0], bl0, acc, 0, 0, 0);
        acc = __builtin_amdgcn_mfma_f32_32x32x16_bf16(mlo[0], bh0, acc, 0, 0, 0);
        acc = __builtin_amdgcn_mfma_f32_32x32x16_bf16(mlo[0], bl0, acc, 0, 0, 0);
        acc = __builtin_amdgcn_mfma_f32_32x32x16_bf16(mhi[1], bh1, acc, 0, 0, 0);
        acc = __builtin_amdgcn_mfma_f32_32x32x16_bf16(mhi[1], bl1, acc, 0, 0, 0);
        acc = __builtin_amdgcn_mfma_f32_32x32x16_bf16(mlo[1], bh1, acc, 0, 0, 0);
        acc = __builtin_amdgcn_mfma_f32_32x32x16_bf16(mlo[1], bl1, acc, 0, 0, 0);
#pragma unroll
        for (int r = 0; r < 16; ++r) {
            const int row = (r & 3) + 8 * (r >> 2) + 4 * half;
            if (row < P)
                zout[(size_t)row * D + cb * 32 + n31] = f2bf(acc[r]);
        }
    }
}

// ---------------- agg-after-gemm (verified r14): h = relu(M @ y + b) --------
template<int D, int CIDX, bool FLATOUT>
__global__ __launch_bounds__(512)
void agg_out_kernel() {
    constexpr int NCB = D / 32;
    __shared__ float Ms[P * P];
    __shared__ float dinv[P];
    const int t = threadIdx.x, w = t >> 6, lane = t & 63;
    const int n31 = lane & 31, half = lane >> 5;
    const float* __restrict__ bp = (CIDX == 1) ? g_b2p : g_b3p;
    compute_M_512(g_C[CIDX], Ms, dinv, t);
    v8s mhi[2], mlo[2];
#pragma unroll
    for (int kc = 0; kc < 2; ++kc)
#pragma unroll
        for (int j = 0; j < 8; ++j) {
            const int u = kc * 16 + half * 8 + j;
            const int v = n31;
            const float m = (v < P && u < P) ? Ms[v * P + u] : 0.f;
            const unsigned short h16 = f2bf(m);
            mhi[kc][j] = (short)h16;
            mlo[kc][j] = (short)f2bf(m - bf2f(h16));
        }
    const size_t s = (size_t)blockIdx.x * 8 + w;
    const float* yr = (const float*)g_bufA + s * (size_t)(P * D);
#pragma unroll
    for (int cb = 0; cb < NCB; ++cb) {
        v8s bh0, bl0, bh1, bl1;
#pragma unroll
        for (int j = 0; j < 8; ++j) {
            const int u0 = half * 8 + j;                 // < 16, always valid
            int u1 = 16 + half * 8 + j; if (u1 > P - 1) u1 = P - 1;  // clamp
            const float x0 = yr[(size_t)u0 * D + cb * 32 + n31];
            const float x1 = yr[(size_t)u1 * D + cb * 32 + n31];
            const unsigned short h0 = f2bf(x0), h1 = f2bf(x1);
            bh0[j] = (short)h0; bl0[j] = (short)f2bf(x0 - bf2f(h0));
            bh1[j] = (short)h1; bl1[j] = (short)f2bf(x1 - bf2f(h1));
        }
        f32x16 acc;
#pragma unroll
        for (int i = 0; i < 16; ++i) acc[i] = 0.f;
        acc = __builtin_amdgcn_mfma_f32_32x32x16_bf16(mhi[0], bh0, acc, 0, 0, 0);
        acc = __builtin_amdgcn_mfma_f32_32x32x16_bf16(mhi[0], bl0, acc, 0, 0, 0);
        acc = __builtin_amdgcn_mfma_f32_32x32x16_bf16(mlo[0], bh0, acc, 0, 0, 0);
        acc = __builtin_amdgcn_mfma_f32_32x32x16_bf16(mlo[0], bl0, acc, 0, 0, 0);
        acc = __builtin_amdgcn_mfma_f32_32x32x16_bf16(mhi[1], bh1, acc, 0, 0, 0);
        acc = __builtin_amdgcn_mfma_f32_32x32x16_bf16(mhi[1], bl1, acc, 0, 0, 0);
        acc = __builtin_amdgcn_mfma_f32_32x32x16_bf16(mlo[1], bh1, acc, 0, 0, 0);
        acc = __builtin_amdgcn_mfma_f32_32x32x16_bf16(mlo[1], bl1, acc, 0, 0, 0);
        const float bv = bp[cb * 32 + n31];
#pragma unroll
        for (int r = 0; r < 16; ++r) {
            const int row = (r & 3) + 8 * (r >> 2) + 4 * half;
            if (row < P) {
                const float val = fmaxf(acc[r] + bv, 0.f);
                if (FLATOUT) {
                    const int d = cb * 32 + n31;
                    if (d < 50)
                        g_bufB[s * 1024 + (size_t)row * 50 + d] = f2bf(val);
                } else {
                    g_bufB[(s * (size_t)P + row) * D + cb * 32 + n31] = f2bf(val);
                }
            }
        }
    }
}

// ---------------- gemm1 (round-15): canonical LDS-staged tile ---------------
// Round-7 lesson: the register-hoist form sat at VGPR=216 / LDS 43.5KB ->
// Occupancy 9.9%, 2.3 TB/s on a 295MB op. Canonical gemm2 structure instead:
// tile 128M x 160N (N-split 2 via blockIdx.y), K=128 chunked by 64; BOTH
// operands staged global->LDS (A 128x72 + W 160x72 = 41.5KB -> 3 blk/CU);
// acc 80 VGPR, no register A-hoist. z1 re-read x2 comes from L3 (84MB).
// K order (kc asc, ks asc) identical to round-7 -> bit-exact.
__global__ __launch_bounds__(256)
void gemm1_kernel() {
    constexpr int KL = 72;                   // padded LDS row, elems
    __shared__ __align__(16) unsigned short As[128 * KL];
    __shared__ __align__(16) unsigned short Wsh[160 * KL];
    const int t = threadIdx.x, w = t >> 6, lane = t & 63;
    const int m15 = lane & 15, q = lane >> 4;
    const long row0 = (long)blockIdx.x * 128;
    const int n0 = blockIdx.y * 160;
    f32x4 acc[2][10];
#pragma unroll
    for (int zr = 0; zr < 2; ++zr)
#pragma unroll
        for (int nf = 0; nf < 10; ++nf) acc[zr][nf] = 0.f;
    for (int kc = 0; kc < 2; ++kc) {         // K chunks of 64 elems
        __syncthreads();                     // guard LDS reuse
        for (int i = t; i < 1024; i += 256) {
            const int r = i >> 3, c8 = i & 7;
            *(v8s*)&As[r * KL + c8 * 8] =
                *(const v8s*)(g_bufA + (size_t)(row0 + r) * 128 + kc * 64 + c8 * 8);
        }
        for (int i = t; i < 1280; i += 256) {
            const int r = i >> 3, c8 = i & 7;
            *(v8s*)&Wsh[r * KL + c8 * 8] =
                *(const v8s*)(g_W1b + (size_t)(n0 + r) * 128 + kc * 64 + c8 * 8);
        }
        __syncthreads();
#pragma unroll
        for (int ks = 0; ks < 2; ++ks) {     // 32-elem MFMA sub-steps
            v8s af[2];
#pragma unroll
            for (int zr = 0; zr < 2; ++zr)
                af[zr] = *(const v8s*)&As[(w * 32 + zr * 16 + m15) * KL + ks * 32 + q * 8];
#pragma unroll
            for (int nf = 0; nf < 10; ++nf) {
                v8s wf = *(const v8s*)&Wsh[(nf * 16 + m15) * KL + ks * 32 + q * 8];
#pragma unroll
                for (int zr = 0; zr < 2; ++zr)
                    acc[zr][nf] = __builtin_amdgcn_mfma_f32_16x16x32_bf16(
                        wf, af[zr], acc[zr][nf], 0, 0, 0);
            }
        }
    }
#pragma unroll
    for (int zr = 0; zr < 2; ++zr) {
        const long m = row0 + w * 32 + zr * 16 + m15;
#pragma unroll
        for (int nf = 0; nf < 10; ++nf) {
            f32x4 b4 = *(const f32x4*)(g_b1p + n0 + nf * 16 + q * 4);
            f32x4 c = acc[zr][nf];
            float v0 = fmaxf(c[0] + b4[0], 0.f), v1 = fmaxf(c[1] + b4[1], 0.f);
            float v2 = fmaxf(c[2] + b4[2], 0.f), v3 = fmaxf(c[3] + b4[3], 0.f);
            ushort4 o; o.x = f2bf(v0); o.y = f2bf(v1); o.z = f2bf(v2); o.w = f2bf(v3);
            *(ushort4*)(g_bufB + (size_t)m * 320 + n0 + nf * 16 + q * 4) = o;
        }
    }
}

// ---------------- gemm2' (verified r14): y2 = h1 @ W2^T, raw f32 out --------
__global__ __launch_bounds__(256)
void gemm2_kernel() {
    constexpr int KL = 72;                   // padded LDS row, elems
    __shared__ __align__(16) unsigned short As[128 * KL];
    __shared__ __align__(16) unsigned short Wsh[128 * KL];
    const int t = threadIdx.x, w = t >> 6, lane = t & 63;
    const int m15 = lane & 15, q = lane >> 4;
    const long row0 = (long)blockIdx.x * 128;
    f32x4 acc[2][8];
#pragma unroll
    for (int zr = 0; zr < 2; ++zr)
#pragma unroll
        for (int nf = 0; nf < 8; ++nf) acc[zr][nf] = 0.f;
    for (int kc = 0; kc < 5; ++kc) {         // K chunks of 64 elems
        __syncthreads();                     // guard LDS reuse
        for (int i = t; i < 1024; i += 256) {
            const int r = i >> 3, c8 = i & 7;
            *(v8s*)&As[r * KL + c8 * 8] =
                *(const v8s*)(g_bufB + (size_t)(row0 + r) * 320 + kc * 64 + c8 * 8);
            *(v8s*)&Wsh[r * KL + c8 * 8] =
                *(const v8s*)(g_W2b + (size_t)r * 320 + kc * 64 + c8 * 8);
        }
        __syncthreads();
#pragma unroll
        for (int ks = 0; ks < 2; ++ks) {     // 32-elem MFMA sub-steps
            v8s af[2];
#pragma unroll
            for (int zr = 0; zr < 2; ++zr)
                af[zr] = *(const v8s*)&As[(w * 32 + zr * 16 + m15) * KL + ks * 32 + q * 8];
#pragma unroll
            for (int nf = 0; nf < 8; ++nf) {
                v8s wf = *(const v8s*)&Wsh[(nf * 16 + m15) * KL + ks * 32 + q * 8];
#pragma unroll
                for (int zr = 0; zr < 2; ++zr)
                    acc[zr][nf] = __builtin_amdgcn_mfma_f32_16x16x32_bf16(
                        wf, af[zr], acc[zr][nf], 0, 0, 0);
            }
        }
    }
    float* yf = (float*)g_bufA;
#pragma unroll
    for (int zr = 0; zr < 2; ++zr) {
        const long m = row0 + w * 32 + zr * 16 + m15;
#pragma unroll
        for (int nf = 0; nf < 8; ++nf)
            *(f32x4*)(yf + (size_t)m * 128 + nf * 16 + q * 4) = acc[zr][nf];
    }
}

// ---------------- streaming MFMA GEMM (round-11 form; + RAWF32 f32-out) -----
template<int Kp, int Np, int ZR, bool FLAT, int WSEL, bool ATOB, int NSPLIT,
         int KSC, int NTHR, long MROWS, bool RAWF32>
__global__ __launch_bounds__(NTHR)
void gemm_kernel() {
    constexpr int BN = Np / NSPLIT;          // cols handled by this block
    constexpr int NF = BN / 16;
    constexpr int KS = Kp / 32;
    constexpr int CPT = KS / KSC;            // chunks per tile
    constexpr int KL = Kp + 8;               // padded LDS row (elems, 16B step)
    constexpr int NW = NTHR / 64;
    constexpr int TM = NW * ZR * 16;         // rows per tile
    constexpr long NTILE = MROWS / TM;
    static_assert(KS % KSC == 0, "KSC must divide KS");
    __shared__ __align__(16) unsigned short Ws[BN * KL];
    __shared__ __align__(16) float bs[BN];
    const unsigned short* __restrict__ Wb =
        (WSEL == 1) ? g_W1b : (WSEL == 2) ? g_W2b : (WSEL == 3) ? g_W3b : g_W4b;
    const float* __restrict__ bp =
        (WSEL == 1) ? g_b1p : (WSEL == 2) ? g_b2p : (WSEL == 3) ? g_b3p : g_b4p;
    const unsigned short* __restrict__ A = ATOB ? g_bufA : g_bufB;
    unsigned short* __restrict__ Hout = ATOB ? g_bufB : g_bufA;
    const int t = threadIdx.x, w = t >> 6, lane = t & 63;
    const int m15 = lane & 15, q = lane >> 4;
    const int n0 = blockIdx.y * BN;
    // ---- stage W slice + bias to LDS (once per block) ----
    for (int i = t; i < BN * (Kp / 8); i += NTHR) {
        int r = i / (Kp / 8), c = i - r * (Kp / 8);
        *(v8s*)(&Ws[r * KL + c * 8]) = *(const v8s*)(Wb + (size_t)(n0 + r) * Kp + c * 8);
    }
    for (int i = t; i < BN; i += NTHR) bs[i] = bp[n0 + i];
    __syncthreads();

    v8s aC[ZR][KSC], aN[ZR][KSC];
    long tile = (long)blockIdx.x;
    if (tile < NTILE) {
        const unsigned short* ab =
            A + (size_t)(tile * TM + w * (ZR * 16) + m15) * Kp + q * 8;
#pragma unroll
        for (int zr = 0; zr < ZR; ++zr)
#pragma unroll
            for (int ks = 0; ks < KSC; ++ks)
                aC[zr][ks] = *(const v8s*)(ab + (size_t)zr * 16 * Kp + ks * 32);
    }
    for (; tile < NTILE; tile += gridDim.x) {
        f32x4 acc[ZR][NF];
#pragma unroll
        for (int zr = 0; zr < ZR; ++zr)
#pragma unroll
            for (int nf = 0; nf < NF; ++nf) acc[zr][nf] = 0.f;
        for (int c = 0; c < CPT; ++c) {
            // issue next chunk's A loads before consuming the current chunk
            const long ntile = (c + 1 < CPT) ? tile : tile + (long)gridDim.x;
            const int nk0 = (c + 1 < CPT) ? (c + 1) * KSC : 0;
            const bool hasNext = (ntile < NTILE);
            if (hasNext) {
                const unsigned short* ab =
                    A + (size_t)(ntile * TM + w * (ZR * 16) + m15) * Kp + nk0 * 32 + q * 8;
#pragma unroll
                for (int zr = 0; zr < ZR; ++zr)
#pragma unroll
                    for (int ks = 0; ks < KSC; ++ks)
                        aN[zr][ks] = *(const v8s*)(ab + (size_t)zr * 16 * Kp + ks * 32);
            }
#pragma unroll
            for (int nf = 0; nf < NF; ++nf) {
                v8s wr[KSC];
#pragma unroll
                for (int ks = 0; ks < KSC; ++ks)
                    wr[ks] = *(const v8s*)(&Ws[(nf * 16 + m15) * KL + (c * KSC + ks) * 32 + q * 8]);
#pragma unroll
                for (int ks = 0; ks < KSC; ++ks)
#pragma unroll
                    for (int zr = 0; zr < ZR; ++zr)
                        acc[zr][nf] = __builtin_amdgcn_mfma_f32_16x16x32_bf16(
                            wr[ks], aC[zr][ks], acc[zr][nf], 0, 0, 0);
            }
            if (hasNext) {
#pragma unroll
                for (int zr = 0; zr < ZR; ++zr)
#pragma unroll
                    for (int ks = 0; ks < KSC; ++ks) aC[zr][ks] = aN[zr][ks];
            }
        }
        // ---- epilogue ----
#pragma unroll
        for (int zr = 0; zr < ZR; ++zr) {
            const long m = tile * TM + w * (ZR * 16) + zr * 16 + m15;
#pragma unroll
            for (int nf = 0; nf < NF; ++nf) {
                f32x4 cc = acc[zr][nf];
                if (RAWF32) {
                    float* fH = (float*)Hout;
                    *(f32x4*)(fH + (size_t)m * Np + n0 + nf * 16 + q * 4) = cc;
                } else {
                    f32x4 b4 = *(const f32x4*)(&bs[nf * 16 + q * 4]);
                    float v0 = fmaxf(cc[0] + b4[0], 0.f), v1 = fmaxf(cc[1] + b4[1], 0.f);
                    float v2 = fmaxf(cc[2] + b4[2], 0.f), v3 = fmaxf(cc[3] + b4[3], 0.f);
                    if (!FLAT) {
                        ushort4 o; o.x = f2bf(v0); o.y = f2bf(v1); o.z = f2bf(v2); o.w = f2bf(v3);
                        *(ushort4*)(Hout + (size_t)m * Np + n0 + nf * 16 + q * 4) = o;
                    } else {
                        const int n0f = nf * 16 + q * 4;   // FLAT only with NSPLIT=1
                        if (n0f <= 48) {
                            const long s = m / 20; const int u = (int)(m - s * 20);
                            unsigned short* base = Hout + (size_t)s * 1024 + u * 50 + n0f;
                            unsigned int lo = (unsigned int)f2bf(v0) | ((unsigned int)f2bf(v1) << 16);
                            *(unsigned int*)(base) = lo;
                            if (n0f < 48) {
                                unsigned int hi = (unsigned int)f2bf(v2) | ((unsigned int)f2bf(v3) << 16);
                                *(unsigned int*)(base + 2) = hi;
                            }
                        }
                    }
                }
            }
        }
    }
}

// logits = W5 h4 + b5; softmax -> out. h4 in g_bufA (112-padded rows).
__global__ __launch_bounds__(256)
void head_kernel(const float* __restrict__ W5, const float* __restrict__ b5,
                 float* __restrict__ out) {
    __shared__ float w5s[300];
    __shared__ float b5s[3];
    const int t = threadIdx.x;
    for (int i = t; i < 300; i += 256) w5s[i] = W5[i];
    if (t < 3) b5s[t] = b5[t];
    __syncthreads();
    const int s = blockIdx.x * 256 + t;
    const unsigned short* h = g_bufA + (size_t)s * 112;
    float a0 = b5s[0], a1 = b5s[1], a2 = b5s[2];
    for (int k = 0; k < 100; ++k) {
        float hv = bf2f(h[k]);
        a0 += hv * w5s[k]; a1 += hv * w5s[100 + k]; a2 += hv * w5s[200 + k];
    }
    float m = fmaxf(a0, fmaxf(a1, a2));
    float e0 = expf(a0 - m), e1 = expf(a1 - m), e2 = expf(a2 - m);
    float inv = 1.f / (e0 + e1 + e2);
    out[(size_t)s * 3 + 0] = e0 * inv;
    out[(size_t)s * 3 + 1] = e1 * inv;
    out[(size_t)s * 3 + 2] = e2 * inv;
}

extern "C" void kernel_launch(void* const* d_in, const int* in_sizes, int n_in,
                              void* d_out, int out_size, void* d_ws, size_t ws_size,
                              hipStream_t stream) {
    const float* x  = (const float*)d_in[0];
    const float* W1 = (const float*)d_in[1];
    const float* b1 = (const float*)d_in[2];
    const float* W2 = (const float*)d_in[3];
    const float* b2 = (const float*)d_in[4];
    const float* W3 = (const float*)d_in[5];
    const float* b3 = (const float*)d_in[6];
    const float* W4 = (const float*)d_in[7];
    const float* b4 = (const float*)d_in[8];
    const float* W5 = (const float*)d_in[9];
    const float* b5 = (const float*)d_in[10];
    float* out = (float*)d_out;

    zero_C_kernel<<<3, P * P, 0, stream>>>();
    prep_kernel<<<256, 256, 0, stream>>>(W1, b1, W2, b2, W3, b3, W4, b4);

    // ---- layer 1 (agg-then-gemm; x is fp32 so reordering would balloon y1) --
    knn1_mfma_kernel<<<BB / 16, NT, 0, stream>>>(x);                 // x -> C0
    agg_mfma_kernel<128, 0><<<BB / 8, 512, 0, stream>>>(x);          // x -> z1(A)
    gemm1_kernel<<<dim3(2560, 2), 256, 0, stream>>>();               // z1 -> h1(B)

    // ---- layer 2 (reordered: gemm first, agg on smaller y2) ----
    knn_mfma_kernel<320, 1><<<BB / 16, NT, 0, stream>>>();           // h1 -> C1
    gemm2_kernel<<<2560, 256, 0, stream>>>();                        // h1 -> y2 f32 (A)
    agg_out_kernel<128, 1, false><<<BB / 8, 512, 0, stream>>>();     // y2 -> h2(B)

    // ---- layer 3 (reordered) ----
    knn_mfma_kernel<128, 2><<<BB / 16, NT, 0, stream>>>();           // h2 -> C2
    gemm_kernel<128, 64, 2, false, 3, false, 1, 4, 256, 327680L, true>
        <<<dim3(512, 1), 256, 0, stream>>>();                        // h2 -> y3 f32 (A)
    agg_out_kernel<64, 2, true><<<BB / 8, 512, 0, stream>>>();       // y3 -> h3f(B) FLAT

    // ---- head MLP ----
    gemm_kernel<1024, 112, 1, false, 4, false, 7, 8, 256, 16384L, false>
        <<<dim3(256, 7), 256, 0, stream>>>();                        // h3f -> h4(A)
    head_kernel<<<BB / 256, 256, 0, stream>>>(W5, b5, out);
}

// Round 9
// 861.753 us; speedup vs baseline: 1.4689x; 1.0298x over previous
//
#include <hip/hip_runtime.h>
#include <math.h>

#define BB 16384
#define P 20
#define NT 512

typedef short v8s __attribute__((ext_vector_type(8)));
typedef _Float16 v8h __attribute__((ext_vector_type(8)));
typedef float f32x4 __attribute__((ext_vector_type(4)));
typedef float f32x16 __attribute__((ext_vector_type(16)));

// ---- static device buffers: referenced ONLY inside device code (never passed
// as kernel args from host — that passes the host shadow and faults). ----
// +4096 pad: knn_mfma/agg_mfma read rows u=20..31 of the last samples (garbage,
// multiplied by zero-padded M columns / never stored).
#define NELEM ((size_t)BB * P * 320)          // 209.7 MB each
__device__ unsigned int g_C[3][P * P];
__device__ __align__(16) unsigned short g_bufA[NELEM + 4096];  // z1 / y2(f32) / y3(f32) / h4
__device__ __align__(16) unsigned short g_bufB[NELEM + 4096];  // h1 / h2 / h3f
__device__ __align__(16) unsigned short g_W1b[320 * 128];
__device__ __align__(16) unsigned short g_W2b[128 * 320];
__device__ __align__(16) unsigned short g_W3b[64 * 128];
__device__ __align__(16) unsigned short g_W4b[112 * 1024];
__device__ __align__(16) float g_b1p[320];
__device__ __align__(16) float g_b2p[128];
__device__ __align__(16) float g_b3p[64];
__device__ __align__(16) float g_b4p[112];

__device__ inline float bf2f(unsigned short u) {
    union { unsigned int i; float f; } c; c.i = ((unsigned int)u) << 16; return c.f;
}
__device__ inline unsigned short f2bf(float f) {
    union { float f; unsigned int i; } c; c.f = f;
    unsigned int u = c.i + 0x7fffu + ((c.i >> 16) & 1u);  // RNE (no NaN in data)
    return (unsigned short)(u >> 16);
}

__global__ void zero_C_kernel() { g_C[blockIdx.x][threadIdx.x] = 0u; }

// Pad+convert weights/biases to bf16 (zero pads -> pad outputs relu(0+0)=0).
__global__ void prep_kernel(const float* __restrict__ W1, const float* __restrict__ b1,
                            const float* __restrict__ W2, const float* __restrict__ b2,
                            const float* __restrict__ W3, const float* __restrict__ b3,
                            const float* __restrict__ W4, const float* __restrict__ b4) {
    const int stride = gridDim.x * blockDim.x;
    const int id = blockIdx.x * blockDim.x + threadIdx.x;
    for (int i = id; i < 320 * 128; i += stride) { int n = i >> 7, k = i & 127;
        g_W1b[i] = (n < 300) ? f2bf(W1[n * 128 + k]) : 0; }
    for (int i = id; i < 128 * 320; i += stride) { int n = i / 320, k = i - n * 320;
        g_W2b[i] = (n < 100 && k < 300) ? f2bf(W2[n * 300 + k]) : 0; }
    for (int i = id; i < 64 * 128; i += stride) { int n = i >> 7, k = i & 127;
        g_W3b[i] = (n < 50 && k < 100) ? f2bf(W3[n * 100 + k]) : 0; }
    for (int i = id; i < 112 * 1024; i += stride) { int n = i >> 10, k = i & 1023;
        g_W4b[i] = (n < 100 && k < 1000) ? f2bf(W4[n * 1000 + k]) : 0; }
    for (int i = id; i < 320; i += stride) g_b1p[i] = (i < 300) ? b1[i] : 0.f;
    for (int i = id; i < 128; i += stride) g_b2p[i] = (i < 100) ? b2[i] : 0.f;
    for (int i = id; i < 64;  i += stride) g_b3p[i] = (i < 50)  ? b3[i] : 0.f;
    for (int i = id; i < 112; i += stride) g_b4p[i] = (i < 100) ? b4[i] : 0.f;
}

// ---------------- kNN layer 1: MFMA Gram on fp16 hi/lo split (verified r8) --
__global__ __launch_bounds__(NT)
void knn1_mfma_kernel(const float* __restrict__ x) {
    __shared__ float Gs[8][P * 21];
    __shared__ unsigned int hist[P * P];
    const int t = threadIdx.x, w = t >> 6, lane = t & 63;
    const int m31 = lane & 31, half = lane >> 5;
    const int mrow = (m31 < P) ? m31 : (P - 1);
    for (int i = t; i < P * P; i += NT) hist[i] = 0;
    for (int pass = 0; pass < 2; ++pass) {
        const size_t s = (size_t)blockIdx.x * 16 + pass * 8 + w;
        const float* rp = x + s * (size_t)(P * 128) + (size_t)mrow * 128 + half * 8;
        f32x16 acc;
#pragma unroll
        for (int i = 0; i < 16; ++i) acc[i] = 0.f;
#pragma unroll
        for (int ks = 0; ks < 8; ++ks) {
            float4 f0 = *(const float4*)(rp + ks * 16);
            float4 f1 = *(const float4*)(rp + ks * 16 + 4);
            float fv[8] = {f0.x, f0.y, f0.z, f0.w, f1.x, f1.y, f1.z, f1.w};
            v8h hi, lo;
#pragma unroll
            for (int j = 0; j < 8; ++j) {
                _Float16 hv = (_Float16)fv[j];
                hi[j] = hv;
                lo[j] = (_Float16)(fv[j] - (float)hv);
            }
            acc = __builtin_amdgcn_mfma_f32_32x32x16_f16(hi, hi, acc, 0, 0, 0);
            acc = __builtin_amdgcn_mfma_f32_32x32x16_f16(hi, lo, acc, 0, 0, 0);
            acc = __builtin_amdgcn_mfma_f32_32x32x16_f16(lo, hi, acc, 0, 0, 0);
            acc = __builtin_amdgcn_mfma_f32_32x32x16_f16(lo, lo, acc, 0, 0, 0);
        }
        float* G = &Gs[w][0];
        if (m31 < P) {
#pragma unroll
            for (int r = 0; r < 16; ++r) {
                int row = (r & 3) + 8 * (r >> 2) + 4 * half;
                if (row < P) G[row * 21 + m31] = acc[r];
            }
        }
        __syncthreads();
        if (lane < P) {
            const int p = lane;
            float d2[P];
            const float gpp = G[p * 21 + p];
#pragma unroll
            for (int u = 0; u < P; ++u)
                d2[u] = (u == p) ? 0.f : gpp + G[u * 21 + u] - 2.f * G[p * 21 + u];
            float pv = -3.0e38f; int pi = -1;
            for (int it = 0; it < 6; ++it) {
                float best = 3.0e38f; int bq = 0;
#pragma unroll
                for (int u = 0; u < P; ++u) {
                    float vu = d2[u];
                    bool cand = (vu > pv) || (vu == pv && u > pi);
                    if (cand && vu < best) { best = vu; bq = u; }
                }
                if (it > 0) atomicAdd(&hist[bq * P + p], 1u);
                pv = best; pi = bq;
            }
        }
        __syncthreads();
    }
    if (t < P * P && hist[t]) atomicAdd(&g_C[0][t], hist[t]);
}

// ---------------- kNN via MFMA Gram: G = Z Z^T per sample (verified r6) -----
template<int D, int CIDX>
__global__ __launch_bounds__(NT)
void knn_mfma_kernel() {
    __shared__ float Gs[8][P * 21];
    __shared__ unsigned int hist[P * P];
    const int t = threadIdx.x, w = t >> 6, lane = t & 63;
    const int m31 = lane & 31, half = lane >> 5;
    for (int i = t; i < P * P; i += NT) hist[i] = 0;
    for (int pass = 0; pass < 2; ++pass) {
        const size_t s = (size_t)blockIdx.x * 16 + pass * 8 + w;
        const unsigned short* rp = g_bufB + s * (P * D) + (size_t)m31 * D + half * 8;
        f32x16 acc;
#pragma unroll
        for (int i = 0; i < 16; ++i) acc[i] = 0.f;
        for (int ks = 0; ks < D / 16; ++ks) {
            v8s z = *(const v8s*)(rp + ks * 16);
            acc = __builtin_amdgcn_mfma_f32_32x32x16_bf16(z, z, acc, 0, 0, 0);
        }
        float* G = &Gs[w][0];
        if (m31 < P) {
#pragma unroll
            for (int r = 0; r < 16; ++r) {
                int row = (r & 3) + 8 * (r >> 2) + 4 * half;
                if (row < P) G[row * 21 + m31] = acc[r];
            }
        }
        __syncthreads();
        if (lane < P) {
            const int p = lane;
            float d2[P];
            const float gpp = G[p * 21 + p];
#pragma unroll
            for (int u = 0; u < P; ++u)
                d2[u] = (u == p) ? 0.f : gpp + G[u * 21 + u] - 2.f * G[p * 21 + u];
            float pv = -3.0e38f; int pi = -1;
            for (int it = 0; it < 6; ++it) {
                float best = 3.0e38f; int bq = 0;
#pragma unroll
                for (int u = 0; u < P; ++u) {
                    float vu = d2[u];
                    bool cand = (vu > pv) || (vu == pv && u > pi);
                    if (cand && vu < best) { best = vu; bq = u; }
                }
                if (it > 0) atomicAdd(&hist[bq * P + p], 1u);
                pv = best; pi = bq;
            }
        }
        __syncthreads();
    }
    if (t < P * P && hist[t]) atomicAdd(&g_C[CIDX][t], hist[t]);
}

// compute_M for 512-thread blocks (strided loops)
__device__ inline void compute_M_512(const unsigned int* __restrict__ Cg,
                                     float* Ms, float* dinv, int t) {
    for (int i = t; i < P * P; i += 512) Ms[i] = (float)Cg[i];
    __syncthreads();
    if (t < P) {
        float deg = 1.f;
        for (int u = 0; u < P; ++u) deg += Ms[t * P + u];
        dinv[t] = 1.f / sqrtf(deg);
    }
    __syncthreads();
    for (int i = t; i < P * P; i += 512) {
        int v = i / P, u = i - v * P;
        float m = dinv[v] * Ms[i] * dinv[u];
        if (v == u) m += dinv[v] * dinv[v];
        Ms[i] = m;
    }
    __syncthreads();
}

// ---------------- agg via MFMA (verified r13): z1 = M @ x, layer 1 only -----
template<int D, int CIDX>
__global__ __launch_bounds__(512)
void agg_mfma_kernel(const float* __restrict__ xin) {
    constexpr int NCB = D / 32;              // 32-col blocks
    __shared__ float Ms[P * P];
    __shared__ float dinv[P];
    const int t = threadIdx.x, w = t >> 6, lane = t & 63;
    const int n31 = lane & 31, half = lane >> 5;
    compute_M_512(g_C[CIDX], Ms, dinv, t);
    v8s mhi[2], mlo[2];
#pragma unroll
    for (int kc = 0; kc < 2; ++kc)
#pragma unroll
        for (int j = 0; j < 8; ++j) {
            const int u = kc * 16 + half * 8 + j;
            const int v = n31;
            const float m = (v < P && u < P) ? Ms[v * P + u] : 0.f;
            const unsigned short h16 = f2bf(m);
            mhi[kc][j] = (short)h16;
            mlo[kc][j] = (short)f2bf(m - bf2f(h16));
        }
    const size_t s = (size_t)blockIdx.x * 8 + w;
    unsigned short* zout = g_bufA + s * (size_t)(P * D);
    const float* xr = xin + s * (size_t)(P * D);
#pragma unroll
    for (int cb = 0; cb < NCB; ++cb) {
        v8s bh0, bl0, bh1, bl1;
#pragma unroll
        for (int j = 0; j < 8; ++j) {
            const int u0 = half * 8 + j;                 // < 16, always valid
            int u1 = 16 + half * 8 + j; if (u1 > P - 1) u1 = P - 1;  // clamp
            const float x0 = xr[(size_t)u0 * D + cb * 32 + n31];
            const float x1 = xr[(size_t)u1 * D + cb * 32 + n31];
            const unsigned short h0 = f2bf(x0), h1 = f2bf(x1);
            bh0[j] = (short)h0; bl0[j] = (short)f2bf(x0 - bf2f(h0));
            bh1[j] = (short)h1; bl1[j] = (short)f2bf(x1 - bf2f(h1));
        }
        f32x16 acc;
#pragma unroll
        for (int i = 0; i < 16; ++i) acc[i] = 0.f;
        acc = __builtin_amdgcn_mfma_f32_32x32x16_bf16(mhi[0], bh0, acc, 0, 0, 0);
        acc = __builtin_amdgcn_mfma_f32_32x32x16_bf16(mhi[0], bl0, acc, 0, 0, 0);
        acc = __builtin_amdgcn_mfma_f32_32x32x16_bf16(mlo[0], bh0, acc, 0, 0, 0);
        acc = __builtin_amdgcn_mfma_f32_32x32x16_bf16(mlo[0], bl0, acc, 0, 0, 0);
        acc = __builtin_amdgcn_mfma_f32_32x32x16_bf16(mhi[1], bh1, acc, 0, 0, 0);
        acc = __builtin_amdgcn_mfma_f32_32x32x16_bf16(mhi[1], bl1, acc, 0, 0, 0);
        acc = __builtin_amdgcn_mfma_f32_32x32x16_bf16(mlo[1], bh1, acc, 0, 0, 0);
        acc = __builtin_amdgcn_mfma_f32_32x32x16_bf16(mlo[1], bl1, acc, 0, 0, 0);
#pragma unroll
        for (int r = 0; r < 16; ++r) {
            const int row = (r & 3) + 8 * (r >> 2) + 4 * half;
            if (row < P)
                zout[(size_t)row * D + cb * 32 + n31] = f2bf(acc[r]);
        }
    }
}

// ---------------- agg-after-gemm (verified r14): h = relu(M @ y + b) --------
template<int D, int CIDX, bool FLATOUT>
__global__ __launch_bounds__(512)
void agg_out_kernel() {
    constexpr int NCB = D / 32;
    __shared__ float Ms[P * P];
    __shared__ float dinv[P];
    const int t = threadIdx.x, w = t >> 6, lane = t & 63;
    const int n31 = lane & 31, half = lane >> 5;
    const float* __restrict__ bp = (CIDX == 1) ? g_b2p : g_b3p;
    compute_M_512(g_C[CIDX], Ms, dinv, t);
    v8s mhi[2], mlo[2];
#pragma unroll
    for (int kc = 0; kc < 2; ++kc)
#pragma unroll
        for (int j = 0; j < 8; ++j) {
            const int u = kc * 16 + half * 8 + j;
            const int v = n31;
            const float m = (v < P && u < P) ? Ms[v * P + u] : 0.f;
            const unsigned short h16 = f2bf(m);
            mhi[kc][j] = (short)h16;
            mlo[kc][j] = (short)f2bf(m - bf2f(h16));
        }
    const size_t s = (size_t)blockIdx.x * 8 + w;
    const float* yr = (const float*)g_bufA + s * (size_t)(P * D);
#pragma unroll
    for (int cb = 0; cb < NCB; ++cb) {
        v8s bh0, bl0, bh1, bl1;
#pragma unroll
        for (int j = 0; j < 8; ++j) {
            const int u0 = half * 8 + j;                 // < 16, always valid
            int u1 = 16 + half * 8 + j; if (u1 > P - 1) u1 = P - 1;  // clamp
            const float x0 = yr[(size_t)u0 * D + cb * 32 + n31];
            const float x1 = yr[(size_t)u1 * D + cb * 32 + n31];
            const unsigned short h0 = f2bf(x0), h1 = f2bf(x1);
            bh0[j] = (short)h0; bl0[j] = (short)f2bf(x0 - bf2f(h0));
            bh1[j] = (short)h1; bl1[j] = (short)f2bf(x1 - bf2f(h1));
        }
        f32x16 acc;
#pragma unroll
        for (int i = 0; i < 16; ++i) acc[i] = 0.f;
        acc = __builtin_amdgcn_mfma_f32_32x32x16_bf16(mhi[0], bh0, acc, 0, 0, 0);
        acc = __builtin_amdgcn_mfma_f32_32x32x16_bf16(mhi[0], bl0, acc, 0, 0, 0);
        acc = __builtin_amdgcn_mfma_f32_32x32x16_bf16(mlo[0], bh0, acc, 0, 0, 0);
        acc = __builtin_amdgcn_mfma_f32_32x32x16_bf16(mlo[0], bl0, acc, 0, 0, 0);
        acc = __builtin_amdgcn_mfma_f32_32x32x16_bf16(mhi[1], bh1, acc, 0, 0, 0);
        acc = __builtin_amdgcn_mfma_f32_32x32x16_bf16(mhi[1], bl1, acc, 0, 0, 0);
        acc = __builtin_amdgcn_mfma_f32_32x32x16_bf16(mlo[1], bh1, acc, 0, 0, 0);
        acc = __builtin_amdgcn_mfma_f32_32x32x16_bf16(mlo[1], bl1, acc, 0, 0, 0);
        const float bv = bp[cb * 32 + n31];
#pragma unroll
        for (int r = 0; r < 16; ++r) {
            const int row = (r & 3) + 8 * (r >> 2) + 4 * half;
            if (row < P) {
                const float val = fmaxf(acc[r] + bv, 0.f);
                if (FLATOUT) {
                    const int d = cb * 32 + n31;
                    if (d < 50)
                        g_bufB[s * 1024 + (size_t)row * 50 + d] = f2bf(val);
                } else {
                    g_bufB[(s * (size_t)P + row) * D + cb * 32 + n31] = f2bf(val);
                }
            }
        }
    }
}

// ---------------- gemm2' (verified r14): y2 = h1 @ W2^T, raw f32 out --------
__global__ __launch_bounds__(256)
void gemm2_kernel() {
    constexpr int KL = 72;                   // padded LDS row, elems
    __shared__ __align__(16) unsigned short As[128 * KL];
    __shared__ __align__(16) unsigned short Wsh[128 * KL];
    const int t = threadIdx.x, w = t >> 6, lane = t & 63;
    const int m15 = lane & 15, q = lane >> 4;
    const long row0 = (long)blockIdx.x * 128;
    f32x4 acc[2][8];
#pragma unroll
    for (int zr = 0; zr < 2; ++zr)
#pragma unroll
        for (int nf = 0; nf < 8; ++nf) acc[zr][nf] = 0.f;
    for (int kc = 0; kc < 5; ++kc) {         // K chunks of 64 elems
        __syncthreads();                     // guard LDS reuse
        for (int i = t; i < 1024; i += 256) {
            const int r = i >> 3, c8 = i & 7;
            *(v8s*)&As[r * KL + c8 * 8] =
                *(const v8s*)(g_bufB + (size_t)(row0 + r) * 320 + kc * 64 + c8 * 8);
            *(v8s*)&Wsh[r * KL + c8 * 8] =
                *(const v8s*)(g_W2b + (size_t)r * 320 + kc * 64 + c8 * 8);
        }
        __syncthreads();
#pragma unroll
        for (int ks = 0; ks < 2; ++ks) {     // 32-elem MFMA sub-steps
            v8s af[2];
#pragma unroll
            for (int zr = 0; zr < 2; ++zr)
                af[zr] = *(const v8s*)&As[(w * 32 + zr * 16 + m15) * KL + ks * 32 + q * 8];
#pragma unroll
            for (int nf = 0; nf < 8; ++nf) {
                v8s wf = *(const v8s*)&Wsh[(nf * 16 + m15) * KL + ks * 32 + q * 8];
#pragma unroll
                for (int zr = 0; zr < 2; ++zr)
                    acc[zr][nf] = __builtin_amdgcn_mfma_f32_16x16x32_bf16(
                        wf, af[zr], acc[zr][nf], 0, 0, 0);
            }
        }
    }
    float* yf = (float*)g_bufA;
#pragma unroll
    for (int zr = 0; zr < 2; ++zr) {
        const long m = row0 + w * 32 + zr * 16 + m15;
#pragma unroll
        for (int nf = 0; nf < 8; ++nf)
            *(f32x4*)(yf + (size_t)m * 128 + nf * 16 + q * 4) = acc[zr][nf];
    }
}

// ---------------- streaming MFMA GEMM (round-11 form; + RAWF32 f32-out) -----
// Round-8 lesson: the canonical 2-barrier form loses at K=128 (2 chunks ->
// pipeline never fills; 149.7us). The streaming form was right; its defect was
// VGPR=216 -> 2 waves/SIMD. gemm1 now runs it with ZR=1, NTHR=512: acc 40 +
// aC/aN 32 -> ~120 VGPR -> 4 waves/SIMD; LDS 43.5KB -> 3 blk/CU -> ~16
// waves/CU. Per-output K order unchanged -> bit-exact.
template<int Kp, int Np, int ZR, bool FLAT, int WSEL, bool ATOB, int NSPLIT,
         int KSC, int NTHR, long MROWS, bool RAWF32>
__global__ __launch_bounds__(NTHR)
void gemm_kernel() {
    constexpr int BN = Np / NSPLIT;          // cols handled by this block
    constexpr int NF = BN / 16;
    constexpr int KS = Kp / 32;
    constexpr int CPT = KS / KSC;            // chunks per tile
    constexpr int KL = Kp + 8;               // padded LDS row (elems, 16B step)
    constexpr int NW = NTHR / 64;
    constexpr int TM = NW * ZR * 16;         // rows per tile
    constexpr long NTILE = MROWS / TM;
    static_assert(KS % KSC == 0, "KSC must divide KS");
    __shared__ __align__(16) unsigned short Ws[BN * KL];
    __shared__ __align__(16) float bs[BN];
    const unsigned short* __restrict__ Wb =
        (WSEL == 1) ? g_W1b : (WSEL == 2) ? g_W2b : (WSEL == 3) ? g_W3b : g_W4b;
    const float* __restrict__ bp =
        (WSEL == 1) ? g_b1p : (WSEL == 2) ? g_b2p : (WSEL == 3) ? g_b3p : g_b4p;
    const unsigned short* __restrict__ A = ATOB ? g_bufA : g_bufB;
    unsigned short* __restrict__ Hout = ATOB ? g_bufB : g_bufA;
    const int t = threadIdx.x, w = t >> 6, lane = t & 63;
    const int m15 = lane & 15, q = lane >> 4;
    const int n0 = blockIdx.y * BN;
    // ---- stage W slice + bias to LDS (once per block) ----
    for (int i = t; i < BN * (Kp / 8); i += NTHR) {
        int r = i / (Kp / 8), c = i - r * (Kp / 8);
        *(v8s*)(&Ws[r * KL + c * 8]) = *(const v8s*)(Wb + (size_t)(n0 + r) * Kp + c * 8);
    }
    for (int i = t; i < BN; i += NTHR) bs[i] = bp[n0 + i];
    __syncthreads();

    v8s aC[ZR][KSC], aN[ZR][KSC];
    long tile = (long)blockIdx.x;
    if (tile < NTILE) {
        const unsigned short* ab =
            A + (size_t)(tile * TM + w * (ZR * 16) + m15) * Kp + q * 8;
#pragma unroll
        for (int zr = 0; zr < ZR; ++zr)
#pragma unroll
            for (int ks = 0; ks < KSC; ++ks)
                aC[zr][ks] = *(const v8s*)(ab + (size_t)zr * 16 * Kp + ks * 32);
    }
    for (; tile < NTILE; tile += gridDim.x) {
        f32x4 acc[ZR][NF];
#pragma unroll
        for (int zr = 0; zr < ZR; ++zr)
#pragma unroll
            for (int nf = 0; nf < NF; ++nf) acc[zr][nf] = 0.f;
        for (int c = 0; c < CPT; ++c) {
            // issue next chunk's A loads before consuming the current chunk
            const long ntile = (c + 1 < CPT) ? tile : tile + (long)gridDim.x;
            const int nk0 = (c + 1 < CPT) ? (c + 1) * KSC : 0;
            const bool hasNext = (ntile < NTILE);
            if (hasNext) {
                const unsigned short* ab =
                    A + (size_t)(ntile * TM + w * (ZR * 16) + m15) * Kp + nk0 * 32 + q * 8;
#pragma unroll
                for (int zr = 0; zr < ZR; ++zr)
#pragma unroll
                    for (int ks = 0; ks < KSC; ++ks)
                        aN[zr][ks] = *(const v8s*)(ab + (size_t)zr * 16 * Kp + ks * 32);
            }
#pragma unroll
            for (int nf = 0; nf < NF; ++nf) {
                v8s wr[KSC];
#pragma unroll
                for (int ks = 0; ks < KSC; ++ks)
                    wr[ks] = *(const v8s*)(&Ws[(nf * 16 + m15) * KL + (c * KSC + ks) * 32 + q * 8]);
#pragma unroll
                for (int ks = 0; ks < KSC; ++ks)
#pragma unroll
                    for (int zr = 0; zr < ZR; ++zr)
                        acc[zr][nf] = __builtin_amdgcn_mfma_f32_16x16x32_bf16(
                            wr[ks], aC[zr][ks], acc[zr][nf], 0, 0, 0);
            }
            if (hasNext) {
#pragma unroll
                for (int zr = 0; zr < ZR; ++zr)
#pragma unroll
                    for (int ks = 0; ks < KSC; ++ks) aC[zr][ks] = aN[zr][ks];
            }
        }
        // ---- epilogue ----
#pragma unroll
        for (int zr = 0; zr < ZR; ++zr) {
            const long m = tile * TM + w * (ZR * 16) + zr * 16 + m15;
#pragma unroll
            for (int nf = 0; nf < NF; ++nf) {
                f32x4 cc = acc[zr][nf];
                if (RAWF32) {
                    float* fH = (float*)Hout;
                    *(f32x4*)(fH + (size_t)m * Np + n0 + nf * 16 + q * 4) = cc;
                } else {
                    f32x4 b4 = *(const f32x4*)(&bs[nf * 16 + q * 4]);
                    float v0 = fmaxf(cc[0] + b4[0], 0.f), v1 = fmaxf(cc[1] + b4[1], 0.f);
                    float v2 = fmaxf(cc[2] + b4[2], 0.f), v3 = fmaxf(cc[3] + b4[3], 0.f);
                    if (!FLAT) {
                        ushort4 o; o.x = f2bf(v0); o.y = f2bf(v1); o.z = f2bf(v2); o.w = f2bf(v3);
                        *(ushort4*)(Hout + (size_t)m * Np + n0 + nf * 16 + q * 4) = o;
                    } else {
                        const int n0f = nf * 16 + q * 4;   // FLAT only with NSPLIT=1
                        if (n0f <= 48) {
                            const long s = m / 20; const int u = (int)(m - s * 20);
                            unsigned short* base = Hout + (size_t)s * 1024 + u * 50 + n0f;
                            unsigned int lo = (unsigned int)f2bf(v0) | ((unsigned int)f2bf(v1) << 16);
                            *(unsigned int*)(base) = lo;
                            if (n0f < 48) {
                                unsigned int hi = (unsigned int)f2bf(v2) | ((unsigned int)f2bf(v3) << 16);
                                *(unsigned int*)(base + 2) = hi;
                            }
                        }
                    }
                }
            }
        }
    }
}

// logits = W5 h4 + b5; softmax -> out. h4 in g_bufA (112-padded rows).
__global__ __launch_bounds__(256)
void head_kernel(const float* __restrict__ W5, const float* __restrict__ b5,
                 float* __restrict__ out) {
    __shared__ float w5s[300];
    __shared__ float b5s[3];
    const int t = threadIdx.x;
    for (int i = t; i < 300; i += 256) w5s[i] = W5[i];
    if (t < 3) b5s[t] = b5[t];
    __syncthreads();
    const int s = blockIdx.x * 256 + t;
    const unsigned short* h = g_bufA + (size_t)s * 112;
    float a0 = b5s[0], a1 = b5s[1], a2 = b5s[2];
    for (int k = 0; k < 100; ++k) {
        float hv = bf2f(h[k]);
        a0 += hv * w5s[k]; a1 += hv * w5s[100 + k]; a2 += hv * w5s[200 + k];
    }
    float m = fmaxf(a0, fmaxf(a1, a2));
    float e0 = expf(a0 - m), e1 = expf(a1 - m), e2 = expf(a2 - m);
    float inv = 1.f / (e0 + e1 + e2);
    out[(size_t)s * 3 + 0] = e0 * inv;
    out[(size_t)s * 3 + 1] = e1 * inv;
    out[(size_t)s * 3 + 2] = e2 * inv;
}

extern "C" void kernel_launch(void* const* d_in, const int* in_sizes, int n_in,
                              void* d_out, int out_size, void* d_ws, size_t ws_size,
                              hipStream_t stream) {
    const float* x  = (const float*)d_in[0];
    const float* W1 = (const float*)d_in[1];
    const float* b1 = (const float*)d_in[2];
    const float* W2 = (const float*)d_in[3];
    const float* b2 = (const float*)d_in[4];
    const float* W3 = (const float*)d_in[5];
    const float* b3 = (const float*)d_in[6];
    const float* W4 = (const float*)d_in[7];
    const float* b4 = (const float*)d_in[8];
    const float* W5 = (const float*)d_in[9];
    const float* b5 = (const float*)d_in[10];
    float* out = (float*)d_out;

    zero_C_kernel<<<3, P * P, 0, stream>>>();
    prep_kernel<<<256, 256, 0, stream>>>(W1, b1, W2, b2, W3, b3, W4, b4);

    // ---- layer 1 (agg-then-gemm; x is fp32 so reordering would balloon y1) --
    knn1_mfma_kernel<<<BB / 16, NT, 0, stream>>>(x);                 // x -> C0
    agg_mfma_kernel<128, 0><<<BB / 8, 512, 0, stream>>>(x);          // x -> z1(A)
    // streaming form, ZR=1, 512-thr (8 waves x 16 rows): ~120 VGPR -> 4 w/SIMD
    gemm_kernel<128, 320, 1, false, 1, true, 2, 4, 512, 327680L, false>
        <<<dim3(512, 2), 512, 0, stream>>>();                        // z1 -> h1(B)

    // ---- layer 2 (reordered: gemm first, agg on smaller y2) ----
    knn_mfma_kernel<320, 1><<<BB / 16, NT, 0, stream>>>();           // h1 -> C1
    gemm2_kernel<<<2560, 256, 0, stream>>>();                        // h1 -> y2 f32 (A)
    agg_out_kernel<128, 1, false><<<BB / 8, 512, 0, stream>>>();     // y2 -> h2(B)

    // ---- layer 3 (reordered) ----
    knn_mfma_kernel<128, 2><<<BB / 16, NT, 0, stream>>>();           // h2 -> C2
    gemm_kernel<128, 64, 2, false, 3, false, 1, 4, 256, 327680L, true>
        <<<dim3(512, 1), 256, 0, stream>>>();                        // h2 -> y3 f32 (A)
    agg_out_kernel<64, 2, true><<<BB / 8, 512, 0, stream>>>();       // y3 -> h3f(B) FLAT

    // ---- head MLP ----
    gemm_kernel<1024, 112, 1, false, 4, false, 7, 8, 256, 16384L, false>
        <<<dim3(256, 7), 256, 0, stream>>>();                        // h3f -> h4(A)
    head_kernel<<<BB / 256, 256, 0, stream>>>(W5, b5, out);
}